// Round 7
// baseline (500.925 us; speedup 1.0000x reference)
//
#include <hip/hip_runtime.h>
#include <hip/hip_bf16.h>
#include <math.h>

#define RR 32
#define R3 32768
#define BB 4
#define CI 64
#define CO 64
#define NN 4096

typedef short v8s __attribute__((ext_vector_type(8)));
typedef float v4f __attribute__((ext_vector_type(4)));
typedef unsigned short ushort_t;

__device__ __forceinline__ unsigned short f2bf(float f) {
    unsigned int u = __float_as_uint(f);
    unsigned int r = (u + 0x7FFFu + ((u >> 16) & 1u)) >> 16;
    return (unsigned short)r;
}

__device__ __forceinline__ void gll16(const void* g, void* l) {
    __builtin_amdgcn_global_load_lds((const __attribute__((address_space(1))) unsigned int*)g,
                                     (__attribute__((address_space(3))) unsigned int*)l, 16, 0, 0);
}

// ---------------- block reduce helpers ----------------
__device__ __forceinline__ float blockReduceSum(float v, float* sm) {
    int tid = threadIdx.x;
    sm[tid] = v; __syncthreads();
    for (int off = 128; off > 0; off >>= 1) {
        if (tid < off) sm[tid] += sm[tid + off];
        __syncthreads();
    }
    float r = sm[0]; __syncthreads();
    return r;
}
__device__ __forceinline__ float blockReduceMax(float v, float* sm) {
    int tid = threadIdx.x;
    sm[tid] = v; __syncthreads();
    for (int off = 128; off > 0; off >>= 1) {
        if (tid < off) sm[tid] = fmaxf(sm[tid], sm[tid + off]);
        __syncthreads();
    }
    float r = sm[0]; __syncthreads();
    return r;
}

// ---------------- voxel coords ----------------
__global__ void k_nc(const float* __restrict__ coords, float* __restrict__ nc,
                     int* __restrict__ vidx) {
    int b = blockIdx.x, tid = threadIdx.x;
    __shared__ float sm[256];
    const float* cb = coords + (size_t)b * 3 * NN;
    float s0 = 0, s1 = 0, s2 = 0;
    for (int n = tid; n < NN; n += 256) {
        s0 += cb[n]; s1 += cb[NN + n]; s2 += cb[2 * NN + n];
    }
    float m0 = blockReduceSum(s0, sm) * (1.0f / NN);
    float m1 = blockReduceSum(s1, sm) * (1.0f / NN);
    float m2 = blockReduceSum(s2, sm) * (1.0f / NN);
    float mx = 0;
    for (int n = tid; n < NN; n += 256) {
        float dx = cb[n] - m0, dy = cb[NN + n] - m1, dz = cb[2 * NN + n] - m2;
        mx = fmaxf(mx, dx * dx + dy * dy + dz * dz);
    }
    mx = blockReduceMax(mx, sm);
    float denom = 2.0f * sqrtf(mx);
    float mean[3] = {m0, m1, m2};
    for (int n = tid; n < NN; n += 256) {
        int vi[3];
        #pragma unroll
        for (int ax = 0; ax < 3; ax++) {
            float x = (cb[ax * NN + n] - mean[ax]) / denom + 0.5f;
            x = x * RR;
            x = fminf(fmaxf(x, 0.0f), (float)(RR - 1));
            nc[((size_t)b * 3 + ax) * NN + n] = x;
            vi[ax] = (int)rintf(x);
        }
        vidx[b * NN + n] = (vi[0] * RR + vi[1]) * RR + vi[2];
    }
}

// ---------------- scatter-mean (channel-first) ----------------
__global__ void k_scatter(const float* __restrict__ feat, const int* __restrict__ vidx,
                          float* __restrict__ grid, float* __restrict__ cnt) {
    int tid = threadIdx.x;
    int pid = blockIdx.x * 64 + (tid & 63);
    int cg = tid >> 6;
    int b = pid / NN, n = pid % NN;
    int idx = vidx[pid];
    if (cg == 0) atomicAdd(&cnt[b * R3 + idx], 1.0f);
    #pragma unroll 4
    for (int c = cg * 16; c < cg * 16 + 16; c++)
        atomicAdd(&grid[((size_t)(b * CI + c)) * R3 + idx], feat[((size_t)(b * CI + c)) * NN + n]);
}

// ---------------- divide + transpose + bf16 cast: cf f32 -> cl bf16 ----------------
__global__ void k_avgT(const float* __restrict__ grid, const float* __restrict__ cnt,
                       ushort_t* __restrict__ gT) {
    __shared__ float ld[64][65];
    int b = blockIdx.y, s0 = blockIdx.x * 64, tid = threadIdx.x;
    int sl = tid & 63, cq = tid >> 6;
    const float* xb = grid + (size_t)b * 64 * R3;
    #pragma unroll
    for (int k = 0; k < 16; k++) {
        int c = cq * 16 + k;
        ld[sl][c] = xb[(size_t)c * R3 + s0 + sl];
    }
    __syncthreads();
    int v = tid >> 2, q = tid & 3;
    float inv = 1.0f / fmaxf(cnt[b * R3 + s0 + v], 1.0f);
    unsigned int pk[8];
    #pragma unroll
    for (int j = 0; j < 8; j++) {
        int c = q * 16 + j * 2;
        float a = ld[v][c] * inv, d = ld[v][c + 1] * inv;
        pk[j] = (unsigned int)f2bf(a) | ((unsigned int)f2bf(d) << 16);
    }
    uint4* op = (uint4*)(gT + ((size_t)(b * R3 + s0 + v)) * 64 + q * 16);
    op[0] = make_uint4(pk[0], pk[1], pk[2], pk[3]);
    op[1] = make_uint4(pk[4], pk[5], pk[6], pk[7]);
}

// ---------------- features f32 -> bf16 ----------------
__global__ void k_f2b(const float* __restrict__ x, ushort_t* __restrict__ o) {
    size_t i = (size_t)blockIdx.x * 256 + threadIdx.x;
    float4 a = ((const float4*)x)[i * 2];
    float4 b = ((const float4*)x)[i * 2 + 1];
    union { __hip_bfloat162 h[4]; uint4 u; } pk;
    pk.h[0] = __float22bfloat162_rn(make_float2(a.x, a.y));
    pk.h[1] = __float22bfloat162_rn(make_float2(a.z, a.w));
    pk.h[2] = __float22bfloat162_rn(make_float2(b.x, b.y));
    pk.h[3] = __float22bfloat162_rn(make_float2(b.z, b.w));
    ((uint4*)o)[i] = pk.u;
}

// ---------------- weight transform: wS[dzdy 9][cih 2][dx 3][co 64][cis 32] bf16 ----------------
__global__ void k_tws(const float* __restrict__ w, ushort_t* __restrict__ wS) {
    int i = blockIdx.x * 256 + threadIdx.x;  // 110592
    int cis = i & 31, co = (i >> 5) & 63;
    int dx = (i >> 11) % 3, cih = (i / 6144) & 1, dzdy = i / 12288;
    int k = dzdy * 3 + dx, ci = cih * 32 + cis;
    wS[i] = f2bf(w[((size_t)co * CI + ci) * 27 + k]);
}

// ---------------- BN + lrelu + bf16 cast (cl -> cl) ----------------
__global__ void k_bncast(const float* __restrict__ x, const float* __restrict__ stats,
                         float slope, ushort_t* __restrict__ o) {
    size_t i = (size_t)blockIdx.x * 256 + threadIdx.x;  // over B*R3*64/8
    int c0 = (int)((i * 8) & 63);
    float4 a = ((const float4*)x)[i * 2];
    float4 d = ((const float4*)x)[i * 2 + 1];
    float va[8] = {a.x, a.y, a.z, a.w, d.x, d.y, d.z, d.w};
    unsigned pk[4];
    #pragma unroll
    for (int j = 0; j < 4; j++) {
        float u0 = va[2 * j] * stats[2 * (c0 + 2 * j)] + stats[2 * (c0 + 2 * j) + 1];
        float u1 = va[2 * j + 1] * stats[2 * (c0 + 2 * j) + 2] + stats[2 * (c0 + 2 * j) + 3];
        u0 = u0 > 0 ? u0 : slope * u0;
        u1 = u1 > 0 ? u1 : slope * u1;
        pk[j] = (unsigned)f2bf(u0) | ((unsigned)f2bf(u1) << 16);
    }
    ((uint4*)o)[i] = make_uint4(pk[0], pk[1], pk[2], pk[3]);
}

// ---------------- LDS-staged MFMA conv3d 3x3x3, fused BN-stats epilogue ----------------
__global__ __launch_bounds__(256) void k_convlds(const ushort_t* __restrict__ gT,
                                                 const ushort_t* __restrict__ wS,
                                                 float* __restrict__ outCL,
                                                 float* __restrict__ accs) {
    __shared__ ushort_t lin[20480];     // 40960B input plane (also reused as stats buf)
    __shared__ ushort_t lw[2][6144];    // 2 x 12288B weights
    int bid = blockIdx.x;
    int wgid = (bid & 7) * 64 + (bid >> 3);
    int yt = wgid & 3, z0 = (wgid >> 2) & 31, b = wgid >> 7;
    int tid = threadIdx.x;
    int w = __builtin_amdgcn_readfirstlane(tid >> 6);
    int lane = tid & 63, l15 = lane & 15, l4 = lane >> 4;
    int y0 = yt * 8;
    const ushort_t* gTb = gT + (size_t)b * R3 * 64;

    int voxF[4];
    #pragma unroll
    for (int f = 0; f < 4; f++)
        voxF[f] = (w * 2 + (f >> 1)) * 32 + (f & 1) * 16 + l15 - 1;
    bool xlo_ok = (l15 != 0), xhi_ok = (l15 != 15);

    const v8s vzero = {};
    v4f acc[4][4];
    #pragma unroll
    for (int m = 0; m < 4; m++)
        #pragma unroll
        for (int f = 0; f < 4; f++)
            acc[m][f] = (v4f){0.0f, 0.0f, 0.0f, 0.0f};

#define WSTAGE(s)                                                              \
    do {                                                                       \
        const ushort_t* _src = wS + (size_t)(s) * 6144;                        \
        ushort_t* _dst = lw[(s) & 1];                                          \
        _Pragma("unroll") for (int _i = 0; _i < 3; _i++) {                     \
            int _p = _i * 256 + w * 64;                                        \
            gll16(_src + (size_t)(_p + lane) * 8, _dst + (size_t)_p * 8);      \
        }                                                                      \
    } while (0)

#define ISTAGE(dz)                                                             \
    do {                                                                       \
        int _zp = z0 - 1 + (dz);                                               \
        if (_zp < 0 || _zp > 31) {                                             \
            for (int _q = 0; _q < 10; _q++)                                    \
                *(v8s*)&lin[(size_t)(w * 640 + _q * 64 + lane) * 8] = vzero;   \
        } else {                                                               \
            if (yt == 0) *(v8s*)&lin[(size_t)tid * 8] = vzero;                 \
            if (yt == 3) *(v8s*)&lin[(size_t)(2304 + tid) * 8] = vzero;        \
            const ushort_t* _pb = gTb + ((size_t)_zp * 1024 + (size_t)(y0 - 1) * 32) * 64; \
            int _g0 = (yt == 0) ? 256 : 0;                                     \
            int _nc = 10 - (yt == 0) - (yt == 3);                              \
            for (int _i = 0; _i < _nc; _i++) {                                 \
                int _pbase = _g0 + _i * 256 + w * 64;                          \
                int _p = _pbase + lane;                                        \
                int _vx = _p >> 3, _js = _p & 7;                               \
                int _sg = _vx * 8 + (_js ^ (_vx & 7));                         \
                gll16(_pb + (size_t)_sg * 8, lin + (size_t)_pbase * 8);        \
            }                                                                  \
        }                                                                      \
    } while (0)

    WSTAGE(0);
    for (int s = 0; s < 18; s++) {
        int dy = (s / 2) % 3, cih = s & 1;
        asm volatile("s_barrier" ::: "memory");
        if ((s % 6) == 0) ISTAGE(s / 6);
        if (s + 1 < 18) WSTAGE(s + 1);
        if (s + 1 < 18) asm volatile("s_waitcnt vmcnt(3) lgkmcnt(0)" ::: "memory");
        else            asm volatile("s_waitcnt vmcnt(0) lgkmcnt(0)" ::: "memory");
        asm volatile("s_barrier" ::: "memory");

        const ushort_t* lwb = lw[s & 1];
        #pragma unroll
        for (int dx = 0; dx < 3; dx++) {
            v8s Bf[4];
            #pragma unroll
            for (int f = 0; f < 4; f++) {
                int vox = voxF[f] + dy * 32 + dx;
                int g = vox * 8 + ((cih * 4 + l4) ^ (vox & 7));
                int bix = g * 16;
                bix = bix < 0 ? 0 : bix;
                v8s vb = *(const v8s*)((const char*)lin + bix);
                bool ok = (dx == 0 && (f & 1) == 0) ? xlo_ok :
                          (dx == 2 && (f & 1) == 1) ? xhi_ok : true;
                Bf[f] = ok ? vb : vzero;
            }
            const ushort_t* ap = lwb + dx * 2048 + l15 * 32 + l4 * 8;
            #pragma unroll
            for (int m = 0; m < 4; m++) {
                v8s Af = *(const v8s*)(ap + m * 512);
                #pragma unroll
                for (int f = 0; f < 4; f++)
                    acc[m][f] = __builtin_amdgcn_mfma_f32_16x16x32_bf16(Af, Bf[f], acc[m][f], 0, 0, 0);
            }
        }
    }

    // channel-last f4 stores
    #pragma unroll
    for (int m = 0; m < 4; m++) {
        #pragma unroll
        for (int f = 0; f < 4; f++) {
            int y = y0 + w * 2 + (f >> 1);
            int x = (f & 1) * 16 + l15;
            float4 o = make_float4(acc[m][f][0], acc[m][f][1], acc[m][f][2], acc[m][f][3]);
            *(float4*)&outCL[((size_t)b * R3 + z0 * 1024 + y * 32 + x) * 64 + m * 16 + l4 * 4] = o;
        }
    }

    // ---- fused BN-stats: per-block sum/sumsq per co -> atomics ----
    __syncthreads();                      // all waves done reading lin
    float* sbuf = (float*)lin;            // 256 thr x 32 floats = 32KB
    #pragma unroll
    for (int m = 0; m < 4; m++)
        #pragma unroll
        for (int r = 0; r < 4; r++) {
            float s = 0, q = 0;
            #pragma unroll
            for (int f = 0; f < 4; f++) {
                float v = acc[m][f][r];
                s += v; q += v * v;
            }
            sbuf[tid * 32 + (m * 4 + r) * 2] = s;
            sbuf[tid * 32 + (m * 4 + r) * 2 + 1] = q;
        }
    __syncthreads();
    if (tid < 128) {
        int co = tid >> 1, val = tid & 1;
        int m = co >> 4, cl4 = (co >> 2) & 3, r = co & 3;
        float a = 0;
        for (int w2 = 0; w2 < 4; w2++)
            for (int l = 0; l < 16; l++)
                a += sbuf[(w2 * 64 + cl4 * 16 + l) * 32 + (m * 4 + r) * 2 + val];
        atomicAdd(&accs[2 * co + val], a);
    }
#undef WSTAGE
#undef ISTAGE
}

__global__ void k_bnfin(const float* __restrict__ pst, const float* __restrict__ g,
                        const float* __restrict__ be, float* __restrict__ stats,
                        int nb, float invcnt) {
    int c = threadIdx.x;
    float s = 0, q = 0;
    for (int b = 0; b < nb; b++) {
        s += pst[(c * nb + b) * 2];
        q += pst[(c * nb + b) * 2 + 1];
    }
    float mean = s * invcnt;
    float var = q * invcnt - mean * mean;
    float sc = g[c] * rsqrtf(var + 1e-4f);
    stats[2 * c] = sc;
    stats[2 * c + 1] = be[c] - mean * sc;
}

__global__ void k_bn_act(const float* __restrict__ x, const float* __restrict__ stats,
                         float* __restrict__ out, int shift, float slope) {
    size_t i = (size_t)blockIdx.x * 256 + threadIdx.x;
    int c = (int)((i >> shift) & 63);
    float sc = stats[2 * c], sh = stats[2 * c + 1];
    float4 v = ((const float4*)x)[i];
    v.x = v.x * sc + sh; v.y = v.y * sc + sh; v.z = v.z * sc + sh; v.w = v.w * sc + sh;
    v.x = v.x > 0 ? v.x : slope * v.x;
    v.y = v.y > 0 ? v.y : slope * v.y;
    v.z = v.z > 0 ? v.z : slope * v.z;
    v.w = v.w > 0 ? v.w : slope * v.w;
    ((float4*)out)[i] = v;
}

// ---------------- devoxelize, fused BN+lrelu, channel-last gather ----------------
__global__ void k_devox2(const float* __restrict__ gcl, const float* __restrict__ stats,
                         const float* __restrict__ nc, float* __restrict__ out) {
    int b = blockIdx.y;
    int tid = threadIdx.x, p = tid >> 4, q = tid & 15;
    int n = blockIdx.x * 16 + p;
    float x = nc[((size_t)b * 3 + 0) * NN + n];
    float y = nc[((size_t)b * 3 + 1) * NN + n];
    float z = nc[((size_t)b * 3 + 2) * NN + n];
    float fx = floorf(x), fy = floorf(y), fz = floorf(z);
    int lx = (int)fx, ly = (int)fy, lz = (int)fz;
    int hx = min(lx + 1, RR - 1), hy = min(ly + 1, RR - 1), hz = min(lz + 1, RR - 1);
    float frx = x - fx, fry = y - fy, frz = z - fz;
    int xx[2] = {lx, hx}, yy[2] = {ly, hy}, zz[2] = {lz, hz};
    float wx[2] = {1.0f - frx, frx}, wy[2] = {1.0f - fry, fry}, wz[2] = {1.0f - frz, frz};
    float sc[4], sh[4];
    #pragma unroll
    for (int j = 0; j < 4; j++) {
        sc[j] = stats[2 * (q * 4 + j)];
        sh[j] = stats[2 * (q * 4 + j) + 1];
    }
    float a0 = 0, a1 = 0, a2 = 0, a3 = 0;
    #pragma unroll
    for (int dx = 0; dx < 2; dx++)
        #pragma unroll
        for (int dy = 0; dy < 2; dy++)
            #pragma unroll
            for (int dz = 0; dz < 2; dz++) {
                int idx = (xx[dx] * RR + yy[dy]) * RR + zz[dz];
                float wt = wx[dx] * wy[dy] * wz[dz];
                float4 v = *(const float4*)&gcl[((size_t)b * R3 + idx) * 64 + q * 4];
                float u0 = v.x * sc[0] + sh[0]; u0 = u0 > 0 ? u0 : 0.1f * u0;
                float u1 = v.y * sc[1] + sh[1]; u1 = u1 > 0 ? u1 : 0.1f * u1;
                float u2 = v.z * sc[2] + sh[2]; u2 = u2 > 0 ? u2 : 0.1f * u2;
                float u3 = v.w * sc[3] + sh[3]; u3 = u3 > 0 ? u3 : 0.1f * u3;
                a0 += wt * u0; a1 += wt * u1; a2 += wt * u2; a3 += wt * u3;
            }
    out[((size_t)(b * 64 + q * 4 + 0)) * NN + n] = a0;
    out[((size_t)(b * 64 + q * 4 + 1)) * NN + n] = a1;
    out[((size_t)(b * 64 + q * 4 + 2)) * NN + n] = a2;
    out[((size_t)(b * 64 + q * 4 + 3)) * NN + n] = a3;
}

// ---------------- fuzzy attention (MFMA), 4 m-chunks ----------------
__global__ __launch_bounds__(256) void k_fuzzym(const float* __restrict__ coords,
                                                const ushort_t* __restrict__ featb,
                                                float* __restrict__ pnum,
                                                float* __restrict__ pden) {
    __shared__ float cm[3][1024];
    int b = blockIdx.z, mc = blockIdx.y, nt = blockIdx.x;
    int tid = threadIdx.x;
    int w = tid >> 6, lane = tid & 63, l15 = lane & 15, l4 = lane >> 4;
    int m0 = mc * 1024;

    for (int i = tid; i < 1024; i += 256) {
        float a0 = coords[((size_t)b * 3 + 0) * NN + m0 + i];
        float a1 = coords[((size_t)b * 3 + 1) * NN + m0 + i];
        float a2 = coords[((size_t)b * 3 + 2) * NN + m0 + i];
        float inv = 1.0f / fmaxf(sqrtf(a0 * a0 + a1 * a1 + a2 * a2), 1e-12f);
        cm[0][i] = a0 * inv; cm[1][i] = a1 * inv; cm[2][i] = a2 * inv;
    }

    int n = nt * 64 + w * 16 + l15;
    float q0 = coords[((size_t)b * 3 + 0) * NN + n];
    float q1 = coords[((size_t)b * 3 + 1) * NN + n];
    float q2 = coords[((size_t)b * 3 + 2) * NN + n];
    float qi = 10.0f / fmaxf(sqrtf(q0 * q0 + q1 * q1 + q2 * q2), 1e-12f);
    q0 *= qi; q1 *= qi; q2 *= qi;

    const ushort_t* fb = featb + (size_t)b * 64 * NN + m0;
    v4f acc[4];
    #pragma unroll
    for (int cb = 0; cb < 4; cb++) acc[cb] = (v4f){0.0f, 0.0f, 0.0f, 0.0f};
    float den = 0.0f;

    __syncthreads();
    #pragma unroll 2
    for (int t = 0; t < 32; t++) {
        int mo = t * 32 + l4 * 8;
        float e[8];
        #pragma unroll
        for (int jj = 0; jj < 2; jj++) {
            float4 x0 = *(const float4*)&cm[0][mo + jj * 4];
            float4 x1 = *(const float4*)&cm[1][mo + jj * 4];
            float4 x2 = *(const float4*)&cm[2][mo + jj * 4];
            e[jj * 4 + 0] = __expf(q0 * x0.x + q1 * x1.x + q2 * x2.x);
            e[jj * 4 + 1] = __expf(q0 * x0.y + q1 * x1.y + q2 * x2.y);
            e[jj * 4 + 2] = __expf(q0 * x0.z + q1 * x1.z + q2 * x2.z);
            e[jj * 4 + 3] = __expf(q0 * x0.w + q1 * x1.w + q2 * x2.w);
        }
        den += ((e[0] + e[1]) + (e[2] + e[3])) + ((e[4] + e[5]) + (e[6] + e[7]));
        union { __hip_bfloat162 h[4]; v8s v; } pk;
        pk.h[0] = __float22bfloat162_rn(make_float2(e[0], e[1]));
        pk.h[1] = __float22bfloat162_rn(make_float2(e[2], e[3]));
        pk.h[2] = __float22bfloat162_rn(make_float2(e[4], e[5]));
        pk.h[3] = __float22bfloat162_rn(make_float2(e[6], e[7]));
        #pragma unroll
        for (int cb = 0; cb < 4; cb++) {
            v8s A = *(const v8s*)(fb + (size_t)(cb * 16 + l15) * NN + mo);
            acc[cb] = __builtin_amdgcn_mfma_f32_16x16x32_bf16(A, pk.v, acc[cb], 0, 0, 0);
        }
    }

    den += __shfl_xor(den, 16);
    den += __shfl_xor(den, 32);

    size_t obase = ((size_t)(b * 4 + mc)) * 64 * NN;
    #pragma unroll
    for (int cb = 0; cb < 4; cb++)
        #pragma unroll
        for (int r = 0; r < 4; r++)
            pnum[obase + (size_t)(cb * 16 + l4 * 4 + r) * NN + n] = acc[cb][r];
    if (l4 == 0) pden[((size_t)(b * 4 + mc)) * NN + n] = den;
}

__global__ void k_combine2(const float* __restrict__ pnum, const float* __restrict__ pden,
                           float* __restrict__ fzf) {
    int i = blockIdx.x * 256 + threadIdx.x;
    int b = i >> 18, c = (i >> 12) & 63, n = i & 4095;
    float num = 0, den = 0;
    #pragma unroll
    for (int ch = 0; ch < 4; ch++) {
        num += pnum[((size_t)(b * 4 + ch) * 64 + c) * NN + n];
        den += pden[((size_t)(b * 4 + ch)) * NN + n];
    }
    fzf[((size_t)(b * 64 + c)) * NN + n] = num / den;
}

// ---------------- 1x1 convs ----------------
// single input + fused BN-stats epilogue (point branch)
__global__ __launch_bounds__(256) void k_1x1s(const float* __restrict__ in,
                                              const float* __restrict__ w,
                                              const float* __restrict__ bias,
                                              float* __restrict__ out,
                                              float* __restrict__ accs) {
    __shared__ float lw[64 * 16];
    int b = blockIdx.z, ob = blockIdx.y;
    int n = blockIdx.x * 64 + (threadIdx.x & 63);
    int og = threadIdx.x >> 6;
    for (int i = threadIdx.x; i < 1024; i += 256) {
        int c = i >> 4, o = i & 15;
        lw[c * 16 + o] = w[(size_t)(ob * 16 + o) * 64 + c];
    }
    __syncthreads();
    float acc[4] = {0, 0, 0, 0};
    const float* src = in + (size_t)b * 64 * NN + n;
    #pragma unroll 8
    for (int c = 0; c < 64; c++) {
        float x = src[(size_t)c * NN];
        float4 wv = *(const float4*)&lw[c * 16 + og * 4];
        acc[0] += x * wv.x; acc[1] += x * wv.y;
        acc[2] += x * wv.z; acc[3] += x * wv.w;
    }
    float s[4], q[4];
    #pragma unroll
    for (int j = 0; j < 4; j++) {
        float v = acc[j] + bias[ob * 16 + og * 4 + j];
        out[((size_t)(b * 64 + ob * 16 + og * 4 + j)) * NN + n] = v;
        s[j] = v; q[j] = v * v;
    }
    #pragma unroll
    for (int off = 1; off < 64; off <<= 1)
        #pragma unroll
        for (int j = 0; j < 4; j++) {
            s[j] += __shfl_xor(s[j], off);
            q[j] += __shfl_xor(q[j], off);
        }
    if ((threadIdx.x & 63) == 0)
        #pragma unroll
        for (int j = 0; j < 4; j++) {
            atomicAdd(&accs[2 * (ob * 16 + og * 4 + j)], s[j]);
            atomicAdd(&accs[2 * (ob * 16 + og * 4 + j) + 1], q[j]);
        }
}

// plain single input (fuzzy proj)
__global__ __launch_bounds__(256) void k_1x1p(const float* __restrict__ in,
                                              const float* __restrict__ w,
                                              const float* __restrict__ bias,
                                              float* __restrict__ out) {
    __shared__ float lw[64 * 16];
    int b = blockIdx.z, ob = blockIdx.y;
    int n = blockIdx.x * 64 + (threadIdx.x & 63);
    int og = threadIdx.x >> 6;
    for (int i = threadIdx.x; i < 1024; i += 256) {
        int c = i >> 4, o = i & 15;
        lw[c * 16 + o] = w[(size_t)(ob * 16 + o) * 64 + c];
    }
    __syncthreads();
    float acc[4] = {0, 0, 0, 0};
    const float* src = in + (size_t)b * 64 * NN + n;
    #pragma unroll 8
    for (int c = 0; c < 64; c++) {
        float x = src[(size_t)c * NN];
        float4 wv = *(const float4*)&lw[c * 16 + og * 4];
        acc[0] += x * wv.x; acc[1] += x * wv.y;
        acc[2] += x * wv.z; acc[3] += x * wv.w;
    }
    #pragma unroll
    for (int j = 0; j < 4; j++)
        out[((size_t)(b * 64 + ob * 16 + og * 4 + j)) * NN + n] = acc[j] + bias[ob * 16 + og * 4 + j];
}

// fusion: segA plain, segB with on-the-fly BN+relu, segC plain; fused stats epilogue
__global__ __launch_bounds__(256) void k_1x1f(const float* __restrict__ inA,
                                              const float* __restrict__ inB,
                                              const float* __restrict__ inC,
                                              const float* __restrict__ bnB,
                                              const float* __restrict__ w,
                                              const float* __restrict__ bias,
                                              float* __restrict__ out,
                                              float* __restrict__ accs) {
    __shared__ float lw[192 * 16];
    int b = blockIdx.z, ob = blockIdx.y;
    int n = blockIdx.x * 64 + (threadIdx.x & 63);
    int og = threadIdx.x >> 6;
    for (int i = threadIdx.x; i < 192 * 16; i += 256) {
        int c = i >> 4, o = i & 15;
        lw[c * 16 + o] = w[(size_t)(ob * 16 + o) * 192 + c];
    }
    __syncthreads();
    float acc[4] = {0, 0, 0, 0};
    const float* srcA = inA + (size_t)b * 64 * NN + n;
    const float* srcB = inB + (size_t)b * 64 * NN + n;
    const float* srcC = inC + (size_t)b * 64 * NN + n;
    #pragma unroll 8
    for (int c = 0; c < 64; c++) {
        float x = srcA[(size_t)c * NN];
        float4 wv = *(const float4*)&lw[c * 16 + og * 4];
        acc[0] += x * wv.x; acc[1] += x * wv.y;
        acc[2] += x * wv.z; acc[3] += x * wv.w;
    }
    #pragma unroll 8
    for (int c = 0; c < 64; c++) {
        float x = srcB[(size_t)c * NN];
        x = fmaxf(x * bnB[2 * c] + bnB[2 * c + 1], 0.0f);
        float4 wv = *(const float4*)&lw[(64 + c) * 16 + og * 4];
        acc[0] += x * wv.x; acc[1] += x * wv.y;
        acc[2] += x * wv.z; acc[3] += x * wv.w;
    }
    #pragma unroll 8
    for (int c = 0; c < 64; c++) {
        float x = srcC[(size_t)c * NN];
        float4 wv = *(const float4*)&lw[(128 + c) * 16 + og * 4];
        acc[0] += x * wv.x; acc[1] += x * wv.y;
        acc[2] += x * wv.z; acc[3] += x * wv.w;
    }
    float s[4], q[4];
    #pragma unroll
    for (int j = 0; j < 4; j++) {
        float v = acc[j] + bias[ob * 16 + og * 4 + j];
        out[((size_t)(b * 64 + ob * 16 + og * 4 + j)) * NN + n] = v;
        s[j] = v; q[j] = v * v;
    }
    #pragma unroll
    for (int off = 1; off < 64; off <<= 1)
        #pragma unroll
        for (int j = 0; j < 4; j++) {
            s[j] += __shfl_xor(s[j], off);
            q[j] += __shfl_xor(q[j], off);
        }
    if ((threadIdx.x & 63) == 0)
        #pragma unroll
        for (int j = 0; j < 4; j++) {
            atomicAdd(&accs[2 * (ob * 16 + og * 4 + j)], s[j]);
            atomicAdd(&accs[2 * (ob * 16 + og * 4 + j) + 1], q[j]);
        }
}

// ---------------- launcher ----------------
extern "C" void kernel_launch(void* const* d_in, const int* in_sizes, int n_in,
                              void* d_out, int out_size, void* d_ws, size_t ws_size,
                              hipStream_t stream) {
    const float* features = (const float*)d_in[0];
    const float* coords = (const float*)d_in[1];
    const float* w1 = (const float*)d_in[2];
    const float* g1 = (const float*)d_in[4];
    const float* be1 = (const float*)d_in[5];
    const float* w2 = (const float*)d_in[6];
    const float* g2 = (const float*)d_in[8];
    const float* be2 = (const float*)d_in[9];
    const float* wp = (const float*)d_in[10];
    const float* bp = (const float*)d_in[11];
    const float* gp = (const float*)d_in[12];
    const float* bep = (const float*)d_in[13];
    const float* wf = (const float*)d_in[14];
    const float* bf = (const float*)d_in[15];
    const float* wfu = (const float*)d_in[16];
    const float* bfu = (const float*)d_in[17];
    const float* gfu = (const float*)d_in[18];
    const float* befu = (const float*)d_in[19];

    float* ws = (float*)d_ws;
    float* nc = ws;                        // 49152
    int* vidx = (int*)(ws + 49152);        // 16384 ints
    float* cnt = ws + 65536;               // 131072 (pden overlays later)
    float* pden = cnt;
    float* gridA = ws + 196608;            // cf f32 scatter grid, then cl f32 conv out
    float* gridCL = gridA;
    float* gTpool = ws + 8585216;          // gT bf16 / pnum later
    ushort_t* gT = (ushort_t*)gTpool;
    float* pnum = gTpool;
    float* stats = ws + 16973824;          // 512 finalized (4 x 128)
    float* voxreg = ws + 16974336;         // wS1/wS2 until devox
    ushort_t* wS1 = (ushort_t*)voxreg;
    ushort_t* wS2 = wS1 + 110592;
    float* vox = voxreg;
    float* pt = ws + 18022912;
    float* fzf = ws + 19071488;
    float* fzc = ws + 20120064;
    float* fpre = ws + 21168640;           // featb overlays
    ushort_t* featb = (ushort_t*)fpre;
    float* accs = ws + 22217216;           // 512 float stat accumulators

    float* out = (float*)d_out;

    hipMemsetAsync(accs, 0, 512 * 4, stream);
    hipMemsetAsync(cnt, 0, (size_t)(131072 + 8388608) * 4, stream);

    // prep
    k_f2b<<<BB * 64 * NN / 8 / 256, 256, 0, stream>>>(features, featb);
    k_tws<<<432, 256, 0, stream>>>(w1, wS1);
    k_tws<<<432, 256, 0, stream>>>(w2, wS2);
    k_nc<<<BB, 256, 0, stream>>>(coords, nc, vidx);
    k_scatter<<<BB * NN / 64, 256, 0, stream>>>(features, vidx, gridA, cnt);
    k_avgT<<<dim3(512, BB), 256, 0, stream>>>(gridA, cnt, gT);

    // voxel branch
    k_convlds<<<512, 256, 0, stream>>>(gT, wS1, gridCL, accs);
    k_bnfin<<<1, 64, 0, stream>>>(accs, g1, be1, stats, 1, 1.0f / (BB * R3));
    k_bncast<<<BB * R3 * 64 / 8 / 256, 256, 0, stream>>>(gridCL, stats, 0.1f, gT);
    k_convlds<<<512, 256, 0, stream>>>(gT, wS2, gridCL, accs + 128);
    k_bnfin<<<1, 64, 0, stream>>>(accs + 128, g2, be2, stats + 128, 1, 1.0f / (BB * R3));
    k_devox2<<<dim3(NN / 16, BB), 256, 0, stream>>>(gridCL, stats + 128, nc, vox);

    // fuzzy branch
    k_fuzzym<<<dim3(64, 4, BB), 256, 0, stream>>>(coords, featb, pnum, pden);
    k_combine2<<<BB * 64 * NN / 256, 256, 0, stream>>>(pnum, pden, fzf);

    // point branch (stats fused)
    k_1x1s<<<dim3(NN / 64, 4, BB), 256, 0, stream>>>(features, wp, bp, pt, accs + 256);
    k_bnfin<<<1, 64, 0, stream>>>(accs + 256, gp, bep, stats + 256, 1, 1.0f / (BB * NN));

    // fuzzy proj
    k_1x1p<<<dim3(NN / 64, 4, BB), 256, 0, stream>>>(fzf, wf, bf, fzc);

    // fusion (applies pt BN on the fly; stats fused)
    k_1x1f<<<dim3(NN / 64, 4, BB), 256, 0, stream>>>(vox, pt, fzc, stats + 256, wfu, bfu,
                                                     fpre, accs + 384);
    k_bnfin<<<1, 64, 0, stream>>>(accs + 384, gfu, befu, stats + 384, 1, 1.0f / (BB * NN));
    k_bn_act<<<BB * 64 * NN / 4 / 256, 256, 0, stream>>>(fpre, stats + 384, out, 10, 0.0f);

    hipMemcpyAsync(out + (size_t)BB * CO * NN, coords, (size_t)BB * 3 * NN * 4,
                   hipMemcpyDeviceToDevice, stream);
}

// Round 8
// 444.936 us; speedup vs baseline: 1.1258x; 1.1258x over previous
//
#include <hip/hip_runtime.h>
#include <hip/hip_bf16.h>
#include <math.h>

#define RR 32
#define R3 32768
#define BB 4
#define CI 64
#define CO 64
#define NN 4096

typedef short v8s __attribute__((ext_vector_type(8)));
typedef float v4f __attribute__((ext_vector_type(4)));
typedef unsigned short ushort_t;

__device__ __forceinline__ unsigned short f2bf(float f) {
    unsigned int u = __float_as_uint(f);
    unsigned int r = (u + 0x7FFFu + ((u >> 16) & 1u)) >> 16;
    return (unsigned short)r;
}

__device__ __forceinline__ void gll16(const void* g, void* l) {
    __builtin_amdgcn_global_load_lds((const __attribute__((address_space(1))) unsigned int*)g,
                                     (__attribute__((address_space(3))) unsigned int*)l, 16, 0, 0);
}

// ---------------- block reduce helpers ----------------
__device__ __forceinline__ float blockReduceSum(float v, float* sm) {
    int tid = threadIdx.x;
    sm[tid] = v; __syncthreads();
    for (int off = 128; off > 0; off >>= 1) {
        if (tid < off) sm[tid] += sm[tid + off];
        __syncthreads();
    }
    float r = sm[0]; __syncthreads();
    return r;
}
__device__ __forceinline__ float blockReduceMax(float v, float* sm) {
    int tid = threadIdx.x;
    sm[tid] = v; __syncthreads();
    for (int off = 128; off > 0; off >>= 1) {
        if (tid < off) sm[tid] = fmaxf(sm[tid], sm[tid + off]);
        __syncthreads();
    }
    float r = sm[0]; __syncthreads();
    return r;
}

// ---------------- voxel coords ----------------
__global__ void k_nc(const float* __restrict__ coords, float* __restrict__ nc,
                     int* __restrict__ vidx) {
    int b = blockIdx.x, tid = threadIdx.x;
    __shared__ float sm[256];
    const float* cb = coords + (size_t)b * 3 * NN;
    float s0 = 0, s1 = 0, s2 = 0;
    for (int n = tid; n < NN; n += 256) {
        s0 += cb[n]; s1 += cb[NN + n]; s2 += cb[2 * NN + n];
    }
    float m0 = blockReduceSum(s0, sm) * (1.0f / NN);
    float m1 = blockReduceSum(s1, sm) * (1.0f / NN);
    float m2 = blockReduceSum(s2, sm) * (1.0f / NN);
    float mx = 0;
    for (int n = tid; n < NN; n += 256) {
        float dx = cb[n] - m0, dy = cb[NN + n] - m1, dz = cb[2 * NN + n] - m2;
        mx = fmaxf(mx, dx * dx + dy * dy + dz * dz);
    }
    mx = blockReduceMax(mx, sm);
    float denom = 2.0f * sqrtf(mx);
    float mean[3] = {m0, m1, m2};
    for (int n = tid; n < NN; n += 256) {
        int vi[3];
        #pragma unroll
        for (int ax = 0; ax < 3; ax++) {
            float x = (cb[ax * NN + n] - mean[ax]) / denom + 0.5f;
            x = x * RR;
            x = fminf(fmaxf(x, 0.0f), (float)(RR - 1));
            nc[((size_t)b * 3 + ax) * NN + n] = x;
            vi[ax] = (int)rintf(x);
        }
        vidx[b * NN + n] = (vi[0] * RR + vi[1]) * RR + vi[2];
    }
}

// ---------------- scatter-mean (channel-first) ----------------
__global__ void k_scatter(const float* __restrict__ feat, const int* __restrict__ vidx,
                          float* __restrict__ grid, float* __restrict__ cnt) {
    int tid = threadIdx.x;
    int pid = blockIdx.x * 64 + (tid & 63);
    int cg = tid >> 6;
    int b = pid / NN, n = pid % NN;
    int idx = vidx[pid];
    if (cg == 0) atomicAdd(&cnt[b * R3 + idx], 1.0f);
    #pragma unroll 4
    for (int c = cg * 16; c < cg * 16 + 16; c++)
        atomicAdd(&grid[((size_t)(b * CI + c)) * R3 + idx], feat[((size_t)(b * CI + c)) * NN + n]);
}

// ---------------- divide + transpose + bf16 cast: cf f32 -> cl bf16 ----------------
__global__ void k_avgT(const float* __restrict__ grid, const float* __restrict__ cnt,
                       ushort_t* __restrict__ gT) {
    __shared__ float ld[64][65];
    int b = blockIdx.y, s0 = blockIdx.x * 64, tid = threadIdx.x;
    int sl = tid & 63, cq = tid >> 6;
    const float* xb = grid + (size_t)b * 64 * R3;
    #pragma unroll
    for (int k = 0; k < 16; k++) {
        int c = cq * 16 + k;
        ld[sl][c] = xb[(size_t)c * R3 + s0 + sl];
    }
    __syncthreads();
    int v = tid >> 2, q = tid & 3;
    float inv = 1.0f / fmaxf(cnt[b * R3 + s0 + v], 1.0f);
    unsigned int pk[8];
    #pragma unroll
    for (int j = 0; j < 8; j++) {
        int c = q * 16 + j * 2;
        float a = ld[v][c] * inv, d = ld[v][c + 1] * inv;
        pk[j] = (unsigned int)f2bf(a) | ((unsigned int)f2bf(d) << 16);
    }
    uint4* op = (uint4*)(gT + ((size_t)(b * R3 + s0 + v)) * 64 + q * 16);
    op[0] = make_uint4(pk[0], pk[1], pk[2], pk[3]);
    op[1] = make_uint4(pk[4], pk[5], pk[6], pk[7]);
}

// ---------------- features f32 -> bf16 ----------------
__global__ void k_f2b(const float* __restrict__ x, ushort_t* __restrict__ o) {
    size_t i = (size_t)blockIdx.x * 256 + threadIdx.x;
    float4 a = ((const float4*)x)[i * 2];
    float4 b = ((const float4*)x)[i * 2 + 1];
    union { __hip_bfloat162 h[4]; uint4 u; } pk;
    pk.h[0] = __float22bfloat162_rn(make_float2(a.x, a.y));
    pk.h[1] = __float22bfloat162_rn(make_float2(a.z, a.w));
    pk.h[2] = __float22bfloat162_rn(make_float2(b.x, b.y));
    pk.h[3] = __float22bfloat162_rn(make_float2(b.z, b.w));
    ((uint4*)o)[i] = pk.u;
}

// ---------------- weight transform: wS[dzdy 9][cih 2][dx 3][co 64][cis 32] bf16 ----------------
__global__ void k_tws(const float* __restrict__ w, ushort_t* __restrict__ wS) {
    int i = blockIdx.x * 256 + threadIdx.x;  // 110592
    int cis = i & 31, co = (i >> 5) & 63;
    int dx = (i >> 11) % 3, cih = (i / 6144) & 1, dzdy = i / 12288;
    int k = dzdy * 3 + dx, ci = cih * 32 + cis;
    wS[i] = f2bf(w[((size_t)co * CI + ci) * 27 + k]);
}

// ---------------- weight fold/transposes for 1x1 kernels ----------------
// wpT[c][o] = wp[o][c]; wfuT rows 0..127 = wfu_A/B^T; rows 128..191 = (wfu_C . wf)^T;
// bC[o] = bfu[o] + sum_k wfu_C[o][k]*bf[k]
__global__ void k_fold(const float* __restrict__ wp, const float* __restrict__ wfu,
                       const float* __restrict__ wf, const float* __restrict__ bf,
                       const float* __restrict__ bfu,
                       float* __restrict__ wpT, float* __restrict__ wfuT,
                       float* __restrict__ bC) {
    int i = blockIdx.x * 256 + threadIdx.x;
    if (i < 4096) {
        int c = i >> 6, o = i & 63;
        wpT[c * 64 + o] = wp[o * 64 + c];
    } else if (i < 12288) {
        int j = i - 4096;
        int c = j >> 6, o = j & 63;
        wfuT[c * 64 + o] = wfu[(size_t)o * 192 + c];
    } else if (i < 16384) {
        int j = i - 12288;
        int c = j >> 6, o = j & 63;
        float s = 0;
        for (int k = 0; k < 64; k++)
            s += wfu[(size_t)o * 192 + 128 + k] * wf[(size_t)k * 64 + c];
        wfuT[(128 + c) * 64 + o] = s;
    } else if (i < 16448) {
        int o = i - 16384;
        float s = bfu[o];
        for (int k = 0; k < 64; k++)
            s += wfu[(size_t)o * 192 + 128 + k] * bf[k];
        bC[o] = s;
    }
}

// ---------------- BN + lrelu + bf16 cast (cl -> cl) ----------------
__global__ void k_bncast(const float* __restrict__ x, const float* __restrict__ stats,
                         float slope, ushort_t* __restrict__ o) {
    size_t i = (size_t)blockIdx.x * 256 + threadIdx.x;  // over B*R3*64/8
    int c0 = (int)((i * 8) & 63);
    float4 a = ((const float4*)x)[i * 2];
    float4 d = ((const float4*)x)[i * 2 + 1];
    float va[8] = {a.x, a.y, a.z, a.w, d.x, d.y, d.z, d.w};
    unsigned pk[4];
    #pragma unroll
    for (int j = 0; j < 4; j++) {
        float u0 = va[2 * j] * stats[2 * (c0 + 2 * j)] + stats[2 * (c0 + 2 * j) + 1];
        float u1 = va[2 * j + 1] * stats[2 * (c0 + 2 * j) + 2] + stats[2 * (c0 + 2 * j) + 3];
        u0 = u0 > 0 ? u0 : slope * u0;
        u1 = u1 > 0 ? u1 : slope * u1;
        pk[j] = (unsigned)f2bf(u0) | ((unsigned)f2bf(u1) << 16);
    }
    ((uint4*)o)[i] = make_uint4(pk[0], pk[1], pk[2], pk[3]);
}

// ---------------- LDS-staged MFMA conv3d 3x3x3, fused BN-stats epilogue ----------------
__global__ __launch_bounds__(256) void k_convlds(const ushort_t* __restrict__ gT,
                                                 const ushort_t* __restrict__ wS,
                                                 float* __restrict__ outCL,
                                                 float* __restrict__ accs) {
    __shared__ ushort_t lin[20480];     // 40960B input plane (also reused as stats buf)
    __shared__ ushort_t lw[2][6144];    // 2 x 12288B weights
    int bid = blockIdx.x;
    int wgid = (bid & 7) * 64 + (bid >> 3);
    int yt = wgid & 3, z0 = (wgid >> 2) & 31, b = wgid >> 7;
    int tid = threadIdx.x;
    int w = __builtin_amdgcn_readfirstlane(tid >> 6);
    int lane = tid & 63, l15 = lane & 15, l4 = lane >> 4;
    int y0 = yt * 8;
    const ushort_t* gTb = gT + (size_t)b * R3 * 64;

    int voxF[4];
    #pragma unroll
    for (int f = 0; f < 4; f++)
        voxF[f] = (w * 2 + (f >> 1)) * 32 + (f & 1) * 16 + l15 - 1;
    bool xlo_ok = (l15 != 0), xhi_ok = (l15 != 15);

    const v8s vzero = {};
    v4f acc[4][4];
    #pragma unroll
    for (int m = 0; m < 4; m++)
        #pragma unroll
        for (int f = 0; f < 4; f++)
            acc[m][f] = (v4f){0.0f, 0.0f, 0.0f, 0.0f};

#define WSTAGE(s)                                                              \
    do {                                                                       \
        const ushort_t* _src = wS + (size_t)(s) * 6144;                        \
        ushort_t* _dst = lw[(s) & 1];                                          \
        _Pragma("unroll") for (int _i = 0; _i < 3; _i++) {                     \
            int _p = _i * 256 + w * 64;                                        \
            gll16(_src + (size_t)(_p + lane) * 8, _dst + (size_t)_p * 8);      \
        }                                                                      \
    } while (0)

#define ISTAGE(dz)                                                             \
    do {                                                                       \
        int _zp = z0 - 1 + (dz);                                               \
        if (_zp < 0 || _zp > 31) {                                             \
            for (int _q = 0; _q < 10; _q++)                                    \
                *(v8s*)&lin[(size_t)(w * 640 + _q * 64 + lane) * 8] = vzero;   \
        } else {                                                               \
            if (yt == 0) *(v8s*)&lin[(size_t)tid * 8] = vzero;                 \
            if (yt == 3) *(v8s*)&lin[(size_t)(2304 + tid) * 8] = vzero;        \
            const ushort_t* _pb = gTb + ((size_t)_zp * 1024 + (size_t)(y0 - 1) * 32) * 64; \
            int _g0 = (yt == 0) ? 256 : 0;                                     \
            int _nc = 10 - (yt == 0) - (yt == 3);                              \
            for (int _i = 0; _i < _nc; _i++) {                                 \
                int _pbase = _g0 + _i * 256 + w * 64;                          \
                int _p = _pbase + lane;                                        \
                int _vx = _p >> 3, _js = _p & 7;                               \
                int _sg = _vx * 8 + (_js ^ (_vx & 7));                         \
                gll16(_pb + (size_t)_sg * 8, lin + (size_t)_pbase * 8);        \
            }                                                                  \
        }                                                                      \
    } while (0)

    WSTAGE(0);
    for (int s = 0; s < 18; s++) {
        int dy = (s / 2) % 3, cih = s & 1;
        asm volatile("s_barrier" ::: "memory");
        if ((s % 6) == 0) ISTAGE(s / 6);
        if (s + 1 < 18) WSTAGE(s + 1);
        if (s + 1 < 18) asm volatile("s_waitcnt vmcnt(3) lgkmcnt(0)" ::: "memory");
        else            asm volatile("s_waitcnt vmcnt(0) lgkmcnt(0)" ::: "memory");
        asm volatile("s_barrier" ::: "memory");

        const ushort_t* lwb = lw[s & 1];
        #pragma unroll
        for (int dx = 0; dx < 3; dx++) {
            v8s Bf[4];
            #pragma unroll
            for (int f = 0; f < 4; f++) {
                int vox = voxF[f] + dy * 32 + dx;
                int g = vox * 8 + ((cih * 4 + l4) ^ (vox & 7));
                int bix = g * 16;
                bix = bix < 0 ? 0 : bix;
                v8s vb = *(const v8s*)((const char*)lin + bix);
                bool ok = (dx == 0 && (f & 1) == 0) ? xlo_ok :
                          (dx == 2 && (f & 1) == 1) ? xhi_ok : true;
                Bf[f] = ok ? vb : vzero;
            }
            const ushort_t* ap = lwb + dx * 2048 + l15 * 32 + l4 * 8;
            #pragma unroll
            for (int m = 0; m < 4; m++) {
                v8s Af = *(const v8s*)(ap + m * 512);
                #pragma unroll
                for (int f = 0; f < 4; f++)
                    acc[m][f] = __builtin_amdgcn_mfma_f32_16x16x32_bf16(Af, Bf[f], acc[m][f], 0, 0, 0);
            }
        }
    }

    // channel-last f4 stores
    #pragma unroll
    for (int m = 0; m < 4; m++) {
        #pragma unroll
        for (int f = 0; f < 4; f++) {
            int y = y0 + w * 2 + (f >> 1);
            int x = (f & 1) * 16 + l15;
            float4 o = make_float4(acc[m][f][0], acc[m][f][1], acc[m][f][2], acc[m][f][3]);
            *(float4*)&outCL[((size_t)b * R3 + z0 * 1024 + y * 32 + x) * 64 + m * 16 + l4 * 4] = o;
        }
    }

    // ---- fused BN-stats: per-block sum/sumsq per co -> atomics ----
    __syncthreads();
    float* sbuf = (float*)lin;
    #pragma unroll
    for (int m = 0; m < 4; m++)
        #pragma unroll
        for (int r = 0; r < 4; r++) {
            float s = 0, q = 0;
            #pragma unroll
            for (int f = 0; f < 4; f++) {
                float v = acc[m][f][r];
                s += v; q += v * v;
            }
            sbuf[tid * 32 + (m * 4 + r) * 2] = s;
            sbuf[tid * 32 + (m * 4 + r) * 2 + 1] = q;
        }
    __syncthreads();
    if (tid < 128) {
        int co = tid >> 1, val = tid & 1;
        int m = co >> 4, cl4 = (co >> 2) & 3, r = co & 3;
        float a = 0;
        for (int w2 = 0; w2 < 4; w2++)
            for (int l = 0; l < 16; l++)
                a += sbuf[(w2 * 64 + cl4 * 16 + l) * 32 + (m * 4 + r) * 2 + val];
        atomicAdd(&accs[2 * co + val], a);
    }
#undef WSTAGE
#undef ISTAGE
}

__global__ void k_bnfin(const float* __restrict__ pst, const float* __restrict__ g,
                        const float* __restrict__ be, float* __restrict__ stats,
                        int nb, float invcnt) {
    int c = threadIdx.x;
    float s = 0, q = 0;
    for (int b = 0; b < nb; b++) {
        s += pst[(c * nb + b) * 2];
        q += pst[(c * nb + b) * 2 + 1];
    }
    float mean = s * invcnt;
    float var = q * invcnt - mean * mean;
    float sc = g[c] * rsqrtf(var + 1e-4f);
    stats[2 * c] = sc;
    stats[2 * c + 1] = be[c] - mean * sc;
}

__global__ void k_bn_act(const float* __restrict__ x, const float* __restrict__ stats,
                         float* __restrict__ out, int shift, float slope) {
    size_t i = (size_t)blockIdx.x * 256 + threadIdx.x;
    int c = (int)((i >> shift) & 63);
    float sc = stats[2 * c], sh = stats[2 * c + 1];
    float4 v = ((const float4*)x)[i];
    v.x = v.x * sc + sh; v.y = v.y * sc + sh; v.z = v.z * sc + sh; v.w = v.w * sc + sh;
    v.x = v.x > 0 ? v.x : slope * v.x;
    v.y = v.y > 0 ? v.y : slope * v.y;
    v.z = v.z > 0 ? v.z : slope * v.z;
    v.w = v.w > 0 ? v.w : slope * v.w;
    ((float4*)out)[i] = v;
}

// ---------------- devoxelize, fused BN+lrelu, channel-last gather ----------------
__global__ void k_devox2(const float* __restrict__ gcl, const float* __restrict__ stats,
                         const float* __restrict__ nc, float* __restrict__ out) {
    int b = blockIdx.y;
    int tid = threadIdx.x, p = tid >> 4, q = tid & 15;
    int n = blockIdx.x * 16 + p;
    float x = nc[((size_t)b * 3 + 0) * NN + n];
    float y = nc[((size_t)b * 3 + 1) * NN + n];
    float z = nc[((size_t)b * 3 + 2) * NN + n];
    float fx = floorf(x), fy = floorf(y), fz = floorf(z);
    int lx = (int)fx, ly = (int)fy, lz = (int)fz;
    int hx = min(lx + 1, RR - 1), hy = min(ly + 1, RR - 1), hz = min(lz + 1, RR - 1);
    float frx = x - fx, fry = y - fy, frz = z - fz;
    int xx[2] = {lx, hx}, yy[2] = {ly, hy}, zz[2] = {lz, hz};
    float wx[2] = {1.0f - frx, frx}, wy[2] = {1.0f - fry, fry}, wz[2] = {1.0f - frz, frz};
    float sc[4], sh[4];
    #pragma unroll
    for (int j = 0; j < 4; j++) {
        sc[j] = stats[2 * (q * 4 + j)];
        sh[j] = stats[2 * (q * 4 + j) + 1];
    }
    float a0 = 0, a1 = 0, a2 = 0, a3 = 0;
    #pragma unroll
    for (int dx = 0; dx < 2; dx++)
        #pragma unroll
        for (int dy = 0; dy < 2; dy++)
            #pragma unroll
            for (int dz = 0; dz < 2; dz++) {
                int idx = (xx[dx] * RR + yy[dy]) * RR + zz[dz];
                float wt = wx[dx] * wy[dy] * wz[dz];
                float4 v = *(const float4*)&gcl[((size_t)b * R3 + idx) * 64 + q * 4];
                float u0 = v.x * sc[0] + sh[0]; u0 = u0 > 0 ? u0 : 0.1f * u0;
                float u1 = v.y * sc[1] + sh[1]; u1 = u1 > 0 ? u1 : 0.1f * u1;
                float u2 = v.z * sc[2] + sh[2]; u2 = u2 > 0 ? u2 : 0.1f * u2;
                float u3 = v.w * sc[3] + sh[3]; u3 = u3 > 0 ? u3 : 0.1f * u3;
                a0 += wt * u0; a1 += wt * u1; a2 += wt * u2; a3 += wt * u3;
            }
    out[((size_t)(b * 64 + q * 4 + 0)) * NN + n] = a0;
    out[((size_t)(b * 64 + q * 4 + 1)) * NN + n] = a1;
    out[((size_t)(b * 64 + q * 4 + 2)) * NN + n] = a2;
    out[((size_t)(b * 64 + q * 4 + 3)) * NN + n] = a3;
}

// ---------------- fuzzy attention (MFMA), 4 m-chunks ----------------
__global__ __launch_bounds__(256) void k_fuzzym(const float* __restrict__ coords,
                                                const ushort_t* __restrict__ featb,
                                                float* __restrict__ pnum,
                                                float* __restrict__ pden) {
    __shared__ float cm[3][1024];
    int b = blockIdx.z, mc = blockIdx.y, nt = blockIdx.x;
    int tid = threadIdx.x;
    int w = tid >> 6, lane = tid & 63, l15 = lane & 15, l4 = lane >> 4;
    int m0 = mc * 1024;

    for (int i = tid; i < 1024; i += 256) {
        float a0 = coords[((size_t)b * 3 + 0) * NN + m0 + i];
        float a1 = coords[((size_t)b * 3 + 1) * NN + m0 + i];
        float a2 = coords[((size_t)b * 3 + 2) * NN + m0 + i];
        float inv = 1.0f / fmaxf(sqrtf(a0 * a0 + a1 * a1 + a2 * a2), 1e-12f);
        cm[0][i] = a0 * inv; cm[1][i] = a1 * inv; cm[2][i] = a2 * inv;
    }

    int n = nt * 64 + w * 16 + l15;
    float q0 = coords[((size_t)b * 3 + 0) * NN + n];
    float q1 = coords[((size_t)b * 3 + 1) * NN + n];
    float q2 = coords[((size_t)b * 3 + 2) * NN + n];
    float qi = 10.0f / fmaxf(sqrtf(q0 * q0 + q1 * q1 + q2 * q2), 1e-12f);
    q0 *= qi; q1 *= qi; q2 *= qi;

    const ushort_t* fb = featb + (size_t)b * 64 * NN + m0;
    v4f acc[4];
    #pragma unroll
    for (int cb = 0; cb < 4; cb++) acc[cb] = (v4f){0.0f, 0.0f, 0.0f, 0.0f};
    float den = 0.0f;

    __syncthreads();
    #pragma unroll 2
    for (int t = 0; t < 32; t++) {
        int mo = t * 32 + l4 * 8;
        float e[8];
        #pragma unroll
        for (int jj = 0; jj < 2; jj++) {
            float4 x0 = *(const float4*)&cm[0][mo + jj * 4];
            float4 x1 = *(const float4*)&cm[1][mo + jj * 4];
            float4 x2 = *(const float4*)&cm[2][mo + jj * 4];
            e[jj * 4 + 0] = __expf(q0 * x0.x + q1 * x1.x + q2 * x2.x);
            e[jj * 4 + 1] = __expf(q0 * x0.y + q1 * x1.y + q2 * x2.y);
            e[jj * 4 + 2] = __expf(q0 * x0.z + q1 * x1.z + q2 * x2.z);
            e[jj * 4 + 3] = __expf(q0 * x0.w + q1 * x1.w + q2 * x2.w);
        }
        den += ((e[0] + e[1]) + (e[2] + e[3])) + ((e[4] + e[5]) + (e[6] + e[7]));
        union { __hip_bfloat162 h[4]; v8s v; } pk;
        pk.h[0] = __float22bfloat162_rn(make_float2(e[0], e[1]));
        pk.h[1] = __float22bfloat162_rn(make_float2(e[2], e[3]));
        pk.h[2] = __float22bfloat162_rn(make_float2(e[4], e[5]));
        pk.h[3] = __float22bfloat162_rn(make_float2(e[6], e[7]));
        #pragma unroll
        for (int cb = 0; cb < 4; cb++) {
            v8s A = *(const v8s*)(fb + (size_t)(cb * 16 + l15) * NN + mo);
            acc[cb] = __builtin_amdgcn_mfma_f32_16x16x32_bf16(A, pk.v, acc[cb], 0, 0, 0);
        }
    }

    den += __shfl_xor(den, 16);
    den += __shfl_xor(den, 32);

    size_t obase = ((size_t)(b * 4 + mc)) * 64 * NN;
    #pragma unroll
    for (int cb = 0; cb < 4; cb++)
        #pragma unroll
        for (int r = 0; r < 4; r++)
            pnum[obase + (size_t)(cb * 16 + l4 * 4 + r) * NN + n] = acc[cb][r];
    if (l4 == 0) pden[((size_t)(b * 4 + mc)) * NN + n] = den;
}

__global__ void k_combine2(const float* __restrict__ pnum, const float* __restrict__ pden,
                           float* __restrict__ fzf) {
    int i = blockIdx.x * 256 + threadIdx.x;
    int b = i >> 18, c = (i >> 12) & 63, n = i & 4095;
    float num = 0, den = 0;
    #pragma unroll
    for (int ch = 0; ch < 4; ch++) {
        num += pnum[((size_t)(b * 4 + ch) * 64 + c) * NN + n];
        den += pden[((size_t)(b * 4 + ch)) * NN + n];
    }
    fzf[((size_t)(b * 64 + c)) * NN + n] = num / den;
}

// ---------------- 1x1 convs, f4-vectorized (thread = 4n x 4co) ----------------
// point branch: out = wp.features + bp, fused BN-stats
__global__ __launch_bounds__(256) void k_1x1s(const float* __restrict__ in,
                                              const float* __restrict__ wT,
                                              const float* __restrict__ bias,
                                              float* __restrict__ out,
                                              float* __restrict__ accs) {
    int b = blockIdx.y;
    int tid = threadIdx.x;
    int q = tid & 15, o = tid >> 4;
    int n = blockIdx.x * 64 + q * 4;
    const float* src = in + (size_t)b * 64 * NN + n;
    float acc[4][4] = {};
    #pragma unroll 8
    for (int c = 0; c < 64; c++) {
        float4 x = *(const float4*)&src[(size_t)c * NN];
        float4 wv = *(const float4*)&wT[c * 64 + o * 4];
        float xs[4] = {x.x, x.y, x.z, x.w};
        float wa[4] = {wv.x, wv.y, wv.z, wv.w};
        #pragma unroll
        for (int j = 0; j < 4; j++)
            #pragma unroll
            for (int v = 0; v < 4; v++)
                acc[j][v] += xs[v] * wa[j];
    }
    float s[4], qq[4];
    #pragma unroll
    for (int j = 0; j < 4; j++) {
        float bv = bias[o * 4 + j];
        float4 ov;
        float* op = (float*)&ov;
        s[j] = 0; qq[j] = 0;
        #pragma unroll
        for (int v = 0; v < 4; v++) {
            float val = acc[j][v] + bv;
            op[v] = val;
            s[j] += val; qq[j] += val * val;
        }
        *(float4*)&out[((size_t)(b * 64 + o * 4 + j)) * NN + n] = ov;
    }
    #pragma unroll
    for (int off = 1; off < 16; off <<= 1)
        #pragma unroll
        for (int j = 0; j < 4; j++) {
            s[j] += __shfl_xor(s[j], off);
            qq[j] += __shfl_xor(qq[j], off);
        }
    if (q == 0)
        #pragma unroll
        for (int j = 0; j < 4; j++) {
            atomicAdd(&accs[2 * (o * 4 + j)], s[j]);
            atomicAdd(&accs[2 * (o * 4 + j) + 1], qq[j]);
        }
}

// fusion: wfuT rows 0..63 (vox), 64..127 (pt, BN+relu on the fly), 128..191 (folded fzf)
__global__ __launch_bounds__(256) void k_1x1f(const float* __restrict__ vox,
                                              const float* __restrict__ pt,
                                              const float* __restrict__ fzf,
                                              const float* __restrict__ bnB,
                                              const float* __restrict__ wfuT,
                                              const float* __restrict__ bC,
                                              float* __restrict__ out,
                                              float* __restrict__ accs) {
    int b = blockIdx.y;
    int tid = threadIdx.x;
    int q = tid & 15, o = tid >> 4;
    int n = blockIdx.x * 64 + q * 4;
    const float* srcA = vox + (size_t)b * 64 * NN + n;
    const float* srcB = pt + (size_t)b * 64 * NN + n;
    const float* srcC = fzf + (size_t)b * 64 * NN + n;
    float acc[4][4] = {};
    #pragma unroll 8
    for (int c = 0; c < 64; c++) {
        float4 x = *(const float4*)&srcA[(size_t)c * NN];
        float4 wv = *(const float4*)&wfuT[c * 64 + o * 4];
        float xs[4] = {x.x, x.y, x.z, x.w};
        float wa[4] = {wv.x, wv.y, wv.z, wv.w};
        #pragma unroll
        for (int j = 0; j < 4; j++)
            #pragma unroll
            for (int v = 0; v < 4; v++)
                acc[j][v] += xs[v] * wa[j];
    }
    #pragma unroll 8
    for (int c = 0; c < 64; c++) {
        float4 x = *(const float4*)&srcB[(size_t)c * NN];
        float sc = bnB[2 * c], sh = bnB[2 * c + 1];
        float4 wv = *(const float4*)&wfuT[(64 + c) * 64 + o * 4];
        float xs[4] = {fmaxf(x.x * sc + sh, 0.0f), fmaxf(x.y * sc + sh, 0.0f),
                       fmaxf(x.z * sc + sh, 0.0f), fmaxf(x.w * sc + sh, 0.0f)};
        float wa[4] = {wv.x, wv.y, wv.z, wv.w};
        #pragma unroll
        for (int j = 0; j < 4; j++)
            #pragma unroll
            for (int v = 0; v < 4; v++)
                acc[j][v] += xs[v] * wa[j];
    }
    #pragma unroll 8
    for (int c = 0; c < 64; c++) {
        float4 x = *(const float4*)&srcC[(size_t)c * NN];
        float4 wv = *(const float4*)&wfuT[(128 + c) * 64 + o * 4];
        float xs[4] = {x.x, x.y, x.z, x.w};
        float wa[4] = {wv.x, wv.y, wv.z, wv.w};
        #pragma unroll
        for (int j = 0; j < 4; j++)
            #pragma unroll
            for (int v = 0; v < 4; v++)
                acc[j][v] += xs[v] * wa[j];
    }
    float s[4], qq[4];
    #pragma unroll
    for (int j = 0; j < 4; j++) {
        float bv = bC[o * 4 + j];
        float4 ov;
        float* op = (float*)&ov;
        s[j] = 0; qq[j] = 0;
        #pragma unroll
        for (int v = 0; v < 4; v++) {
            float val = acc[j][v] + bv;
            op[v] = val;
            s[j] += val; qq[j] += val * val;
        }
        *(float4*)&out[((size_t)(b * 64 + o * 4 + j)) * NN + n] = ov;
    }
    #pragma unroll
    for (int off = 1; off < 16; off <<= 1)
        #pragma unroll
        for (int j = 0; j < 4; j++) {
            s[j] += __shfl_xor(s[j], off);
            qq[j] += __shfl_xor(qq[j], off);
        }
    if (q == 0)
        #pragma unroll
        for (int j = 0; j < 4; j++) {
            atomicAdd(&accs[2 * (o * 4 + j)], s[j]);
            atomicAdd(&accs[2 * (o * 4 + j) + 1], qq[j]);
        }
}

// ---------------- launcher ----------------
extern "C" void kernel_launch(void* const* d_in, const int* in_sizes, int n_in,
                              void* d_out, int out_size, void* d_ws, size_t ws_size,
                              hipStream_t stream) {
    const float* features = (const float*)d_in[0];
    const float* coords = (const float*)d_in[1];
    const float* w1 = (const float*)d_in[2];
    const float* g1 = (const float*)d_in[4];
    const float* be1 = (const float*)d_in[5];
    const float* w2 = (const float*)d_in[6];
    const float* g2 = (const float*)d_in[8];
    const float* be2 = (const float*)d_in[9];
    const float* wp = (const float*)d_in[10];
    const float* bp = (const float*)d_in[11];
    const float* gp = (const float*)d_in[12];
    const float* bep = (const float*)d_in[13];
    const float* wf = (const float*)d_in[14];
    const float* bf = (const float*)d_in[15];
    const float* wfu = (const float*)d_in[16];
    const float* bfu = (const float*)d_in[17];
    const float* gfu = (const float*)d_in[18];
    const float* befu = (const float*)d_in[19];

    float* ws = (float*)d_ws;
    float* nc = ws;                        // 49152
    int* vidx = (int*)(ws + 49152);        // 16384 ints
    float* cnt = ws + 65536;               // 131072 (pden overlays later)
    float* pden = cnt;
    float* gridA = ws + 196608;            // cf f32 scatter grid, then cl f32 conv out
    float* gridCL = gridA;
    float* gTpool = ws + 8585216;          // gT bf16 / pnum later
    ushort_t* gT = (ushort_t*)gTpool;
    float* pnum = gTpool;
    float* stats = ws + 16973824;          // 512 finalized (4 x 128)
    float* voxreg = ws + 16974336;         // wS1/wS2 until devox
    ushort_t* wS1 = (ushort_t*)voxreg;
    ushort_t* wS2 = wS1 + 110592;
    float* vox = voxreg;
    float* pt = ws + 18022912;
    float* fzf = ws + 19071488;
    float* wpT = ws + 20120064;            // 4096 (old fzc slot, now folded weights)
    float* wfuT = wpT + 4096;              // 12288
    float* bC = wfuT + 12288;              // 64
    float* fpre = ws + 21168640;           // featb overlays
    ushort_t* featb = (ushort_t*)fpre;
    float* accs = ws + 22217216;           // 512 float stat accumulators

    float* out = (float*)d_out;

    hipMemsetAsync(accs, 0, 512 * 4, stream);
    hipMemsetAsync(cnt, 0, (size_t)(131072 + 8388608) * 4, stream);

    // prep
    k_fold<<<65, 256, 0, stream>>>(wp, wfu, wf, bf, bfu, wpT, wfuT, bC);
    k_f2b<<<BB * 64 * NN / 8 / 256, 256, 0, stream>>>(features, featb);
    k_tws<<<432, 256, 0, stream>>>(w1, wS1);
    k_tws<<<432, 256, 0, stream>>>(w2, wS2);
    k_nc<<<BB, 256, 0, stream>>>(coords, nc, vidx);
    k_scatter<<<BB * NN / 64, 256, 0, stream>>>(features, vidx, gridA, cnt);
    k_avgT<<<dim3(512, BB), 256, 0, stream>>>(gridA, cnt, gT);

    // voxel branch
    k_convlds<<<512, 256, 0, stream>>>(gT, wS1, gridCL, accs);
    k_bnfin<<<1, 64, 0, stream>>>(accs, g1, be1, stats, 1, 1.0f / (BB * R3));
    k_bncast<<<BB * R3 * 64 / 8 / 256, 256, 0, stream>>>(gridCL, stats, 0.1f, gT);
    k_convlds<<<512, 256, 0, stream>>>(gT, wS2, gridCL, accs + 128);
    k_bnfin<<<1, 64, 0, stream>>>(accs + 128, g2, be2, stats + 128, 1, 1.0f / (BB * R3));
    k_devox2<<<dim3(NN / 16, BB), 256, 0, stream>>>(gridCL, stats + 128, nc, vox);

    // fuzzy branch
    k_fuzzym<<<dim3(64, 4, BB), 256, 0, stream>>>(coords, featb, pnum, pden);
    k_combine2<<<BB * 64 * NN / 256, 256, 0, stream>>>(pnum, pden, fzf);

    // point branch (stats fused)
    k_1x1s<<<dim3(NN / 64, BB), 256, 0, stream>>>(features, wpT, bp, pt, accs + 256);
    k_bnfin<<<1, 64, 0, stream>>>(accs + 256, gp, bep, stats + 256, 1, 1.0f / (BB * NN));

    // fusion (wf folded into wfuT segC; pt BN on the fly; stats fused)
    k_1x1f<<<dim3(NN / 64, BB), 256, 0, stream>>>(vox, pt, fzf, stats + 256, wfuT, bC,
                                                  fpre, accs + 384);
    k_bnfin<<<1, 64, 0, stream>>>(accs + 384, gfu, befu, stats + 384, 1, 1.0f / (BB * NN));
    k_bn_act<<<BB * 64 * NN / 4 / 256, 256, 0, stream>>>(fpre, stats + 384, out, 10, 0.0f);

    hipMemcpyAsync(out + (size_t)BB * CO * NN, coords, (size_t)BB * 3 * NN * 4,
                   hipMemcpyDeviceToDevice, stream);
}

// Round 9
// 320.352 us; speedup vs baseline: 1.5637x; 1.3889x over previous
//
#include <hip/hip_runtime.h>
#include <hip/hip_bf16.h>
#include <math.h>

#define RR 32
#define R3 32768
#define BB 4
#define CI 64
#define CO 64
#define NN 4096

typedef short v8s __attribute__((ext_vector_type(8)));
typedef float v4f __attribute__((ext_vector_type(4)));
typedef unsigned short ushort_t;

__device__ __forceinline__ unsigned short f2bf(float f) {
    unsigned int u = __float_as_uint(f);
    unsigned int r = (u + 0x7FFFu + ((u >> 16) & 1u)) >> 16;
    return (unsigned short)r;
}

__device__ __forceinline__ void gll16(const void* g, void* l) {
    __builtin_amdgcn_global_load_lds((const __attribute__((address_space(1))) unsigned int*)g,
                                     (__attribute__((address_space(3))) unsigned int*)l, 16, 0, 0);
}

// ---------------- block reduce helpers ----------------
__device__ __forceinline__ float blockReduceSum(float v, float* sm) {
    int tid = threadIdx.x;
    sm[tid] = v; __syncthreads();
    for (int off = 128; off > 0; off >>= 1) {
        if (tid < off) sm[tid] += sm[tid + off];
        __syncthreads();
    }
    float r = sm[0]; __syncthreads();
    return r;
}
__device__ __forceinline__ float blockReduceMax(float v, float* sm) {
    int tid = threadIdx.x;
    sm[tid] = v; __syncthreads();
    for (int off = 128; off > 0; off >>= 1) {
        if (tid < off) sm[tid] = fmaxf(sm[tid], sm[tid + off]);
        __syncthreads();
    }
    float r = sm[0]; __syncthreads();
    return r;
}

// ---------------- voxel coords ----------------
__global__ void k_nc(const float* __restrict__ coords, float* __restrict__ nc,
                     int* __restrict__ vidx) {
    int b = blockIdx.x, tid = threadIdx.x;
    __shared__ float sm[256];
    const float* cb = coords + (size_t)b * 3 * NN;
    float s0 = 0, s1 = 0, s2 = 0;
    for (int n = tid; n < NN; n += 256) {
        s0 += cb[n]; s1 += cb[NN + n]; s2 += cb[2 * NN + n];
    }
    float m0 = blockReduceSum(s0, sm) * (1.0f / NN);
    float m1 = blockReduceSum(s1, sm) * (1.0f / NN);
    float m2 = blockReduceSum(s2, sm) * (1.0f / NN);
    float mx = 0;
    for (int n = tid; n < NN; n += 256) {
        float dx = cb[n] - m0, dy = cb[NN + n] - m1, dz = cb[2 * NN + n] - m2;
        mx = fmaxf(mx, dx * dx + dy * dy + dz * dz);
    }
    mx = blockReduceMax(mx, sm);
    float denom = 2.0f * sqrtf(mx);
    float mean[3] = {m0, m1, m2};
    for (int n = tid; n < NN; n += 256) {
        int vi[3];
        #pragma unroll
        for (int ax = 0; ax < 3; ax++) {
            float x = (cb[ax * NN + n] - mean[ax]) / denom + 0.5f;
            x = x * RR;
            x = fminf(fmaxf(x, 0.0f), (float)(RR - 1));
            nc[((size_t)b * 3 + ax) * NN + n] = x;
            vi[ax] = (int)rintf(x);
        }
        vidx[b * NN + n] = (vi[0] * RR + vi[1]) * RR + vi[2];
    }
}

// ---------------- scatter-mean (channel-first) ----------------
__global__ void k_scatter(const float* __restrict__ feat, const int* __restrict__ vidx,
                          float* __restrict__ grid, float* __restrict__ cnt) {
    int tid = threadIdx.x;
    int pid = blockIdx.x * 64 + (tid & 63);
    int cg = tid >> 6;
    int b = pid / NN, n = pid % NN;
    int idx = vidx[pid];
    if (cg == 0) atomicAdd(&cnt[b * R3 + idx], 1.0f);
    #pragma unroll 4
    for (int c = cg * 16; c < cg * 16 + 16; c++)
        atomicAdd(&grid[((size_t)(b * CI + c)) * R3 + idx], feat[((size_t)(b * CI + c)) * NN + n]);
}

// ---------------- divide + transpose + bf16 cast: cf f32 -> cl bf16 ----------------
__global__ void k_avgT(const float* __restrict__ grid, const float* __restrict__ cnt,
                       ushort_t* __restrict__ gT) {
    __shared__ float ld[64][65];
    int b = blockIdx.y, s0 = blockIdx.x * 64, tid = threadIdx.x;
    int sl = tid & 63, cq = tid >> 6;
    const float* xb = grid + (size_t)b * 64 * R3;
    #pragma unroll
    for (int k = 0; k < 16; k++) {
        int c = cq * 16 + k;
        ld[sl][c] = xb[(size_t)c * R3 + s0 + sl];
    }
    __syncthreads();
    int v = tid >> 2, q = tid & 3;
    float inv = 1.0f / fmaxf(cnt[b * R3 + s0 + v], 1.0f);
    unsigned int pk[8];
    #pragma unroll
    for (int j = 0; j < 8; j++) {
        int c = q * 16 + j * 2;
        float a = ld[v][c] * inv, d = ld[v][c + 1] * inv;
        pk[j] = (unsigned int)f2bf(a) | ((unsigned int)f2bf(d) << 16);
    }
    uint4* op = (uint4*)(gT + ((size_t)(b * R3 + s0 + v)) * 64 + q * 16);
    op[0] = make_uint4(pk[0], pk[1], pk[2], pk[3]);
    op[1] = make_uint4(pk[4], pk[5], pk[6], pk[7]);
}

// ---------------- features f32 -> bf16 ----------------
__global__ void k_f2b(const float* __restrict__ x, ushort_t* __restrict__ o) {
    size_t i = (size_t)blockIdx.x * 256 + threadIdx.x;
    float4 a = ((const float4*)x)[i * 2];
    float4 b = ((const float4*)x)[i * 2 + 1];
    union { __hip_bfloat162 h[4]; uint4 u; } pk;
    pk.h[0] = __float22bfloat162_rn(make_float2(a.x, a.y));
    pk.h[1] = __float22bfloat162_rn(make_float2(a.z, a.w));
    pk.h[2] = __float22bfloat162_rn(make_float2(b.x, b.y));
    pk.h[3] = __float22bfloat162_rn(make_float2(b.z, b.w));
    ((uint4*)o)[i] = pk.u;
}

// ---------------- weight transform: wS[dzdy 9][cih 2][dx 3][co 64][cis 32] bf16 ----------------
__global__ void k_tws(const float* __restrict__ w, ushort_t* __restrict__ wS) {
    int i = blockIdx.x * 256 + threadIdx.x;  // 110592
    int cis = i & 31, co = (i >> 5) & 63;
    int dx = (i >> 11) % 3, cih = (i / 6144) & 1, dzdy = i / 12288;
    int k = dzdy * 3 + dx, ci = cih * 32 + cis;
    wS[i] = f2bf(w[((size_t)co * CI + ci) * 27 + k]);
}

// ---------------- weight fold/transposes for 1x1 kernels ----------------
__global__ void k_fold(const float* __restrict__ wp, const float* __restrict__ wfu,
                       const float* __restrict__ wf, const float* __restrict__ bf,
                       const float* __restrict__ bfu,
                       float* __restrict__ wpT, float* __restrict__ wfuT,
                       float* __restrict__ bC) {
    int i = blockIdx.x * 256 + threadIdx.x;
    if (i < 4096) {
        int c = i >> 6, o = i & 63;
        wpT[c * 64 + o] = wp[o * 64 + c];
    } else if (i < 12288) {
        int j = i - 4096;
        int c = j >> 6, o = j & 63;
        wfuT[c * 64 + o] = wfu[(size_t)o * 192 + c];
    } else if (i < 16384) {
        int j = i - 12288;
        int c = j >> 6, o = j & 63;
        float s = 0;
        for (int k = 0; k < 64; k++)
            s += wfu[(size_t)o * 192 + 128 + k] * wf[(size_t)k * 64 + c];
        wfuT[(128 + c) * 64 + o] = s;
    } else if (i < 16448) {
        int o = i - 16384;
        float s = bfu[o];
        for (int k = 0; k < 64; k++)
            s += wfu[(size_t)o * 192 + 128 + k] * bf[k];
        bC[o] = s;
    }
}

// ---------------- BN + lrelu + bf16 cast (cl -> cl) ----------------
__global__ void k_bncast(const float* __restrict__ x, const float* __restrict__ stats,
                         float slope, ushort_t* __restrict__ o) {
    size_t i = (size_t)blockIdx.x * 256 + threadIdx.x;  // over B*R3*64/8
    int c0 = (int)((i * 8) & 63);
    float4 a = ((const float4*)x)[i * 2];
    float4 d = ((const float4*)x)[i * 2 + 1];
    float va[8] = {a.x, a.y, a.z, a.w, d.x, d.y, d.z, d.w};
    unsigned pk[4];
    #pragma unroll
    for (int j = 0; j < 4; j++) {
        float u0 = va[2 * j] * stats[2 * (c0 + 2 * j)] + stats[2 * (c0 + 2 * j) + 1];
        float u1 = va[2 * j + 1] * stats[2 * (c0 + 2 * j) + 2] + stats[2 * (c0 + 2 * j) + 3];
        u0 = u0 > 0 ? u0 : slope * u0;
        u1 = u1 > 0 ? u1 : slope * u1;
        pk[j] = (unsigned)f2bf(u0) | ((unsigned)f2bf(u1) << 16);
    }
    ((uint4*)o)[i] = make_uint4(pk[0], pk[1], pk[2], pk[3]);
}

// ---------------- LDS-staged MFMA conv3d 3x3x3, fused BN-stats epilogue ----------------
__global__ __launch_bounds__(256) void k_convlds(const ushort_t* __restrict__ gT,
                                                 const ushort_t* __restrict__ wS,
                                                 float* __restrict__ outCL,
                                                 float* __restrict__ accs) {
    __shared__ ushort_t lin[20480];     // 40960B input plane (also reused as stats buf)
    __shared__ ushort_t lw[2][6144];    // 2 x 12288B weights
    int bid = blockIdx.x;
    int wgid = (bid & 7) * 64 + (bid >> 3);
    int yt = wgid & 3, z0 = (wgid >> 2) & 31, b = wgid >> 7;
    int tid = threadIdx.x;
    int w = __builtin_amdgcn_readfirstlane(tid >> 6);
    int lane = tid & 63, l15 = lane & 15, l4 = lane >> 4;
    int y0 = yt * 8;
    const ushort_t* gTb = gT + (size_t)b * R3 * 64;

    int voxF[4];
    #pragma unroll
    for (int f = 0; f < 4; f++)
        voxF[f] = (w * 2 + (f >> 1)) * 32 + (f & 1) * 16 + l15 - 1;
    bool xlo_ok = (l15 != 0), xhi_ok = (l15 != 15);

    const v8s vzero = {};
    v4f acc[4][4];
    #pragma unroll
    for (int m = 0; m < 4; m++)
        #pragma unroll
        for (int f = 0; f < 4; f++)
            acc[m][f] = (v4f){0.0f, 0.0f, 0.0f, 0.0f};

#define WSTAGE(s)                                                              \
    do {                                                                       \
        const ushort_t* _src = wS + (size_t)(s) * 6144;                        \
        ushort_t* _dst = lw[(s) & 1];                                          \
        _Pragma("unroll") for (int _i = 0; _i < 3; _i++) {                     \
            int _p = _i * 256 + w * 64;                                        \
            gll16(_src + (size_t)(_p + lane) * 8, _dst + (size_t)_p * 8);      \
        }                                                                      \
    } while (0)

#define ISTAGE(dz)                                                             \
    do {                                                                       \
        int _zp = z0 - 1 + (dz);                                               \
        if (_zp < 0 || _zp > 31) {                                             \
            for (int _q = 0; _q < 10; _q++)                                    \
                *(v8s*)&lin[(size_t)(w * 640 + _q * 64 + lane) * 8] = vzero;   \
        } else {                                                               \
            if (yt == 0) *(v8s*)&lin[(size_t)tid * 8] = vzero;                 \
            if (yt == 3) *(v8s*)&lin[(size_t)(2304 + tid) * 8] = vzero;        \
            const ushort_t* _pb = gTb + ((size_t)_zp * 1024 + (size_t)(y0 - 1) * 32) * 64; \
            int _g0 = (yt == 0) ? 256 : 0;                                     \
            int _nc = 10 - (yt == 0) - (yt == 3);                              \
            for (int _i = 0; _i < _nc; _i++) {                                 \
                int _pbase = _g0 + _i * 256 + w * 64;                          \
                int _p = _pbase + lane;                                        \
                int _vx = _p >> 3, _js = _p & 7;                               \
                int _sg = _vx * 8 + (_js ^ (_vx & 7));                         \
                gll16(_pb + (size_t)_sg * 8, lin + (size_t)_pbase * 8);        \
            }                                                                  \
        }                                                                      \
    } while (0)

    WSTAGE(0);
    for (int s = 0; s < 18; s++) {
        int dy = (s / 2) % 3, cih = s & 1;
        asm volatile("s_barrier" ::: "memory");
        if ((s % 6) == 0) ISTAGE(s / 6);
        if (s + 1 < 18) WSTAGE(s + 1);
        if (s + 1 < 18) asm volatile("s_waitcnt vmcnt(3) lgkmcnt(0)" ::: "memory");
        else            asm volatile("s_waitcnt vmcnt(0) lgkmcnt(0)" ::: "memory");
        asm volatile("s_barrier" ::: "memory");

        const ushort_t* lwb = lw[s & 1];
        #pragma unroll
        for (int dx = 0; dx < 3; dx++) {
            v8s Bf[4];
            #pragma unroll
            for (int f = 0; f < 4; f++) {
                int vox = voxF[f] + dy * 32 + dx;
                int g = vox * 8 + ((cih * 4 + l4) ^ (vox & 7));
                int bix = g * 16;
                bix = bix < 0 ? 0 : bix;
                v8s vb = *(const v8s*)((const char*)lin + bix);
                bool ok = (dx == 0 && (f & 1) == 0) ? xlo_ok :
                          (dx == 2 && (f & 1) == 1) ? xhi_ok : true;
                Bf[f] = ok ? vb : vzero;
            }
            const ushort_t* ap = lwb + dx * 2048 + l15 * 32 + l4 * 8;
            #pragma unroll
            for (int m = 0; m < 4; m++) {
                v8s Af = *(const v8s*)(ap + m * 512);
                #pragma unroll
                for (int f = 0; f < 4; f++)
                    acc[m][f] = __builtin_amdgcn_mfma_f32_16x16x32_bf16(Af, Bf[f], acc[m][f], 0, 0, 0);
            }
        }
    }

    // channel-last f4 stores
    #pragma unroll
    for (int m = 0; m < 4; m++) {
        #pragma unroll
        for (int f = 0; f < 4; f++) {
            int y = y0 + w * 2 + (f >> 1);
            int x = (f & 1) * 16 + l15;
            float4 o = make_float4(acc[m][f][0], acc[m][f][1], acc[m][f][2], acc[m][f][3]);
            *(float4*)&outCL[((size_t)b * R3 + z0 * 1024 + y * 32 + x) * 64 + m * 16 + l4 * 4] = o;
        }
    }

    // ---- fused BN-stats: per-block sum/sumsq per co -> atomics ----
    __syncthreads();
    float* sbuf = (float*)lin;
    #pragma unroll
    for (int m = 0; m < 4; m++)
        #pragma unroll
        for (int r = 0; r < 4; r++) {
            float s = 0, q = 0;
            #pragma unroll
            for (int f = 0; f < 4; f++) {
                float v = acc[m][f][r];
                s += v; q += v * v;
            }
            sbuf[tid * 32 + (m * 4 + r) * 2] = s;
            sbuf[tid * 32 + (m * 4 + r) * 2 + 1] = q;
        }
    __syncthreads();
    if (tid < 128) {
        int co = tid >> 1, val = tid & 1;
        int m = co >> 4, cl4 = (co >> 2) & 3, r = co & 3;
        float a = 0;
        for (int w2 = 0; w2 < 4; w2++)
            for (int l = 0; l < 16; l++)
                a += sbuf[(w2 * 64 + cl4 * 16 + l) * 32 + (m * 4 + r) * 2 + val];
        atomicAdd(&accs[2 * co + val], a);
    }
#undef WSTAGE
#undef ISTAGE
}

__global__ void k_bnfin(const float* __restrict__ pst, const float* __restrict__ g,
                        const float* __restrict__ be, float* __restrict__ stats,
                        int nb, float invcnt) {
    int c = threadIdx.x;
    float s = 0, q = 0;
    for (int b = 0; b < nb; b++) {
        s += pst[(c * nb + b) * 2];
        q += pst[(c * nb + b) * 2 + 1];
    }
    float mean = s * invcnt;
    float var = q * invcnt - mean * mean;
    float sc = g[c] * rsqrtf(var + 1e-4f);
    stats[2 * c] = sc;
    stats[2 * c + 1] = be[c] - mean * sc;
}

// reduce 256 partials per channel (one block per channel)
__global__ void k_bnfin2(const float* __restrict__ pst, const float* __restrict__ g,
                         const float* __restrict__ be, float* __restrict__ stats,
                         float invcnt) {
    int c = blockIdx.x, tid = threadIdx.x;
    __shared__ float rs[256], rq[256];
    rs[tid] = pst[(c * 256 + tid) * 2];
    rq[tid] = pst[(c * 256 + tid) * 2 + 1];
    __syncthreads();
    for (int off = 128; off > 0; off >>= 1) {
        if (tid < off) { rs[tid] += rs[tid + off]; rq[tid] += rq[tid + off]; }
        __syncthreads();
    }
    if (tid == 0) {
        float mean = rs[0] * invcnt;
        float var = rq[0] * invcnt - mean * mean;
        float sc = g[c] * rsqrtf(var + 1e-4f);
        stats[2 * c] = sc;
        stats[2 * c + 1] = be[c] - mean * sc;
    }
}

__global__ void k_bn_act(const float* __restrict__ x, const float* __restrict__ stats,
                         float* __restrict__ out, int shift, float slope) {
    size_t i = (size_t)blockIdx.x * 256 + threadIdx.x;
    int c = (int)((i >> shift) & 63);
    float sc = stats[2 * c], sh = stats[2 * c + 1];
    float4 v = ((const float4*)x)[i];
    v.x = v.x * sc + sh; v.y = v.y * sc + sh; v.z = v.z * sc + sh; v.w = v.w * sc + sh;
    v.x = v.x > 0 ? v.x : slope * v.x;
    v.y = v.y > 0 ? v.y : slope * v.y;
    v.z = v.z > 0 ? v.z : slope * v.z;
    v.w = v.w > 0 ? v.w : slope * v.w;
    ((float4*)out)[i] = v;
}

// ---------------- devoxelize, fused BN+lrelu, channel-last gather ----------------
__global__ void k_devox2(const float* __restrict__ gcl, const float* __restrict__ stats,
                         const float* __restrict__ nc, float* __restrict__ out) {
    int b = blockIdx.y;
    int tid = threadIdx.x, p = tid >> 4, q = tid & 15;
    int n = blockIdx.x * 16 + p;
    float x = nc[((size_t)b * 3 + 0) * NN + n];
    float y = nc[((size_t)b * 3 + 1) * NN + n];
    float z = nc[((size_t)b * 3 + 2) * NN + n];
    float fx = floorf(x), fy = floorf(y), fz = floorf(z);
    int lx = (int)fx, ly = (int)fy, lz = (int)fz;
    int hx = min(lx + 1, RR - 1), hy = min(ly + 1, RR - 1), hz = min(lz + 1, RR - 1);
    float frx = x - fx, fry = y - fy, frz = z - fz;
    int xx[2] = {lx, hx}, yy[2] = {ly, hy}, zz[2] = {lz, hz};
    float wx[2] = {1.0f - frx, frx}, wy[2] = {1.0f - fry, fry}, wz[2] = {1.0f - frz, frz};
    float sc[4], sh[4];
    #pragma unroll
    for (int j = 0; j < 4; j++) {
        sc[j] = stats[2 * (q * 4 + j)];
        sh[j] = stats[2 * (q * 4 + j) + 1];
    }
    float a0 = 0, a1 = 0, a2 = 0, a3 = 0;
    #pragma unroll
    for (int dx = 0; dx < 2; dx++)
        #pragma unroll
        for (int dy = 0; dy < 2; dy++)
            #pragma unroll
            for (int dz = 0; dz < 2; dz++) {
                int idx = (xx[dx] * RR + yy[dy]) * RR + zz[dz];
                float wt = wx[dx] * wy[dy] * wz[dz];
                float4 v = *(const float4*)&gcl[((size_t)b * R3 + idx) * 64 + q * 4];
                float u0 = v.x * sc[0] + sh[0]; u0 = u0 > 0 ? u0 : 0.1f * u0;
                float u1 = v.y * sc[1] + sh[1]; u1 = u1 > 0 ? u1 : 0.1f * u1;
                float u2 = v.z * sc[2] + sh[2]; u2 = u2 > 0 ? u2 : 0.1f * u2;
                float u3 = v.w * sc[3] + sh[3]; u3 = u3 > 0 ? u3 : 0.1f * u3;
                a0 += wt * u0; a1 += wt * u1; a2 += wt * u2; a3 += wt * u3;
            }
    out[((size_t)(b * 64 + q * 4 + 0)) * NN + n] = a0;
    out[((size_t)(b * 64 + q * 4 + 1)) * NN + n] = a1;
    out[((size_t)(b * 64 + q * 4 + 2)) * NN + n] = a2;
    out[((size_t)(b * 64 + q * 4 + 3)) * NN + n] = a3;
}

// ---------------- fuzzy attention (MFMA), 4 m-chunks ----------------
__global__ __launch_bounds__(256) void k_fuzzym(const float* __restrict__ coords,
                                                const ushort_t* __restrict__ featb,
                                                float* __restrict__ pnum,
                                                float* __restrict__ pden) {
    __shared__ float cm[3][1024];
    int b = blockIdx.z, mc = blockIdx.y, nt = blockIdx.x;
    int tid = threadIdx.x;
    int w = tid >> 6, lane = tid & 63, l15 = lane & 15, l4 = lane >> 4;
    int m0 = mc * 1024;

    for (int i = tid; i < 1024; i += 256) {
        float a0 = coords[((size_t)b * 3 + 0) * NN + m0 + i];
        float a1 = coords[((size_t)b * 3 + 1) * NN + m0 + i];
        float a2 = coords[((size_t)b * 3 + 2) * NN + m0 + i];
        float inv = 1.0f / fmaxf(sqrtf(a0 * a0 + a1 * a1 + a2 * a2), 1e-12f);
        cm[0][i] = a0 * inv; cm[1][i] = a1 * inv; cm[2][i] = a2 * inv;
    }

    int n = nt * 64 + w * 16 + l15;
    float q0 = coords[((size_t)b * 3 + 0) * NN + n];
    float q1 = coords[((size_t)b * 3 + 1) * NN + n];
    float q2 = coords[((size_t)b * 3 + 2) * NN + n];
    float qi = 10.0f / fmaxf(sqrtf(q0 * q0 + q1 * q1 + q2 * q2), 1e-12f);
    q0 *= qi; q1 *= qi; q2 *= qi;

    const ushort_t* fb = featb + (size_t)b * 64 * NN + m0;
    v4f acc[4];
    #pragma unroll
    for (int cb = 0; cb < 4; cb++) acc[cb] = (v4f){0.0f, 0.0f, 0.0f, 0.0f};
    float den = 0.0f;

    __syncthreads();
    #pragma unroll 2
    for (int t = 0; t < 32; t++) {
        int mo = t * 32 + l4 * 8;
        float e[8];
        #pragma unroll
        for (int jj = 0; jj < 2; jj++) {
            float4 x0 = *(const float4*)&cm[0][mo + jj * 4];
            float4 x1 = *(const float4*)&cm[1][mo + jj * 4];
            float4 x2 = *(const float4*)&cm[2][mo + jj * 4];
            e[jj * 4 + 0] = __expf(q0 * x0.x + q1 * x1.x + q2 * x2.x);
            e[jj * 4 + 1] = __expf(q0 * x0.y + q1 * x1.y + q2 * x2.y);
            e[jj * 4 + 2] = __expf(q0 * x0.z + q1 * x1.z + q2 * x2.z);
            e[jj * 4 + 3] = __expf(q0 * x0.w + q1 * x1.w + q2 * x2.w);
        }
        den += ((e[0] + e[1]) + (e[2] + e[3])) + ((e[4] + e[5]) + (e[6] + e[7]));
        union { __hip_bfloat162 h[4]; v8s v; } pk;
        pk.h[0] = __float22bfloat162_rn(make_float2(e[0], e[1]));
        pk.h[1] = __float22bfloat162_rn(make_float2(e[2], e[3]));
        pk.h[2] = __float22bfloat162_rn(make_float2(e[4], e[5]));
        pk.h[3] = __float22bfloat162_rn(make_float2(e[6], e[7]));
        #pragma unroll
        for (int cb = 0; cb < 4; cb++) {
            v8s A = *(const v8s*)(fb + (size_t)(cb * 16 + l15) * NN + mo);
            acc[cb] = __builtin_amdgcn_mfma_f32_16x16x32_bf16(A, pk.v, acc[cb], 0, 0, 0);
        }
    }

    den += __shfl_xor(den, 16);
    den += __shfl_xor(den, 32);

    size_t obase = ((size_t)(b * 4 + mc)) * 64 * NN;
    #pragma unroll
    for (int cb = 0; cb < 4; cb++)
        #pragma unroll
        for (int r = 0; r < 4; r++)
            pnum[obase + (size_t)(cb * 16 + l4 * 4 + r) * NN + n] = acc[cb][r];
    if (l4 == 0) pden[((size_t)(b * 4 + mc)) * NN + n] = den;
}

__global__ void k_combine2(const float* __restrict__ pnum, const float* __restrict__ pden,
                           float* __restrict__ fzf) {
    int i = blockIdx.x * 256 + threadIdx.x;
    int b = i >> 18, c = (i >> 12) & 63, n = i & 4095;
    float num = 0, den = 0;
    #pragma unroll
    for (int ch = 0; ch < 4; ch++) {
        num += pnum[((size_t)(b * 4 + ch) * 64 + c) * NN + n];
        den += pden[((size_t)(b * 4 + ch)) * NN + n];
    }
    fzf[((size_t)(b * 64 + c)) * NN + n] = num / den;
}

// ---------------- 1x1 convs v3: thread = 4n x 1o, 1024 blocks, partial stats ----------------
// pst layout: [o 64][part 256][2], part = bx*4 + b
__global__ __launch_bounds__(256) void k_1x1s(const float* __restrict__ in,
                                              const float* __restrict__ wT,
                                              const float* __restrict__ bias,
                                              float* __restrict__ out,
                                              float* __restrict__ pst) {
    int b = blockIdx.z, ob = blockIdx.y, bx = blockIdx.x;
    int tid = threadIdx.x;
    int q = tid & 15, o = ob * 16 + (tid >> 4);
    int n = bx * 64 + q * 4;
    const float* src = in + (size_t)b * 64 * NN + n;
    const float* wp_ = wT + o;
    v4f acc = {0, 0, 0, 0};
    #pragma unroll 8
    for (int c = 0; c < 64; c++) {
        float4 x = *(const float4*)&src[(size_t)c * NN];
        float w = wp_[c * 64];
        acc[0] += x.x * w; acc[1] += x.y * w; acc[2] += x.z * w; acc[3] += x.w * w;
    }
    float bv = bias[o];
    float s = 0, q2 = 0;
    float4 ov;
    float* op = (float*)&ov;
    #pragma unroll
    for (int v = 0; v < 4; v++) {
        float val = acc[v] + bv;
        op[v] = val;
        s += val; q2 += val * val;
    }
    *(float4*)&out[((size_t)(b * 64 + o)) * NN + n] = ov;
    #pragma unroll
    for (int off = 1; off < 16; off <<= 1) {
        s += __shfl_xor(s, off);
        q2 += __shfl_xor(q2, off);
    }
    if (q == 0) {
        int part = bx * 4 + b;
        pst[(o * 256 + part) * 2] = s;
        pst[(o * 256 + part) * 2 + 1] = q2;
    }
}

// fusion: wfuT rows 0..63 (vox), 64..127 (pt with BN+relu), 128..191 (folded fzf)
__global__ __launch_bounds__(256) void k_1x1f(const float* __restrict__ vox,
                                              const float* __restrict__ pt,
                                              const float* __restrict__ fzf,
                                              const float* __restrict__ bnB,
                                              const float* __restrict__ wfuT,
                                              const float* __restrict__ bC,
                                              float* __restrict__ out,
                                              float* __restrict__ pst) {
    int b = blockIdx.z, ob = blockIdx.y, bx = blockIdx.x;
    int tid = threadIdx.x;
    int q = tid & 15, o = ob * 16 + (tid >> 4);
    int n = bx * 64 + q * 4;
    const float* srcA = vox + (size_t)b * 64 * NN + n;
    const float* srcB = pt + (size_t)b * 64 * NN + n;
    const float* srcC = fzf + (size_t)b * 64 * NN + n;
    const float* wA = wfuT + o;
    v4f acc = {0, 0, 0, 0};
    #pragma unroll 8
    for (int c = 0; c < 64; c++) {
        float4 x = *(const float4*)&srcA[(size_t)c * NN];
        float w = wA[c * 64];
        acc[0] += x.x * w; acc[1] += x.y * w; acc[2] += x.z * w; acc[3] += x.w * w;
    }
    #pragma unroll 8
    for (int c = 0; c < 64; c++) {
        float4 x = *(const float4*)&srcB[(size_t)c * NN];
        float sc = bnB[2 * c], sh = bnB[2 * c + 1];
        float w = wA[(64 + c) * 64];
        float x0 = fmaxf(x.x * sc + sh, 0.0f), x1 = fmaxf(x.y * sc + sh, 0.0f);
        float x2 = fmaxf(x.z * sc + sh, 0.0f), x3 = fmaxf(x.w * sc + sh, 0.0f);
        acc[0] += x0 * w; acc[1] += x1 * w; acc[2] += x2 * w; acc[3] += x3 * w;
    }
    #pragma unroll 8
    for (int c = 0; c < 64; c++) {
        float4 x = *(const float4*)&srcC[(size_t)c * NN];
        float w = wA[(128 + c) * 64];
        acc[0] += x.x * w; acc[1] += x.y * w; acc[2] += x.z * w; acc[3] += x.w * w;
    }
    float bv = bC[o];
    float s = 0, q2 = 0;
    float4 ov;
    float* op = (float*)&ov;
    #pragma unroll
    for (int v = 0; v < 4; v++) {
        float val = acc[v] + bv;
        op[v] = val;
        s += val; q2 += val * val;
    }
    *(float4*)&out[((size_t)(b * 64 + o)) * NN + n] = ov;
    #pragma unroll
    for (int off = 1; off < 16; off <<= 1) {
        s += __shfl_xor(s, off);
        q2 += __shfl_xor(q2, off);
    }
    if (q == 0) {
        int part = bx * 4 + b;
        pst[(o * 256 + part) * 2] = s;
        pst[(o * 256 + part) * 2 + 1] = q2;
    }
}

// ---------------- launcher ----------------
extern "C" void kernel_launch(void* const* d_in, const int* in_sizes, int n_in,
                              void* d_out, int out_size, void* d_ws, size_t ws_size,
                              hipStream_t stream) {
    const float* features = (const float*)d_in[0];
    const float* coords = (const float*)d_in[1];
    const float* w1 = (const float*)d_in[2];
    const float* g1 = (const float*)d_in[4];
    const float* be1 = (const float*)d_in[5];
    const float* w2 = (const float*)d_in[6];
    const float* g2 = (const float*)d_in[8];
    const float* be2 = (const float*)d_in[9];
    const float* wp = (const float*)d_in[10];
    const float* bp = (const float*)d_in[11];
    const float* gp = (const float*)d_in[12];
    const float* bep = (const float*)d_in[13];
    const float* wf = (const float*)d_in[14];
    const float* bf = (const float*)d_in[15];
    const float* wfu = (const float*)d_in[16];
    const float* bfu = (const float*)d_in[17];
    const float* gfu = (const float*)d_in[18];
    const float* befu = (const float*)d_in[19];

    float* ws = (float*)d_ws;
    float* nc = ws;                        // 49152
    int* vidx = (int*)(ws + 49152);        // 16384 ints
    float* cnt = ws + 65536;               // 131072 (pden overlays later)
    float* pden = cnt;
    float* gridA = ws + 196608;            // cf f32 scatter grid, then cl f32 conv out
    float* gridCL = gridA;
    float* gTpool = ws + 8585216;          // gT bf16 / pnum / pstB later
    ushort_t* gT = (ushort_t*)gTpool;
    float* pnum = gTpool;
    float* pstB = gTpool;                  // 32768 floats (after combine2, pool is dead)
    float* stats = ws + 16973824;          // 512 finalized (4 x 128)
    float* voxreg = ws + 16974336;         // wS1/wS2 until devox
    ushort_t* wS1 = (ushort_t*)voxreg;
    ushort_t* wS2 = wS1 + 110592;
    float* vox = voxreg;
    float* pt = ws + 18022912;
    float* fzf = ws + 19071488;
    float* wpT = ws + 20120064;            // 4096
    float* wfuT = wpT + 4096;              // 12288
    float* bC = wfuT + 12288;              // 64
    float* fpre = ws + 21168640;           // featb overlays
    ushort_t* featb = (ushort_t*)fpre;
    float* accs = ws + 22217216;           // 512 float stat accumulators (conv)

    float* out = (float*)d_out;

    hipMemsetAsync(accs, 0, 512 * 4, stream);
    hipMemsetAsync(cnt, 0, (size_t)(131072 + 8388608) * 4, stream);

    // prep
    k_fold<<<65, 256, 0, stream>>>(wp, wfu, wf, bf, bfu, wpT, wfuT, bC);
    k_f2b<<<BB * 64 * NN / 8 / 256, 256, 0, stream>>>(features, featb);
    k_tws<<<432, 256, 0, stream>>>(w1, wS1);
    k_tws<<<432, 256, 0, stream>>>(w2, wS2);
    k_nc<<<BB, 256, 0, stream>>>(coords, nc, vidx);
    k_scatter<<<BB * NN / 64, 256, 0, stream>>>(features, vidx, gridA, cnt);
    k_avgT<<<dim3(512, BB), 256, 0, stream>>>(gridA, cnt, gT);

    // voxel branch
    k_convlds<<<512, 256, 0, stream>>>(gT, wS1, gridCL, accs);
    k_bnfin<<<1, 64, 0, stream>>>(accs, g1, be1, stats, 1, 1.0f / (BB * R3));
    k_bncast<<<BB * R3 * 64 / 8 / 256, 256, 0, stream>>>(gridCL, stats, 0.1f, gT);
    k_convlds<<<512, 256, 0, stream>>>(gT, wS2, gridCL, accs + 128);
    k_bnfin<<<1, 64, 0, stream>>>(accs + 128, g2, be2, stats + 128, 1, 1.0f / (BB * R3));
    k_devox2<<<dim3(NN / 16, BB), 256, 0, stream>>>(gridCL, stats + 128, nc, vox);

    // fuzzy branch
    k_fuzzym<<<dim3(64, 4, BB), 256, 0, stream>>>(coords, featb, pnum, pden);
    k_combine2<<<BB * 64 * NN / 256, 256, 0, stream>>>(pnum, pden, fzf);

    // point branch (partial stats into pstB, which overlays the now-dead pnum pool)
    k_1x1s<<<dim3(NN / 64, 4, BB), 256, 0, stream>>>(features, wpT, bp, pt, pstB);
    k_bnfin2<<<64, 256, 0, stream>>>(pstB, gp, bep, stats + 256, 1.0f / (BB * NN));

    // fusion (wf folded into wfuT segC; pt BN on the fly; partial stats)
    k_1x1f<<<dim3(NN / 64, 4, BB), 256, 0, stream>>>(vox, pt, fzf, stats + 256, wfuT, bC,
                                                     fpre, pstB);
    k_bnfin2<<<64, 256, 0, stream>>>(pstB, gfu, befu, stats + 384, 1.0f / (BB * NN));
    k_bn_act<<<BB * 64 * NN / 4 / 256, 256, 0, stream>>>(fpre, stats + 384, out, 10, 0.0f);

    hipMemcpyAsync(out + (size_t)BB * CO * NN, coords, (size_t)BB * 3 * NN * 4,
                   hipMemcpyDeviceToDevice, stream);
}

// Round 10
// 291.865 us; speedup vs baseline: 1.7163x; 1.0976x over previous
//
#include <hip/hip_runtime.h>
#include <hip/hip_bf16.h>
#include <math.h>

#define RR 32
#define R3 32768
#define BB 4
#define CI 64
#define CO 64
#define NN 4096

typedef short v8s __attribute__((ext_vector_type(8)));
typedef float v4f __attribute__((ext_vector_type(4)));
typedef unsigned short ushort_t;

__device__ __forceinline__ unsigned short f2bf(float f) {
    unsigned int u = __float_as_uint(f);
    unsigned int r = (u + 0x7FFFu + ((u >> 16) & 1u)) >> 16;
    return (unsigned short)r;
}

__device__ __forceinline__ void gll16(const void* g, void* l) {
    __builtin_amdgcn_global_load_lds((const __attribute__((address_space(1))) unsigned int*)g,
                                     (__attribute__((address_space(3))) unsigned int*)l, 16, 0, 0);
}

// ---------------- block reduce helpers ----------------
__device__ __forceinline__ float blockReduceSum(float v, float* sm) {
    int tid = threadIdx.x;
    sm[tid] = v; __syncthreads();
    for (int off = 128; off > 0; off >>= 1) {
        if (tid < off) sm[tid] += sm[tid + off];
        __syncthreads();
    }
    float r = sm[0]; __syncthreads();
    return r;
}
__device__ __forceinline__ float blockReduceMax(float v, float* sm) {
    int tid = threadIdx.x;
    sm[tid] = v; __syncthreads();
    for (int off = 128; off > 0; off >>= 1) {
        if (tid < off) sm[tid] = fmaxf(sm[tid], sm[tid + off]);
        __syncthreads();
    }
    float r = sm[0]; __syncthreads();
    return r;
}

// ---------------- voxel coords ----------------
__global__ void k_nc(const float* __restrict__ coords, float* __restrict__ nc,
                     int* __restrict__ vidx) {
    int b = blockIdx.x, tid = threadIdx.x;
    __shared__ float sm[256];
    const float* cb = coords + (size_t)b * 3 * NN;
    float s0 = 0, s1 = 0, s2 = 0;
    for (int n = tid; n < NN; n += 256) {
        s0 += cb[n]; s1 += cb[NN + n]; s2 += cb[2 * NN + n];
    }
    float m0 = blockReduceSum(s0, sm) * (1.0f / NN);
    float m1 = blockReduceSum(s1, sm) * (1.0f / NN);
    float m2 = blockReduceSum(s2, sm) * (1.0f / NN);
    float mx = 0;
    for (int n = tid; n < NN; n += 256) {
        float dx = cb[n] - m0, dy = cb[NN + n] - m1, dz = cb[2 * NN + n] - m2;
        mx = fmaxf(mx, dx * dx + dy * dy + dz * dz);
    }
    mx = blockReduceMax(mx, sm);
    float denom = 2.0f * sqrtf(mx);
    float mean[3] = {m0, m1, m2};
    for (int n = tid; n < NN; n += 256) {
        int vi[3];
        #pragma unroll
        for (int ax = 0; ax < 3; ax++) {
            float x = (cb[ax * NN + n] - mean[ax]) / denom + 0.5f;
            x = x * RR;
            x = fminf(fmaxf(x, 0.0f), (float)(RR - 1));
            nc[((size_t)b * 3 + ax) * NN + n] = x;
            vi[ax] = (int)rintf(x);
        }
        vidx[b * NN + n] = (vi[0] * RR + vi[1]) * RR + vi[2];
    }
}

// ---------------- scatter-mean (channel-first) ----------------
__global__ void k_scatter(const float* __restrict__ feat, const int* __restrict__ vidx,
                          float* __restrict__ grid, float* __restrict__ cnt) {
    int tid = threadIdx.x;
    int pid = blockIdx.x * 64 + (tid & 63);
    int cg = tid >> 6;
    int b = pid / NN, n = pid % NN;
    int idx = vidx[pid];
    if (cg == 0) atomicAdd(&cnt[b * R3 + idx], 1.0f);
    #pragma unroll 4
    for (int c = cg * 16; c < cg * 16 + 16; c++)
        atomicAdd(&grid[((size_t)(b * CI + c)) * R3 + idx], feat[((size_t)(b * CI + c)) * NN + n]);
}

// ---------------- divide + transpose + bf16 cast: cf f32 -> cl bf16 ----------------
__global__ void k_avgT(const float* __restrict__ grid, const float* __restrict__ cnt,
                       ushort_t* __restrict__ gT) {
    __shared__ float ld[64][65];
    int b = blockIdx.y, s0 = blockIdx.x * 64, tid = threadIdx.x;
    int sl = tid & 63, cq = tid >> 6;
    const float* xb = grid + (size_t)b * 64 * R3;
    #pragma unroll
    for (int k = 0; k < 16; k++) {
        int c = cq * 16 + k;
        ld[sl][c] = xb[(size_t)c * R3 + s0 + sl];
    }
    __syncthreads();
    int v = tid >> 2, q = tid & 3;
    float inv = 1.0f / fmaxf(cnt[b * R3 + s0 + v], 1.0f);
    unsigned int pk[8];
    #pragma unroll
    for (int j = 0; j < 8; j++) {
        int c = q * 16 + j * 2;
        float a = ld[v][c] * inv, d = ld[v][c + 1] * inv;
        pk[j] = (unsigned int)f2bf(a) | ((unsigned int)f2bf(d) << 16);
    }
    uint4* op = (uint4*)(gT + ((size_t)(b * R3 + s0 + v)) * 64 + q * 16);
    op[0] = make_uint4(pk[0], pk[1], pk[2], pk[3]);
    op[1] = make_uint4(pk[4], pk[5], pk[6], pk[7]);
}

// ---------------- features f32 -> bf16 ----------------
__global__ void k_f2b(const float* __restrict__ x, ushort_t* __restrict__ o) {
    size_t i = (size_t)blockIdx.x * 256 + threadIdx.x;
    float4 a = ((const float4*)x)[i * 2];
    float4 b = ((const float4*)x)[i * 2 + 1];
    union { __hip_bfloat162 h[4]; uint4 u; } pk;
    pk.h[0] = __float22bfloat162_rn(make_float2(a.x, a.y));
    pk.h[1] = __float22bfloat162_rn(make_float2(a.z, a.w));
    pk.h[2] = __float22bfloat162_rn(make_float2(b.x, b.y));
    pk.h[3] = __float22bfloat162_rn(make_float2(b.z, b.w));
    ((uint4*)o)[i] = pk.u;
}

// ---------------- weight transform: wS[dzdy 9][cih 2][dx 3][co 64][cis 32] bf16 ----------------
__global__ void k_tws(const float* __restrict__ w, ushort_t* __restrict__ wS) {
    int i = blockIdx.x * 256 + threadIdx.x;  // 110592
    int cis = i & 31, co = (i >> 5) & 63;
    int dx = (i >> 11) % 3, cih = (i / 6144) & 1, dzdy = i / 12288;
    int k = dzdy * 3 + dx, ci = cih * 32 + cis;
    wS[i] = f2bf(w[((size_t)co * CI + ci) * 27 + k]);
}

// ---------------- weight fold/transposes for 1x1 kernels ----------------
__global__ void k_fold(const float* __restrict__ wp, const float* __restrict__ wfu,
                       const float* __restrict__ wf, const float* __restrict__ bf,
                       const float* __restrict__ bfu,
                       float* __restrict__ wpT, float* __restrict__ wfuT,
                       float* __restrict__ bC) {
    int i = blockIdx.x * 256 + threadIdx.x;
    if (i < 4096) {
        int c = i >> 6, o = i & 63;
        wpT[c * 64 + o] = wp[o * 64 + c];
    } else if (i < 12288) {
        int j = i - 4096;
        int c = j >> 6, o = j & 63;
        wfuT[c * 64 + o] = wfu[(size_t)o * 192 + c];
    } else if (i < 16384) {
        int j = i - 12288;
        int c = j >> 6, o = j & 63;
        float s = 0;
        for (int k = 0; k < 64; k++)
            s += wfu[(size_t)o * 192 + 128 + k] * wf[(size_t)k * 64 + c];
        wfuT[(128 + c) * 64 + o] = s;
    } else if (i < 16448) {
        int o = i - 16384;
        float s = bfu[o];
        for (int k = 0; k < 64; k++)
            s += wfu[(size_t)o * 192 + 128 + k] * bf[k];
        bC[o] = s;
    }
}

// ---------------- BN + lrelu + bf16 cast (cl -> cl) ----------------
__global__ void k_bncast(const float* __restrict__ x, const float* __restrict__ stats,
                         float slope, ushort_t* __restrict__ o) {
    size_t i = (size_t)blockIdx.x * 256 + threadIdx.x;  // over B*R3*64/8
    int c0 = (int)((i * 8) & 63);
    float4 a = ((const float4*)x)[i * 2];
    float4 d = ((const float4*)x)[i * 2 + 1];
    float va[8] = {a.x, a.y, a.z, a.w, d.x, d.y, d.z, d.w};
    unsigned pk[4];
    #pragma unroll
    for (int j = 0; j < 4; j++) {
        float u0 = va[2 * j] * stats[2 * (c0 + 2 * j)] + stats[2 * (c0 + 2 * j) + 1];
        float u1 = va[2 * j + 1] * stats[2 * (c0 + 2 * j) + 2] + stats[2 * (c0 + 2 * j) + 3];
        u0 = u0 > 0 ? u0 : slope * u0;
        u1 = u1 > 0 ? u1 : slope * u1;
        pk[j] = (unsigned)f2bf(u0) | ((unsigned)f2bf(u1) << 16);
    }
    ((uint4*)o)[i] = make_uint4(pk[0], pk[1], pk[2], pk[3]);
}

// ---------------- LDS-staged MFMA conv3d 3x3x3, fused BN-stats epilogue ----------------
__global__ __launch_bounds__(256) void k_convlds(const ushort_t* __restrict__ gT,
                                                 const ushort_t* __restrict__ wS,
                                                 float* __restrict__ outCL,
                                                 float* __restrict__ accs) {
    __shared__ ushort_t lin[20480];     // 40960B input plane (also reused as stats buf)
    __shared__ ushort_t lw[2][6144];    // 2 x 12288B weights
    int bid = blockIdx.x;
    int wgid = (bid & 7) * 64 + (bid >> 3);
    int yt = wgid & 3, z0 = (wgid >> 2) & 31, b = wgid >> 7;
    int tid = threadIdx.x;
    int w = __builtin_amdgcn_readfirstlane(tid >> 6);
    int lane = tid & 63, l15 = lane & 15, l4 = lane >> 4;
    int y0 = yt * 8;
    const ushort_t* gTb = gT + (size_t)b * R3 * 64;

    int voxF[4];
    #pragma unroll
    for (int f = 0; f < 4; f++)
        voxF[f] = (w * 2 + (f >> 1)) * 32 + (f & 1) * 16 + l15 - 1;
    bool xlo_ok = (l15 != 0), xhi_ok = (l15 != 15);

    const v8s vzero = {};
    v4f acc[4][4];
    #pragma unroll
    for (int m = 0; m < 4; m++)
        #pragma unroll
        for (int f = 0; f < 4; f++)
            acc[m][f] = (v4f){0.0f, 0.0f, 0.0f, 0.0f};

#define WSTAGE(s)                                                              \
    do {                                                                       \
        const ushort_t* _src = wS + (size_t)(s) * 6144;                        \
        ushort_t* _dst = lw[(s) & 1];                                          \
        _Pragma("unroll") for (int _i = 0; _i < 3; _i++) {                     \
            int _p = _i * 256 + w * 64;                                        \
            gll16(_src + (size_t)(_p + lane) * 8, _dst + (size_t)_p * 8);      \
        }                                                                      \
    } while (0)

#define ISTAGE(dz)                                                             \
    do {                                                                       \
        int _zp = z0 - 1 + (dz);                                               \
        if (_zp < 0 || _zp > 31) {                                             \
            for (int _q = 0; _q < 10; _q++)                                    \
                *(v8s*)&lin[(size_t)(w * 640 + _q * 64 + lane) * 8] = vzero;   \
        } else {                                                               \
            if (yt == 0) *(v8s*)&lin[(size_t)tid * 8] = vzero;                 \
            if (yt == 3) *(v8s*)&lin[(size_t)(2304 + tid) * 8] = vzero;        \
            const ushort_t* _pb = gTb + ((size_t)_zp * 1024 + (size_t)(y0 - 1) * 32) * 64; \
            int _g0 = (yt == 0) ? 256 : 0;                                     \
            int _nc = 10 - (yt == 0) - (yt == 3);                              \
            for (int _i = 0; _i < _nc; _i++) {                                 \
                int _pbase = _g0 + _i * 256 + w * 64;                          \
                int _p = _pbase + lane;                                        \
                int _vx = _p >> 3, _js = _p & 7;                               \
                int _sg = _vx * 8 + (_js ^ (_vx & 7));                         \
                gll16(_pb + (size_t)_sg * 8, lin + (size_t)_pbase * 8);        \
            }                                                                  \
        }                                                                      \
    } while (0)

    WSTAGE(0);
    for (int s = 0; s < 18; s++) {
        int dy = (s / 2) % 3, cih = s & 1;
        asm volatile("s_barrier" ::: "memory");
        if ((s % 6) == 0) ISTAGE(s / 6);
        if (s + 1 < 18) WSTAGE(s + 1);
        if (s + 1 < 18) asm volatile("s_waitcnt vmcnt(3) lgkmcnt(0)" ::: "memory");
        else            asm volatile("s_waitcnt vmcnt(0) lgkmcnt(0)" ::: "memory");
        asm volatile("s_barrier" ::: "memory");

        const ushort_t* lwb = lw[s & 1];
        #pragma unroll
        for (int dx = 0; dx < 3; dx++) {
            v8s Bf[4];
            #pragma unroll
            for (int f = 0; f < 4; f++) {
                int vox = voxF[f] + dy * 32 + dx;
                int g = vox * 8 + ((cih * 4 + l4) ^ (vox & 7));
                int bix = g * 16;
                bix = bix < 0 ? 0 : bix;
                v8s vb = *(const v8s*)((const char*)lin + bix);
                bool ok = (dx == 0 && (f & 1) == 0) ? xlo_ok :
                          (dx == 2 && (f & 1) == 1) ? xhi_ok : true;
                Bf[f] = ok ? vb : vzero;
            }
            const ushort_t* ap = lwb + dx * 2048 + l15 * 32 + l4 * 8;
            #pragma unroll
            for (int m = 0; m < 4; m++) {
                v8s Af = *(const v8s*)(ap + m * 512);
                #pragma unroll
                for (int f = 0; f < 4; f++)
                    acc[m][f] = __builtin_amdgcn_mfma_f32_16x16x32_bf16(Af, Bf[f], acc[m][f], 0, 0, 0);
            }
        }
    }

    // channel-last f4 stores
    #pragma unroll
    for (int m = 0; m < 4; m++) {
        #pragma unroll
        for (int f = 0; f < 4; f++) {
            int y = y0 + w * 2 + (f >> 1);
            int x = (f & 1) * 16 + l15;
            float4 o = make_float4(acc[m][f][0], acc[m][f][1], acc[m][f][2], acc[m][f][3]);
            *(float4*)&outCL[((size_t)b * R3 + z0 * 1024 + y * 32 + x) * 64 + m * 16 + l4 * 4] = o;
        }
    }

    // ---- fused BN-stats: per-block sum/sumsq per co -> atomics ----
    __syncthreads();
    float* sbuf = (float*)lin;
    #pragma unroll
    for (int m = 0; m < 4; m++)
        #pragma unroll
        for (int r = 0; r < 4; r++) {
            float s = 0, q = 0;
            #pragma unroll
            for (int f = 0; f < 4; f++) {
                float v = acc[m][f][r];
                s += v; q += v * v;
            }
            sbuf[tid * 32 + (m * 4 + r) * 2] = s;
            sbuf[tid * 32 + (m * 4 + r) * 2 + 1] = q;
        }
    __syncthreads();
    if (tid < 128) {
        int co = tid >> 1, val = tid & 1;
        int m = co >> 4, cl4 = (co >> 2) & 3, r = co & 3;
        float a = 0;
        for (int w2 = 0; w2 < 4; w2++)
            for (int l = 0; l < 16; l++)
                a += sbuf[(w2 * 64 + cl4 * 16 + l) * 32 + (m * 4 + r) * 2 + val];
        atomicAdd(&accs[2 * co + val], a);
    }
#undef WSTAGE
#undef ISTAGE
}

__global__ void k_bnfin(const float* __restrict__ pst, const float* __restrict__ g,
                        const float* __restrict__ be, float* __restrict__ stats,
                        int nb, float invcnt) {
    int c = threadIdx.x;
    float s = 0, q = 0;
    for (int b = 0; b < nb; b++) {
        s += pst[(c * nb + b) * 2];
        q += pst[(c * nb + b) * 2 + 1];
    }
    float mean = s * invcnt;
    float var = q * invcnt - mean * mean;
    float sc = g[c] * rsqrtf(var + 1e-4f);
    stats[2 * c] = sc;
    stats[2 * c + 1] = be[c] - mean * sc;
}

// reduce 256 partials per channel (one block per channel)
__global__ void k_bnfin2(const float* __restrict__ pst, const float* __restrict__ g,
                         const float* __restrict__ be, float* __restrict__ stats,
                         float invcnt) {
    int c = blockIdx.x, tid = threadIdx.x;
    __shared__ float rs[256], rq[256];
    rs[tid] = pst[(c * 256 + tid) * 2];
    rq[tid] = pst[(c * 256 + tid) * 2 + 1];
    __syncthreads();
    for (int off = 128; off > 0; off >>= 1) {
        if (tid < off) { rs[tid] += rs[tid + off]; rq[tid] += rq[tid + off]; }
        __syncthreads();
    }
    if (tid == 0) {
        float mean = rs[0] * invcnt;
        float var = rq[0] * invcnt - mean * mean;
        float sc = g[c] * rsqrtf(var + 1e-4f);
        stats[2 * c] = sc;
        stats[2 * c + 1] = be[c] - mean * sc;
    }
}

__global__ void k_bn_act(const float* __restrict__ x, const float* __restrict__ stats,
                         float* __restrict__ out, int shift, float slope) {
    size_t i = (size_t)blockIdx.x * 256 + threadIdx.x;
    int c = (int)((i >> shift) & 63);
    float sc = stats[2 * c], sh = stats[2 * c + 1];
    float4 v = ((const float4*)x)[i];
    v.x = v.x * sc + sh; v.y = v.y * sc + sh; v.z = v.z * sc + sh; v.w = v.w * sc + sh;
    v.x = v.x > 0 ? v.x : slope * v.x;
    v.y = v.y > 0 ? v.y : slope * v.y;
    v.z = v.z > 0 ? v.z : slope * v.z;
    v.w = v.w > 0 ? v.w : slope * v.w;
    ((float4*)out)[i] = v;
}

// ---------------- devoxelize, fused BN+lrelu, channel-last gather ----------------
__global__ void k_devox2(const float* __restrict__ gcl, const float* __restrict__ stats,
                         const float* __restrict__ nc, float* __restrict__ out) {
    int b = blockIdx.y;
    int tid = threadIdx.x, p = tid >> 4, q = tid & 15;
    int n = blockIdx.x * 16 + p;
    float x = nc[((size_t)b * 3 + 0) * NN + n];
    float y = nc[((size_t)b * 3 + 1) * NN + n];
    float z = nc[((size_t)b * 3 + 2) * NN + n];
    float fx = floorf(x), fy = floorf(y), fz = floorf(z);
    int lx = (int)fx, ly = (int)fy, lz = (int)fz;
    int hx = min(lx + 1, RR - 1), hy = min(ly + 1, RR - 1), hz = min(lz + 1, RR - 1);
    float frx = x - fx, fry = y - fy, frz = z - fz;
    int xx[2] = {lx, hx}, yy[2] = {ly, hy}, zz[2] = {lz, hz};
    float wx[2] = {1.0f - frx, frx}, wy[2] = {1.0f - fry, fry}, wz[2] = {1.0f - frz, frz};
    float sc[4], sh[4];
    #pragma unroll
    for (int j = 0; j < 4; j++) {
        sc[j] = stats[2 * (q * 4 + j)];
        sh[j] = stats[2 * (q * 4 + j) + 1];
    }
    float a0 = 0, a1 = 0, a2 = 0, a3 = 0;
    #pragma unroll
    for (int dx = 0; dx < 2; dx++)
        #pragma unroll
        for (int dy = 0; dy < 2; dy++)
            #pragma unroll
            for (int dz = 0; dz < 2; dz++) {
                int idx = (xx[dx] * RR + yy[dy]) * RR + zz[dz];
                float wt = wx[dx] * wy[dy] * wz[dz];
                float4 v = *(const float4*)&gcl[((size_t)b * R3 + idx) * 64 + q * 4];
                float u0 = v.x * sc[0] + sh[0]; u0 = u0 > 0 ? u0 : 0.1f * u0;
                float u1 = v.y * sc[1] + sh[1]; u1 = u1 > 0 ? u1 : 0.1f * u1;
                float u2 = v.z * sc[2] + sh[2]; u2 = u2 > 0 ? u2 : 0.1f * u2;
                float u3 = v.w * sc[3] + sh[3]; u3 = u3 > 0 ? u3 : 0.1f * u3;
                a0 += wt * u0; a1 += wt * u1; a2 += wt * u2; a3 += wt * u3;
            }
    out[((size_t)(b * 64 + q * 4 + 0)) * NN + n] = a0;
    out[((size_t)(b * 64 + q * 4 + 1)) * NN + n] = a1;
    out[((size_t)(b * 64 + q * 4 + 2)) * NN + n] = a2;
    out[((size_t)(b * 64 + q * 4 + 3)) * NN + n] = a3;
}

// ---------------- fuzzy attention (MFMA) v5: A staged in LDS, double-buffered ----------------
// grid (64 n-tiles, 4 m-chunks, B). Per t-step: A chunk [64ch][32m] bf16 = 4KB staged
// via one gll16/thread with pre-swizzled source; reads swizzled (slot = l4 ^ ((row>>1)&3)).
__global__ __launch_bounds__(256) void k_fuzzym(const float* __restrict__ coords,
                                                const ushort_t* __restrict__ featb,
                                                float* __restrict__ pnum,
                                                float* __restrict__ pden) {
    __shared__ float cm[3][1024];        // 12 KB
    __shared__ ushort_t la[2][2048];     // 2 x 4 KB A ring
    int b = blockIdx.z, mc = blockIdx.y, nt = blockIdx.x;
    int tid = threadIdx.x;
    int w = tid >> 6, lane = tid & 63, l15 = lane & 15, l4 = lane >> 4;
    int m0 = mc * 1024;

    for (int i = tid; i < 1024; i += 256) {
        float a0 = coords[((size_t)b * 3 + 0) * NN + m0 + i];
        float a1 = coords[((size_t)b * 3 + 1) * NN + m0 + i];
        float a2 = coords[((size_t)b * 3 + 2) * NN + m0 + i];
        float inv = 1.0f / fmaxf(sqrtf(a0 * a0 + a1 * a1 + a2 * a2), 1e-12f);
        cm[0][i] = a0 * inv; cm[1][i] = a1 * inv; cm[2][i] = a2 * inv;
    }

    int n = nt * 64 + w * 16 + l15;
    float q0 = coords[((size_t)b * 3 + 0) * NN + n];
    float q1 = coords[((size_t)b * 3 + 1) * NN + n];
    float q2 = coords[((size_t)b * 3 + 2) * NN + n];
    float qi = 10.0f / fmaxf(sqrtf(q0 * q0 + q1 * q1 + q2 * q2), 1e-12f);
    q0 *= qi; q1 *= qi; q2 *= qi;

    // A stage addressing: thread -> (row = tid>>2, slot = tid&3); source colgroup
    // g0 = slot ^ ((row>>1)&3) so that reader (row, l4) finds colgroup l4 at
    // slot l4 ^ ((row>>1)&3). 16 rows x 4 slots -> 2-way bank aliasing (free).
    int srow = tid >> 2, sslot = tid & 3;
    int g0 = sslot ^ ((srow >> 1) & 3);
    const ushort_t* fb = featb + (size_t)b * 64 * NN + m0;
    const ushort_t* sbase = fb + (size_t)srow * NN + g0 * 8;
    int rsw = (l15 >> 1) & 3;  // (row>>1)&3 for row = cb*16+l15 (cb*16 keeps bits 1,2)

    v4f acc[4];
    #pragma unroll
    for (int cb = 0; cb < 4; cb++) acc[cb] = (v4f){0.0f, 0.0f, 0.0f, 0.0f};
    float den = 0.0f;

    // prologue: stage t=0
    gll16(sbase, &la[0][(size_t)tid * 8]);
    asm volatile("s_waitcnt vmcnt(0)" ::: "memory");
    __syncthreads();   // covers cm writes + stage(0)

    for (int t = 0; t < 32; t++) {
        int cur = t & 1;
        if (t + 1 < 32)
            gll16(sbase + (t + 1) * 32, &la[cur ^ 1][(size_t)tid * 8]);

        int mo = t * 32 + l4 * 8;
        float e[8];
        #pragma unroll
        for (int jj = 0; jj < 2; jj++) {
            float4 x0 = *(const float4*)&cm[0][mo + jj * 4];
            float4 x1 = *(const float4*)&cm[1][mo + jj * 4];
            float4 x2 = *(const float4*)&cm[2][mo + jj * 4];
            e[jj * 4 + 0] = __expf(q0 * x0.x + q1 * x1.x + q2 * x2.x);
            e[jj * 4 + 1] = __expf(q0 * x0.y + q1 * x1.y + q2 * x2.y);
            e[jj * 4 + 2] = __expf(q0 * x0.z + q1 * x1.z + q2 * x2.z);
            e[jj * 4 + 3] = __expf(q0 * x0.w + q1 * x1.w + q2 * x2.w);
        }
        den += ((e[0] + e[1]) + (e[2] + e[3])) + ((e[4] + e[5]) + (e[6] + e[7]));
        union { __hip_bfloat162 h[4]; v8s v; } pk;
        pk.h[0] = __float22bfloat162_rn(make_float2(e[0], e[1]));
        pk.h[1] = __float22bfloat162_rn(make_float2(e[2], e[3]));
        pk.h[2] = __float22bfloat162_rn(make_float2(e[4], e[5]));
        pk.h[3] = __float22bfloat162_rn(make_float2(e[6], e[7]));
        #pragma unroll
        for (int cb = 0; cb < 4; cb++) {
            v8s A = *(const v8s*)&la[cur][(size_t)((cb * 16 + l15) * 4 + (l4 ^ rsw)) * 8];
            acc[cb] = __builtin_amdgcn_mfma_f32_16x16x32_bf16(A, pk.v, acc[cb], 0, 0, 0);
        }
        asm volatile("s_waitcnt vmcnt(0)" ::: "memory");
        __syncthreads();
    }

    den += __shfl_xor(den, 16);
    den += __shfl_xor(den, 32);

    size_t obase = ((size_t)(b * 4 + mc)) * 64 * NN;
    #pragma unroll
    for (int cb = 0; cb < 4; cb++)
        #pragma unroll
        for (int r = 0; r < 4; r++)
            pnum[obase + (size_t)(cb * 16 + l4 * 4 + r) * NN + n] = acc[cb][r];
    if (l4 == 0) pden[((size_t)(b * 4 + mc)) * NN + n] = den;
}

__global__ void k_combine2(const float* __restrict__ pnum, const float* __restrict__ pden,
                           float* __restrict__ fzf) {
    int i = blockIdx.x * 256 + threadIdx.x;
    int b = i >> 18, c = (i >> 12) & 63, n = i & 4095;
    float num = 0, den = 0;
    #pragma unroll
    for (int ch = 0; ch < 4; ch++) {
        num += pnum[((size_t)(b * 4 + ch) * 64 + c) * NN + n];
        den += pden[((size_t)(b * 4 + ch)) * NN + n];
    }
    fzf[((size_t)(b * 64 + c)) * NN + n] = num / den;
}

// ---------------- 1x1 convs v3: thread = 4n x 1o, partial stats ----------------
__global__ __launch_bounds__(256) void k_1x1s(const float* __restrict__ in,
                                              const float* __restrict__ wT,
                                              const float* __restrict__ bias,
                                              float* __restrict__ out,
                                              float* __restrict__ pst) {
    int b = blockIdx.z, ob = blockIdx.y, bx = blockIdx.x;
    int tid = threadIdx.x;
    int q = tid & 15, o = ob * 16 + (tid >> 4);
    int n = bx * 64 + q * 4;
    const float* src = in + (size_t)b * 64 * NN + n;
    const float* wp_ = wT + o;
    v4f acc = {0, 0, 0, 0};
    #pragma unroll 8
    for (int c = 0; c < 64; c++) {
        float4 x = *(const float4*)&src[(size_t)c * NN];
        float w = wp_[c * 64];
        acc[0] += x.x * w; acc[1] += x.y * w; acc[2] += x.z * w; acc[3] += x.w * w;
    }
    float bv = bias[o];
    float s = 0, q2 = 0;
    float4 ov;
    float* op = (float*)&ov;
    #pragma unroll
    for (int v = 0; v < 4; v++) {
        float val = acc[v] + bv;
        op[v] = val;
        s += val; q2 += val * val;
    }
    *(float4*)&out[((size_t)(b * 64 + o)) * NN + n] = ov;
    #pragma unroll
    for (int off = 1; off < 16; off <<= 1) {
        s += __shfl_xor(s, off);
        q2 += __shfl_xor(q2, off);
    }
    if (q == 0) {
        int part = bx * 4 + b;
        pst[(o * 256 + part) * 2] = s;
        pst[(o * 256 + part) * 2 + 1] = q2;
    }
}

// fusion: wfuT rows 0..63 (vox), 64..127 (pt with BN+relu), 128..191 (folded fzf)
__global__ __launch_bounds__(256) void k_1x1f(const float* __restrict__ vox,
                                              const float* __restrict__ pt,
                                              const float* __restrict__ fzf,
                                              const float* __restrict__ bnB,
                                              const float* __restrict__ wfuT,
                                              const float* __restrict__ bC,
                                              float* __restrict__ out,
                                              float* __restrict__ pst) {
    int b = blockIdx.z, ob = blockIdx.y, bx = blockIdx.x;
    int tid = threadIdx.x;
    int q = tid & 15, o = ob * 16 + (tid >> 4);
    int n = bx * 64 + q * 4;
    const float* srcA = vox + (size_t)b * 64 * NN + n;
    const float* srcB = pt + (size_t)b * 64 * NN + n;
    const float* srcC = fzf + (size_t)b * 64 * NN + n;
    const float* wA = wfuT + o;
    v4f acc = {0, 0, 0, 0};
    #pragma unroll 8
    for (int c = 0; c < 64; c++) {
        float4 x = *(const float4*)&srcA[(size_t)c * NN];
        float w = wA[c * 64];
        acc[0] += x.x * w; acc[1] += x.y * w; acc[2] += x.z * w; acc[3] += x.w * w;
    }
    #pragma unroll 8
    for (int c = 0; c < 64; c++) {
        float4 x = *(const float4*)&srcB[(size_t)c * NN];
        float sc = bnB[2 * c], sh = bnB[2 * c + 1];
        float w = wA[(64 + c) * 64];
        float x0 = fmaxf(x.x * sc + sh, 0.0f), x1 = fmaxf(x.y * sc + sh, 0.0f);
        float x2 = fmaxf(x.z * sc + sh, 0.0f), x3 = fmaxf(x.w * sc + sh, 0.0f);
        acc[0] += x0 * w; acc[1] += x1 * w; acc[2] += x2 * w; acc[3] += x3 * w;
    }
    #pragma unroll 8
    for (int c = 0; c < 64; c++) {
        float4 x = *(const float4*)&srcC[(size_t)c * NN];
        float w = wA[(128 + c) * 64];
        acc[0] += x.x * w; acc[1] += x.y * w; acc[2] += x.z * w; acc[3] += x.w * w;
    }
    float bv = bC[o];
    float s = 0, q2 = 0;
    float4 ov;
    float* op = (float*)&ov;
    #pragma unroll
    for (int v = 0; v < 4; v++) {
        float val = acc[v] + bv;
        op[v] = val;
        s += val; q2 += val * val;
    }
    *(float4*)&out[((size_t)(b * 64 + o)) * NN + n] = ov;
    #pragma unroll
    for (int off = 1; off < 16; off <<= 1) {
        s += __shfl_xor(s, off);
        q2 += __shfl_xor(q2, off);
    }
    if (q == 0) {
        int part = bx * 4 + b;
        pst[(o * 256 + part) * 2] = s;
        pst[(o * 256 + part) * 2 + 1] = q2;
    }
}

// ---------------- launcher ----------------
extern "C" void kernel_launch(void* const* d_in, const int* in_sizes, int n_in,
                              void* d_out, int out_size, void* d_ws, size_t ws_size,
                              hipStream_t stream) {
    const float* features = (const float*)d_in[0];
    const float* coords = (const float*)d_in[1];
    const float* w1 = (const float*)d_in[2];
    const float* g1 = (const float*)d_in[4];
    const float* be1 = (const float*)d_in[5];
    const float* w2 = (const float*)d_in[6];
    const float* g2 = (const float*)d_in[8];
    const float* be2 = (const float*)d_in[9];
    const float* wp = (const float*)d_in[10];
    const float* bp = (const float*)d_in[11];
    const float* gp = (const float*)d_in[12];
    const float* bep = (const float*)d_in[13];
    const float* wf = (const float*)d_in[14];
    const float* bf = (const float*)d_in[15];
    const float* wfu = (const float*)d_in[16];
    const float* bfu = (const float*)d_in[17];
    const float* gfu = (const float*)d_in[18];
    const float* befu = (const float*)d_in[19];

    float* ws = (float*)d_ws;
    float* nc = ws;                        // 49152
    int* vidx = (int*)(ws + 49152);        // 16384 ints
    float* cnt = ws + 65536;               // 131072 (pden overlays later)
    float* pden = cnt;
    float* gridA = ws + 196608;            // cf f32 scatter grid, then cl f32 conv out
    float* gridCL = gridA;
    float* gTpool = ws + 8585216;          // gT bf16 / pnum / pstB later
    ushort_t* gT = (ushort_t*)gTpool;
    float* pnum = gTpool;
    float* pstB = gTpool;                  // 32768 floats (after combine2, pool is dead)
    float* stats = ws + 16973824;          // 512 finalized (4 x 128)
    float* voxreg = ws + 16974336;         // wS1/wS2 until devox
    ushort_t* wS1 = (ushort_t*)voxreg;
    ushort_t* wS2 = wS1 + 110592;
    float* vox = voxreg;
    float* pt = ws + 18022912;
    float* fzf = ws + 19071488;
    float* wpT = ws + 20120064;            // 4096
    float* wfuT = wpT + 4096;              // 12288
    float* bC = wfuT + 12288;              // 64
    float* fpre = ws + 21168640;           // featb overlays
    ushort_t* featb = (ushort_t*)fpre;
    float* accs = ws + 22217216;           // 512 float stat accumulators (conv)

    float* out = (float*)d_out;

    hipMemsetAsync(accs, 0, 512 * 4, stream);
    hipMemsetAsync(cnt, 0, (size_t)(131072 + 8388608) * 4, stream);

    // prep
    k_fold<<<65, 256, 0, stream>>>(wp, wfu, wf, bf, bfu, wpT, wfuT, bC);
    k_f2b<<<BB * 64 * NN / 8 / 256, 256, 0, stream>>>(features, featb);
    k_tws<<<432, 256, 0, stream>>>(w1, wS1);
    k_tws<<<432, 256, 0, stream>>>(w2, wS2);
    k_nc<<<BB, 256, 0, stream>>>(coords, nc, vidx);
    k_scatter<<<BB * NN / 64, 256, 0, stream>>>(features, vidx, gridA, cnt);
    k_avgT<<<dim3(512, BB), 256, 0, stream>>>(gridA, cnt, gT);

    // voxel branch
    k_convlds<<<512, 256, 0, stream>>>(gT, wS1, gridCL, accs);
    k_bnfin<<<1, 64, 0, stream>>>(accs, g1, be1, stats, 1, 1.0f / (BB * R3));
    k_bncast<<<BB * R3 * 64 / 8 / 256, 256, 0, stream>>>(gridCL, stats, 0.1f, gT);
    k_convlds<<<512, 256, 0, stream>>>(gT, wS2, gridCL, accs + 128);
    k_bnfin<<<1, 64, 0, stream>>>(accs + 128, g2, be2, stats + 128, 1, 1.0f / (BB * R3));
    k_devox2<<<dim3(NN / 16, BB), 256, 0, stream>>>(gridCL, stats + 128, nc, vox);

    // fuzzy branch
    k_fuzzym<<<dim3(64, 4, BB), 256, 0, stream>>>(coords, featb, pnum, pden);
    k_combine2<<<BB * 64 * NN / 256, 256, 0, stream>>>(pnum, pden, fzf);

    // point branch (partial stats into pstB, overlaying the now-dead pnum pool)
    k_1x1s<<<dim3(NN / 64, 4, BB), 256, 0, stream>>>(features, wpT, bp, pt, pstB);
    k_bnfin2<<<64, 256, 0, stream>>>(pstB, gp, bep, stats + 256, 1.0f / (BB * NN));

    // fusion (wf folded into wfuT segC; pt BN on the fly; partial stats)
    k_1x1f<<<dim3(NN / 64, 4, BB), 256, 0, stream>>>(vox, pt, fzf, stats + 256, wfuT, bC,
                                                     fpre, pstB);
    k_bnfin2<<<64, 256, 0, stream>>>(pstB, gfu, befu, stats + 384, 1.0f / (BB * NN));
    k_bn_act<<<BB * 64 * NN / 4 / 256, 256, 0, stream>>>(fpre, stats + 384, out, 10, 0.0f);

    hipMemcpyAsync(out + (size_t)BB * CO * NN, coords, (size_t)BB * 3 * NN * 4,
                   hipMemcpyDeviceToDevice, stream);
}

// Round 11
// 287.912 us; speedup vs baseline: 1.7399x; 1.0137x over previous
//
#include <hip/hip_runtime.h>
#include <hip/hip_bf16.h>
#include <math.h>

#define RR 32
#define R3 32768
#define BB 4
#define CI 64
#define CO 64
#define NN 4096

typedef short v8s __attribute__((ext_vector_type(8)));
typedef float v4f __attribute__((ext_vector_type(4)));
typedef unsigned short ushort_t;

__device__ __forceinline__ unsigned short f2bf(float f) {
    unsigned int u = __float_as_uint(f);
    unsigned int r = (u + 0x7FFFu + ((u >> 16) & 1u)) >> 16;
    return (unsigned short)r;
}

__device__ __forceinline__ void gll16(const void* g, void* l) {
    __builtin_amdgcn_global_load_lds((const __attribute__((address_space(1))) unsigned int*)g,
                                     (__attribute__((address_space(3))) unsigned int*)l, 16, 0, 0);
}

// ---------------- block reduce helpers ----------------
__device__ __forceinline__ float blockReduceSum(float v, float* sm) {
    int tid = threadIdx.x;
    sm[tid] = v; __syncthreads();
    for (int off = 128; off > 0; off >>= 1) {
        if (tid < off) sm[tid] += sm[tid + off];
        __syncthreads();
    }
    float r = sm[0]; __syncthreads();
    return r;
}
__device__ __forceinline__ float blockReduceMax(float v, float* sm) {
    int tid = threadIdx.x;
    sm[tid] = v; __syncthreads();
    for (int off = 128; off > 0; off >>= 1) {
        if (tid < off) sm[tid] = fmaxf(sm[tid], sm[tid + off]);
        __syncthreads();
    }
    float r = sm[0]; __syncthreads();
    return r;
}

// ---------------- voxel coords ----------------
__global__ void k_nc(const float* __restrict__ coords, float* __restrict__ nc,
                     int* __restrict__ vidx) {
    int b = blockIdx.x, tid = threadIdx.x;
    __shared__ float sm[256];
    const float* cb = coords + (size_t)b * 3 * NN;
    float s0 = 0, s1 = 0, s2 = 0;
    for (int n = tid; n < NN; n += 256) {
        s0 += cb[n]; s1 += cb[NN + n]; s2 += cb[2 * NN + n];
    }
    float m0 = blockReduceSum(s0, sm) * (1.0f / NN);
    float m1 = blockReduceSum(s1, sm) * (1.0f / NN);
    float m2 = blockReduceSum(s2, sm) * (1.0f / NN);
    float mx = 0;
    for (int n = tid; n < NN; n += 256) {
        float dx = cb[n] - m0, dy = cb[NN + n] - m1, dz = cb[2 * NN + n] - m2;
        mx = fmaxf(mx, dx * dx + dy * dy + dz * dz);
    }
    mx = blockReduceMax(mx, sm);
    float denom = 2.0f * sqrtf(mx);
    float mean[3] = {m0, m1, m2};
    for (int n = tid; n < NN; n += 256) {
        int vi[3];
        #pragma unroll
        for (int ax = 0; ax < 3; ax++) {
            float x = (cb[ax * NN + n] - mean[ax]) / denom + 0.5f;
            x = x * RR;
            x = fminf(fmaxf(x, 0.0f), (float)(RR - 1));
            nc[((size_t)b * 3 + ax) * NN + n] = x;
            vi[ax] = (int)rintf(x);
        }
        vidx[b * NN + n] = (vi[0] * RR + vi[1]) * RR + vi[2];
    }
}

// ---------------- scatter-mean v2: one thread per (point, channel) ----------------
__global__ void k_scatter(const float* __restrict__ feat, const int* __restrict__ vidx,
                          float* __restrict__ grid, float* __restrict__ cnt) {
    int i = blockIdx.x * 256 + threadIdx.x;   // over BB*64*NN = 1048576
    int n = i & (NN - 1);
    int c = (i >> 12) & 63;
    int b = i >> 18;
    int idx = vidx[b * NN + n];
    atomicAdd(&grid[((size_t)(b * 64 + c)) * R3 + idx], feat[((size_t)(b * 64 + c)) * NN + n]);
    if (c == 0) atomicAdd(&cnt[b * R3 + idx], 1.0f);
}

// ---------------- divide + transpose + bf16 cast: cf f32 -> cl bf16 ----------------
__global__ void k_avgT(const float* __restrict__ grid, const float* __restrict__ cnt,
                       ushort_t* __restrict__ gT) {
    __shared__ float ld[64][65];
    int b = blockIdx.y, s0 = blockIdx.x * 64, tid = threadIdx.x;
    int sl = tid & 63, cq = tid >> 6;
    const float* xb = grid + (size_t)b * 64 * R3;
    #pragma unroll
    for (int k = 0; k < 16; k++) {
        int c = cq * 16 + k;
        ld[sl][c] = xb[(size_t)c * R3 + s0 + sl];
    }
    __syncthreads();
    int v = tid >> 2, q = tid & 3;
    float inv = 1.0f / fmaxf(cnt[b * R3 + s0 + v], 1.0f);
    unsigned int pk[8];
    #pragma unroll
    for (int j = 0; j < 8; j++) {
        int c = q * 16 + j * 2;
        float a = ld[v][c] * inv, d = ld[v][c + 1] * inv;
        pk[j] = (unsigned int)f2bf(a) | ((unsigned int)f2bf(d) << 16);
    }
    uint4* op = (uint4*)(gT + ((size_t)(b * R3 + s0 + v)) * 64 + q * 16);
    op[0] = make_uint4(pk[0], pk[1], pk[2], pk[3]);
    op[1] = make_uint4(pk[4], pk[5], pk[6], pk[7]);
}

// ---------------- features f32 -> bf16 ----------------
__global__ void k_f2b(const float* __restrict__ x, ushort_t* __restrict__ o) {
    size_t i = (size_t)blockIdx.x * 256 + threadIdx.x;
    float4 a = ((const float4*)x)[i * 2];
    float4 b = ((const float4*)x)[i * 2 + 1];
    union { __hip_bfloat162 h[4]; uint4 u; } pk;
    pk.h[0] = __float22bfloat162_rn(make_float2(a.x, a.y));
    pk.h[1] = __float22bfloat162_rn(make_float2(a.z, a.w));
    pk.h[2] = __float22bfloat162_rn(make_float2(b.x, b.y));
    pk.h[3] = __float22bfloat162_rn(make_float2(b.z, b.w));
    ((uint4*)o)[i] = pk.u;
}

// ---------------- weight transform: wS[dzdy 9][cih 2][dx 3][co 64][cis 32] bf16 ----------------
__global__ void k_tws(const float* __restrict__ w, ushort_t* __restrict__ wS) {
    int i = blockIdx.x * 256 + threadIdx.x;  // 110592
    int cis = i & 31, co = (i >> 5) & 63;
    int dx = (i >> 11) % 3, cih = (i / 6144) & 1, dzdy = i / 12288;
    int k = dzdy * 3 + dx, ci = cih * 32 + cis;
    wS[i] = f2bf(w[((size_t)co * CI + ci) * 27 + k]);
}

// ---------------- weight fold/transposes for 1x1 kernels ----------------
__global__ void k_fold(const float* __restrict__ wp, const float* __restrict__ wfu,
                       const float* __restrict__ wf, const float* __restrict__ bf,
                       const float* __restrict__ bfu,
                       float* __restrict__ wpT, float* __restrict__ wfuT,
                       float* __restrict__ bC) {
    int i = blockIdx.x * 256 + threadIdx.x;
    if (i < 4096) {
        int c = i >> 6, o = i & 63;
        wpT[c * 64 + o] = wp[o * 64 + c];
    } else if (i < 12288) {
        int j = i - 4096;
        int c = j >> 6, o = j & 63;
        wfuT[c * 64 + o] = wfu[(size_t)o * 192 + c];
    } else if (i < 16384) {
        int j = i - 12288;
        int c = j >> 6, o = j & 63;
        float s = 0;
        for (int k = 0; k < 64; k++)
            s += wfu[(size_t)o * 192 + 128 + k] * wf[(size_t)k * 64 + c];
        wfuT[(128 + c) * 64 + o] = s;
    } else if (i < 16448) {
        int o = i - 16384;
        float s = bfu[o];
        for (int k = 0; k < 64; k++)
            s += wfu[(size_t)o * 192 + 128 + k] * bf[k];
        bC[o] = s;
    }
}

// ---------------- BN(from accs) + lrelu + bf16 cast (cl -> cl) ----------------
__global__ void k_bncast(const float* __restrict__ x, const float* __restrict__ accs,
                         const float* __restrict__ g, const float* __restrict__ be,
                         float invcnt, float slope, ushort_t* __restrict__ o) {
    size_t i = (size_t)blockIdx.x * 256 + threadIdx.x;  // over B*R3*64/8
    int c0 = (int)((i * 8) & 63);
    float sc[8], sh[8];
    #pragma unroll
    for (int j = 0; j < 8; j++) {
        int c = c0 + j;
        float mean = accs[2 * c] * invcnt;
        float var = accs[2 * c + 1] * invcnt - mean * mean;
        float scale = g[c] * rsqrtf(var + 1e-4f);
        sc[j] = scale;
        sh[j] = be[c] - mean * scale;
    }
    float4 a = ((const float4*)x)[i * 2];
    float4 d = ((const float4*)x)[i * 2 + 1];
    float va[8] = {a.x, a.y, a.z, a.w, d.x, d.y, d.z, d.w};
    unsigned pk[4];
    #pragma unroll
    for (int j = 0; j < 4; j++) {
        float u0 = va[2 * j] * sc[2 * j] + sh[2 * j];
        float u1 = va[2 * j + 1] * sc[2 * j + 1] + sh[2 * j + 1];
        u0 = u0 > 0 ? u0 : slope * u0;
        u1 = u1 > 0 ? u1 : slope * u1;
        pk[j] = (unsigned)f2bf(u0) | ((unsigned)f2bf(u1) << 16);
    }
    ((uint4*)o)[i] = make_uint4(pk[0], pk[1], pk[2], pk[3]);
}

// ---------------- LDS-staged MFMA conv3d 3x3x3, fused BN-stats epilogue ----------------
__global__ __launch_bounds__(256) void k_convlds(const ushort_t* __restrict__ gT,
                                                 const ushort_t* __restrict__ wS,
                                                 float* __restrict__ outCL,
                                                 float* __restrict__ accs) {
    __shared__ ushort_t lin[20480];     // 40960B input plane (also reused as stats buf)
    __shared__ ushort_t lw[2][6144];    // 2 x 12288B weights
    int bid = blockIdx.x;
    int wgid = (bid & 7) * 64 + (bid >> 3);
    int yt = wgid & 3, z0 = (wgid >> 2) & 31, b = wgid >> 7;
    int tid = threadIdx.x;
    int w = __builtin_amdgcn_readfirstlane(tid >> 6);
    int lane = tid & 63, l15 = lane & 15, l4 = lane >> 4;
    int y0 = yt * 8;
    const ushort_t* gTb = gT + (size_t)b * R3 * 64;

    int voxF[4];
    #pragma unroll
    for (int f = 0; f < 4; f++)
        voxF[f] = (w * 2 + (f >> 1)) * 32 + (f & 1) * 16 + l15 - 1;
    bool xlo_ok = (l15 != 0), xhi_ok = (l15 != 15);

    const v8s vzero = {};
    v4f acc[4][4];
    #pragma unroll
    for (int m = 0; m < 4; m++)
        #pragma unroll
        for (int f = 0; f < 4; f++)
            acc[m][f] = (v4f){0.0f, 0.0f, 0.0f, 0.0f};

#define WSTAGE(s)                                                              \
    do {                                                                       \
        const ushort_t* _src = wS + (size_t)(s) * 6144;                        \
        ushort_t* _dst = lw[(s) & 1];                                          \
        _Pragma("unroll") for (int _i = 0; _i < 3; _i++) {                     \
            int _p = _i * 256 + w * 64;                                        \
            gll16(_src + (size_t)(_p + lane) * 8, _dst + (size_t)_p * 8);      \
        }                                                                      \
    } while (0)

#define ISTAGE(dz)                                                             \
    do {                                                                       \
        int _zp = z0 - 1 + (dz);                                               \
        if (_zp < 0 || _zp > 31) {                                             \
            for (int _q = 0; _q < 10; _q++)                                    \
                *(v8s*)&lin[(size_t)(w * 640 + _q * 64 + lane) * 8] = vzero;   \
        } else {                                                               \
            if (yt == 0) *(v8s*)&lin[(size_t)tid * 8] = vzero;                 \
            if (yt == 3) *(v8s*)&lin[(size_t)(2304 + tid) * 8] = vzero;        \
            const ushort_t* _pb = gTb + ((size_t)_zp * 1024 + (size_t)(y0 - 1) * 32) * 64; \
            int _g0 = (yt == 0) ? 256 : 0;                                     \
            int _nc = 10 - (yt == 0) - (yt == 3);                              \
            for (int _i = 0; _i < _nc; _i++) {                                 \
                int _pbase = _g0 + _i * 256 + w * 64;                          \
                int _p = _pbase + lane;                                        \
                int _vx = _p >> 3, _js = _p & 7;                               \
                int _sg = _vx * 8 + (_js ^ (_vx & 7));                         \
                gll16(_pb + (size_t)_sg * 8, lin + (size_t)_pbase * 8);        \
            }                                                                  \
        }                                                                      \
    } while (0)

    WSTAGE(0);
    for (int s = 0; s < 18; s++) {
        int dy = (s / 2) % 3, cih = s & 1;
        asm volatile("s_barrier" ::: "memory");
        if ((s % 6) == 0) ISTAGE(s / 6);
        if (s + 1 < 18) WSTAGE(s + 1);
        if (s + 1 < 18) asm volatile("s_waitcnt vmcnt(3) lgkmcnt(0)" ::: "memory");
        else            asm volatile("s_waitcnt vmcnt(0) lgkmcnt(0)" ::: "memory");
        asm volatile("s_barrier" ::: "memory");

        const ushort_t* lwb = lw[s & 1];
        #pragma unroll
        for (int dx = 0; dx < 3; dx++) {
            v8s Bf[4];
            #pragma unroll
            for (int f = 0; f < 4; f++) {
                int vox = voxF[f] + dy * 32 + dx;
                int g = vox * 8 + ((cih * 4 + l4) ^ (vox & 7));
                int bix = g * 16;
                bix = bix < 0 ? 0 : bix;
                v8s vb = *(const v8s*)((const char*)lin + bix);
                bool ok = (dx == 0 && (f & 1) == 0) ? xlo_ok :
                          (dx == 2 && (f & 1) == 1) ? xhi_ok : true;
                Bf[f] = ok ? vb : vzero;
            }
            const ushort_t* ap = lwb + dx * 2048 + l15 * 32 + l4 * 8;
            #pragma unroll
            for (int m = 0; m < 4; m++) {
                v8s Af = *(const v8s*)(ap + m * 512);
                #pragma unroll
                for (int f = 0; f < 4; f++)
                    acc[m][f] = __builtin_amdgcn_mfma_f32_16x16x32_bf16(Af, Bf[f], acc[m][f], 0, 0, 0);
            }
        }
    }

    // channel-last f4 stores
    #pragma unroll
    for (int m = 0; m < 4; m++) {
        #pragma unroll
        for (int f = 0; f < 4; f++) {
            int y = y0 + w * 2 + (f >> 1);
            int x = (f & 1) * 16 + l15;
            float4 o = make_float4(acc[m][f][0], acc[m][f][1], acc[m][f][2], acc[m][f][3]);
            *(float4*)&outCL[((size_t)b * R3 + z0 * 1024 + y * 32 + x) * 64 + m * 16 + l4 * 4] = o;
        }
    }

    // ---- fused BN-stats: per-block sum/sumsq per co -> atomics ----
    __syncthreads();
    float* sbuf = (float*)lin;
    #pragma unroll
    for (int m = 0; m < 4; m++)
        #pragma unroll
        for (int r = 0; r < 4; r++) {
            float s = 0, q = 0;
            #pragma unroll
            for (int f = 0; f < 4; f++) {
                float v = acc[m][f][r];
                s += v; q += v * v;
            }
            sbuf[tid * 32 + (m * 4 + r) * 2] = s;
            sbuf[tid * 32 + (m * 4 + r) * 2 + 1] = q;
        }
    __syncthreads();
    if (tid < 128) {
        int co = tid >> 1, val = tid & 1;
        int m = co >> 4, cl4 = (co >> 2) & 3, r = co & 3;
        float a = 0;
        for (int w2 = 0; w2 < 4; w2++)
            for (int l = 0; l < 16; l++)
                a += sbuf[(w2 * 64 + cl4 * 16 + l) * 32 + (m * 4 + r) * 2 + val];
        atomicAdd(&accs[2 * co + val], a);
    }
#undef WSTAGE
#undef ISTAGE
}

// reduce 256 partials per channel (one block per channel)
__global__ void k_bnfin2(const float* __restrict__ pst, const float* __restrict__ g,
                         const float* __restrict__ be, float* __restrict__ stats,
                         float invcnt) {
    int c = blockIdx.x, tid = threadIdx.x;
    __shared__ float rs[256], rq[256];
    rs[tid] = pst[(c * 256 + tid) * 2];
    rq[tid] = pst[(c * 256 + tid) * 2 + 1];
    __syncthreads();
    for (int off = 128; off > 0; off >>= 1) {
        if (tid < off) { rs[tid] += rs[tid + off]; rq[tid] += rq[tid + off]; }
        __syncthreads();
    }
    if (tid == 0) {
        float mean = rs[0] * invcnt;
        float var = rq[0] * invcnt - mean * mean;
        float sc = g[c] * rsqrtf(var + 1e-4f);
        stats[2 * c] = sc;
        stats[2 * c + 1] = be[c] - mean * sc;
    }
}

__global__ void k_bn_act(const float* __restrict__ x, const float* __restrict__ stats,
                         float* __restrict__ out, int shift, float slope) {
    size_t i = (size_t)blockIdx.x * 256 + threadIdx.x;
    int c = (int)((i >> shift) & 63);
    float sc = stats[2 * c], sh = stats[2 * c + 1];
    float4 v = ((const float4*)x)[i];
    v.x = v.x * sc + sh; v.y = v.y * sc + sh; v.z = v.z * sc + sh; v.w = v.w * sc + sh;
    v.x = v.x > 0 ? v.x : slope * v.x;
    v.y = v.y > 0 ? v.y : slope * v.y;
    v.z = v.z > 0 ? v.z : slope * v.z;
    v.w = v.w > 0 ? v.w : slope * v.w;
    ((float4*)out)[i] = v;
}

// ---------------- devoxelize, BN(from accs)+lrelu fused, channel-last gather ----------------
__global__ void k_devox2(const float* __restrict__ gcl, const float* __restrict__ accs,
                         const float* __restrict__ g, const float* __restrict__ be,
                         float invcnt, const float* __restrict__ nc,
                         float* __restrict__ out) {
    int b = blockIdx.y;
    int tid = threadIdx.x, p = tid >> 4, q = tid & 15;
    int n = blockIdx.x * 16 + p;
    float x = nc[((size_t)b * 3 + 0) * NN + n];
    float y = nc[((size_t)b * 3 + 1) * NN + n];
    float z = nc[((size_t)b * 3 + 2) * NN + n];
    float fx = floorf(x), fy = floorf(y), fz = floorf(z);
    int lx = (int)fx, ly = (int)fy, lz = (int)fz;
    int hx = min(lx + 1, RR - 1), hy = min(ly + 1, RR - 1), hz = min(lz + 1, RR - 1);
    float frx = x - fx, fry = y - fy, frz = z - fz;
    int xx[2] = {lx, hx}, yy[2] = {ly, hy}, zz[2] = {lz, hz};
    float wx[2] = {1.0f - frx, frx}, wy[2] = {1.0f - fry, fry}, wz[2] = {1.0f - frz, frz};
    float sc[4], sh[4];
    #pragma unroll
    for (int j = 0; j < 4; j++) {
        int c = q * 4 + j;
        float mean = accs[2 * c] * invcnt;
        float var = accs[2 * c + 1] * invcnt - mean * mean;
        float scale = g[c] * rsqrtf(var + 1e-4f);
        sc[j] = scale;
        sh[j] = be[c] - mean * scale;
    }
    float a0 = 0, a1 = 0, a2 = 0, a3 = 0;
    #pragma unroll
    for (int dx = 0; dx < 2; dx++)
        #pragma unroll
        for (int dy = 0; dy < 2; dy++)
            #pragma unroll
            for (int dz = 0; dz < 2; dz++) {
                int idx = (xx[dx] * RR + yy[dy]) * RR + zz[dz];
                float wt = wx[dx] * wy[dy] * wz[dz];
                float4 v = *(const float4*)&gcl[((size_t)b * R3 + idx) * 64 + q * 4];
                float u0 = v.x * sc[0] + sh[0]; u0 = u0 > 0 ? u0 : 0.1f * u0;
                float u1 = v.y * sc[1] + sh[1]; u1 = u1 > 0 ? u1 : 0.1f * u1;
                float u2 = v.z * sc[2] + sh[2]; u2 = u2 > 0 ? u2 : 0.1f * u2;
                float u3 = v.w * sc[3] + sh[3]; u3 = u3 > 0 ? u3 : 0.1f * u3;
                a0 += wt * u0; a1 += wt * u1; a2 += wt * u2; a3 += wt * u3;
            }
    out[((size_t)(b * 64 + q * 4 + 0)) * NN + n] = a0;
    out[((size_t)(b * 64 + q * 4 + 1)) * NN + n] = a1;
    out[((size_t)(b * 64 + q * 4 + 2)) * NN + n] = a2;
    out[((size_t)(b * 64 + q * 4 + 3)) * NN + n] = a3;
}

// ---------------- fuzzy attention (MFMA) v5: A staged in LDS, double-buffered ----------------
__global__ __launch_bounds__(256) void k_fuzzym(const float* __restrict__ coords,
                                                const ushort_t* __restrict__ featb,
                                                float* __restrict__ pnum,
                                                float* __restrict__ pden) {
    __shared__ float cm[3][1024];        // 12 KB
    __shared__ ushort_t la[2][2048];     // 2 x 4 KB A ring
    int b = blockIdx.z, mc = blockIdx.y, nt = blockIdx.x;
    int tid = threadIdx.x;
    int w = tid >> 6, lane = tid & 63, l15 = lane & 15, l4 = lane >> 4;
    int m0 = mc * 1024;

    for (int i = tid; i < 1024; i += 256) {
        float a0 = coords[((size_t)b * 3 + 0) * NN + m0 + i];
        float a1 = coords[((size_t)b * 3 + 1) * NN + m0 + i];
        float a2 = coords[((size_t)b * 3 + 2) * NN + m0 + i];
        float inv = 1.0f / fmaxf(sqrtf(a0 * a0 + a1 * a1 + a2 * a2), 1e-12f);
        cm[0][i] = a0 * inv; cm[1][i] = a1 * inv; cm[2][i] = a2 * inv;
    }

    int n = nt * 64 + w * 16 + l15;
    float q0 = coords[((size_t)b * 3 + 0) * NN + n];
    float q1 = coords[((size_t)b * 3 + 1) * NN + n];
    float q2 = coords[((size_t)b * 3 + 2) * NN + n];
    float qi = 10.0f / fmaxf(sqrtf(q0 * q0 + q1 * q1 + q2 * q2), 1e-12f);
    q0 *= qi; q1 *= qi; q2 *= qi;

    int srow = tid >> 2, sslot = tid & 3;
    int g0 = sslot ^ ((srow >> 1) & 3);
    const ushort_t* fb = featb + (size_t)b * 64 * NN + m0;
    const ushort_t* sbase = fb + (size_t)srow * NN + g0 * 8;
    int rsw = (l15 >> 1) & 3;

    v4f acc[4];
    #pragma unroll
    for (int cb = 0; cb < 4; cb++) acc[cb] = (v4f){0.0f, 0.0f, 0.0f, 0.0f};
    float den = 0.0f;

    gll16(sbase, &la[0][(size_t)tid * 8]);
    asm volatile("s_waitcnt vmcnt(0)" ::: "memory");
    __syncthreads();

    for (int t = 0; t < 32; t++) {
        int cur = t & 1;
        if (t + 1 < 32)
            gll16(sbase + (t + 1) * 32, &la[cur ^ 1][(size_t)tid * 8]);

        int mo = t * 32 + l4 * 8;
        float e[8];
        #pragma unroll
        for (int jj = 0; jj < 2; jj++) {
            float4 x0 = *(const float4*)&cm[0][mo + jj * 4];
            float4 x1 = *(const float4*)&cm[1][mo + jj * 4];
            float4 x2 = *(const float4*)&cm[2][mo + jj * 4];
            e[jj * 4 + 0] = __expf(q0 * x0.x + q1 * x1.x + q2 * x2.x);
            e[jj * 4 + 1] = __expf(q0 * x0.y + q1 * x1.y + q2 * x2.y);
            e[jj * 4 + 2] = __expf(q0 * x0.z + q1 * x1.z + q2 * x2.z);
            e[jj * 4 + 3] = __expf(q0 * x0.w + q1 * x1.w + q2 * x2.w);
        }
        den += ((e[0] + e[1]) + (e[2] + e[3])) + ((e[4] + e[5]) + (e[6] + e[7]));
        union { __hip_bfloat162 h[4]; v8s v; } pk;
        pk.h[0] = __float22bfloat162_rn(make_float2(e[0], e[1]));
        pk.h[1] = __float22bfloat162_rn(make_float2(e[2], e[3]));
        pk.h[2] = __float22bfloat162_rn(make_float2(e[4], e[5]));
        pk.h[3] = __float22bfloat162_rn(make_float2(e[6], e[7]));
        #pragma unroll
        for (int cb = 0; cb < 4; cb++) {
            v8s A = *(const v8s*)&la[cur][(size_t)((cb * 16 + l15) * 4 + (l4 ^ rsw)) * 8];
            acc[cb] = __builtin_amdgcn_mfma_f32_16x16x32_bf16(A, pk.v, acc[cb], 0, 0, 0);
        }
        asm volatile("s_waitcnt vmcnt(0)" ::: "memory");
        __syncthreads();
    }

    den += __shfl_xor(den, 16);
    den += __shfl_xor(den, 32);

    size_t obase = ((size_t)(b * 4 + mc)) * 64 * NN;
    #pragma unroll
    for (int cb = 0; cb < 4; cb++)
        #pragma unroll
        for (int r = 0; r < 4; r++)
            pnum[obase + (size_t)(cb * 16 + l4 * 4 + r) * NN + n] = acc[cb][r];
    if (l4 == 0) pden[((size_t)(b * 4 + mc)) * NN + n] = den;
}

__global__ void k_combine2(const float* __restrict__ pnum, const float* __restrict__ pden,
                           float* __restrict__ fzf) {
    int i = blockIdx.x * 256 + threadIdx.x;
    int b = i >> 18, c = (i >> 12) & 63, n = i & 4095;
    float num = 0, den = 0;
    #pragma unroll
    for (int ch = 0; ch < 4; ch++) {
        num += pnum[((size_t)(b * 4 + ch) * 64 + c) * NN + n];
        den += pden[((size_t)(b * 4 + ch)) * NN + n];
    }
    fzf[((size_t)(b * 64 + c)) * NN + n] = num / den;
}

// ---------------- 1x1 convs: thread = 4n x 1o, partial stats ----------------
__global__ __launch_bounds__(256) void k_1x1s(const float* __restrict__ in,
                                              const float* __restrict__ wT,
                                              const float* __restrict__ bias,
                                              float* __restrict__ out,
                                              float* __restrict__ pst) {
    int b = blockIdx.z, ob = blockIdx.y, bx = blockIdx.x;
    int tid = threadIdx.x;
    int q = tid & 15, o = ob * 16 + (tid >> 4);
    int n = bx * 64 + q * 4;
    const float* src = in + (size_t)b * 64 * NN + n;
    const float* wp_ = wT + o;
    v4f acc = {0, 0, 0, 0};
    #pragma unroll 8
    for (int c = 0; c < 64; c++) {
        float4 x = *(const float4*)&src[(size_t)c * NN];
        float w = wp_[c * 64];
        acc[0] += x.x * w; acc[1] += x.y * w; acc[2] += x.z * w; acc[3] += x.w * w;
    }
    float bv = bias[o];
    float s = 0, q2 = 0;
    float4 ov;
    float* op = (float*)&ov;
    #pragma unroll
    for (int v = 0; v < 4; v++) {
        float val = acc[v] + bv;
        op[v] = val;
        s += val; q2 += val * val;
    }
    *(float4*)&out[((size_t)(b * 64 + o)) * NN + n] = ov;
    #pragma unroll
    for (int off = 1; off < 16; off <<= 1) {
        s += __shfl_xor(s, off);
        q2 += __shfl_xor(q2, off);
    }
    if (q == 0) {
        int part = bx * 4 + b;
        pst[(o * 256 + part) * 2] = s;
        pst[(o * 256 + part) * 2 + 1] = q2;
    }
}

// fusion: wfuT rows 0..63 (vox), 64..127 (pt with BN+relu), 128..191 (folded fzf)
__global__ __launch_bounds__(256) void k_1x1f(const float* __restrict__ vox,
                                              const float* __restrict__ pt,
                                              const float* __restrict__ fzf,
                                              const float* __restrict__ bnB,
                                              const float* __restrict__ wfuT,
                                              const float* __restrict__ bC,
                                              float* __restrict__ out,
                                              float* __restrict__ pst) {
    int b = blockIdx.z, ob = blockIdx.y, bx = blockIdx.x;
    int tid = threadIdx.x;
    int q = tid & 15, o = ob * 16 + (tid >> 4);
    int n = bx * 64 + q * 4;
    const float* srcA = vox + (size_t)b * 64 * NN + n;
    const float* srcB = pt + (size_t)b * 64 * NN + n;
    const float* srcC = fzf + (size_t)b * 64 * NN + n;
    const float* wA = wfuT + o;
    v4f acc = {0, 0, 0, 0};
    #pragma unroll 8
    for (int c = 0; c < 64; c++) {
        float4 x = *(const float4*)&srcA[(size_t)c * NN];
        float w = wA[c * 64];
        acc[0] += x.x * w; acc[1] += x.y * w; acc[2] += x.z * w; acc[3] += x.w * w;
    }
    #pragma unroll 8
    for (int c = 0; c < 64; c++) {
        float4 x = *(const float4*)&srcB[(size_t)c * NN];
        float sc = bnB[2 * c], sh = bnB[2 * c + 1];
        float w = wA[(64 + c) * 64];
        float x0 = fmaxf(x.x * sc + sh, 0.0f), x1 = fmaxf(x.y * sc + sh, 0.0f);
        float x2 = fmaxf(x.z * sc + sh, 0.0f), x3 = fmaxf(x.w * sc + sh, 0.0f);
        acc[0] += x0 * w; acc[1] += x1 * w; acc[2] += x2 * w; acc[3] += x3 * w;
    }
    #pragma unroll 8
    for (int c = 0; c < 64; c++) {
        float4 x = *(const float4*)&srcC[(size_t)c * NN];
        float w = wA[(128 + c) * 64];
        acc[0] += x.x * w; acc[1] += x.y * w; acc[2] += x.z * w; acc[3] += x.w * w;
    }
    float bv = bC[o];
    float s = 0, q2 = 0;
    float4 ov;
    float* op = (float*)&ov;
    #pragma unroll
    for (int v = 0; v < 4; v++) {
        float val = acc[v] + bv;
        op[v] = val;
        s += val; q2 += val * val;
    }
    *(float4*)&out[((size_t)(b * 64 + o)) * NN + n] = ov;
    #pragma unroll
    for (int off = 1; off < 16; off <<= 1) {
        s += __shfl_xor(s, off);
        q2 += __shfl_xor(q2, off);
    }
    if (q == 0) {
        int part = bx * 4 + b;
        pst[(o * 256 + part) * 2] = s;
        pst[(o * 256 + part) * 2 + 1] = q2;
    }
}

// ---------------- launcher ----------------
extern "C" void kernel_launch(void* const* d_in, const int* in_sizes, int n_in,
                              void* d_out, int out_size, void* d_ws, size_t ws_size,
                              hipStream_t stream) {
    const float* features = (const float*)d_in[0];
    const float* coords = (const float*)d_in[1];
    const float* w1 = (const float*)d_in[2];
    const float* g1 = (const float*)d_in[4];
    const float* be1 = (const float*)d_in[5];
    const float* w2 = (const float*)d_in[6];
    const float* g2 = (const float*)d_in[8];
    const float* be2 = (const float*)d_in[9];
    const float* wp = (const float*)d_in[10];
    const float* bp = (const float*)d_in[11];
    const float* gp = (const float*)d_in[12];
    const float* bep = (const float*)d_in[13];
    const float* wf = (const float*)d_in[14];
    const float* bf = (const float*)d_in[15];
    const float* wfu = (const float*)d_in[16];
    const float* bfu = (const float*)d_in[17];
    const float* gfu = (const float*)d_in[18];
    const float* befu = (const float*)d_in[19];

    float* ws = (float*)d_ws;
    float* nc = ws;                        // 49152
    int* vidx = (int*)(ws + 49152);        // 16384 ints
    float* cnt = ws + 65536;               // 131072 (pden overlays later)
    float* pden = cnt;
    float* gridA = ws + 196608;            // cf f32 scatter grid, then cl f32 conv out
    float* gridCL = gridA;
    float* gTpool = ws + 8585216;          // gT bf16 / pnum / pstB later
    ushort_t* gT = (ushort_t*)gTpool;
    float* pnum = gTpool;
    float* pstB = gTpool;                  // 32768 floats (after combine2, pool is dead)
    float* stats = ws + 16973824;          // 512 finalized (pt, fusion)
    float* voxreg = ws + 16974336;         // wS1/wS2 until devox
    ushort_t* wS1 = (ushort_t*)voxreg;
    ushort_t* wS2 = wS1 + 110592;
    float* vox = voxreg;
    float* pt = ws + 18022912;
    float* fzf = ws + 19071488;
    float* wpT = ws + 20120064;            // 4096
    float* wfuT = wpT + 4096;              // 12288
    float* bC = wfuT + 12288;              // 64
    float* fpre = ws + 21168640;           // featb overlays
    ushort_t* featb = (ushort_t*)fpre;
    float* accs = ws + 22217216;           // 512 float stat accumulators (conv)

    float* out = (float*)d_out;

    hipMemsetAsync(accs, 0, 512 * 4, stream);
    hipMemsetAsync(cnt, 0, (size_t)(131072 + 8388608) * 4, stream);

    // prep
    k_fold<<<65, 256, 0, stream>>>(wp, wfu, wf, bf, bfu, wpT, wfuT, bC);
    k_f2b<<<BB * 64 * NN / 8 / 256, 256, 0, stream>>>(features, featb);
    k_tws<<<432, 256, 0, stream>>>(w1, wS1);
    k_tws<<<432, 256, 0, stream>>>(w2, wS2);
    k_nc<<<BB, 256, 0, stream>>>(coords, nc, vidx);
    k_scatter<<<BB * 64 * NN / 256, 256, 0, stream>>>(features, vidx, gridA, cnt);
    k_avgT<<<dim3(512, BB), 256, 0, stream>>>(gridA, cnt, gT);

    // voxel branch
    k_convlds<<<512, 256, 0, stream>>>(gT, wS1, gridCL, accs);
    k_bncast<<<BB * R3 * 64 / 8 / 256, 256, 0, stream>>>(gridCL, accs, g1, be1,
                                                         1.0f / (BB * R3), 0.1f, gT);
    k_convlds<<<512, 256, 0, stream>>>(gT, wS2, gridCL, accs + 128);
    k_devox2<<<dim3(NN / 16, BB), 256, 0, stream>>>(gridCL, accs + 128, g2, be2,
                                                    1.0f / (BB * R3), nc, vox);

    // fuzzy branch
    k_fuzzym<<<dim3(64, 4, BB), 256, 0, stream>>>(coords, featb, pnum, pden);
    k_combine2<<<BB * 64 * NN / 256, 256, 0, stream>>>(pnum, pden, fzf);

    // point branch (partial stats into pstB, overlaying the now-dead pnum pool)
    k_1x1s<<<dim3(NN / 64, 4, BB), 256, 0, stream>>>(features, wpT, bp, pt, pstB);
    k_bnfin2<<<64, 256, 0, stream>>>(pstB, gp, bep, stats + 256, 1.0f / (BB * NN));

    // fusion (wf folded into wfuT segC; pt BN on the fly; partial stats)
    k_1x1f<<<dim3(NN / 64, 4, BB), 256, 0, stream>>>(vox, pt, fzf, stats + 256, wfuT, bC,
                                                     fpre, pstB);
    k_bnfin2<<<64, 256, 0, stream>>>(pstB, gfu, befu, stats + 384, 1.0f / (BB * NN));
    k_bn_act<<<BB * 64 * NN / 4 / 256, 256, 0, stream>>>(fpre, stats + 384, out, 10, 0.0f);

    hipMemcpyAsync(out + (size_t)BB * CO * NN, coords, (size_t)BB * 3 * NN * 4,
                   hipMemcpyDeviceToDevice, stream);
}

// Round 12
// 275.120 us; speedup vs baseline: 1.8208x; 1.0465x over previous
//
#include <hip/hip_runtime.h>
#include <hip/hip_bf16.h>
#include <math.h>

#define RR 32
#define R3 32768
#define BB 4
#define CI 64
#define CO 64
#define NN 4096

typedef short v8s __attribute__((ext_vector_type(8)));
typedef float v4f __attribute__((ext_vector_type(4)));
typedef unsigned short ushort_t;

__device__ __forceinline__ unsigned short f2bf(float f) {
    unsigned int u = __float_as_uint(f);
    unsigned int r = (u + 0x7FFFu + ((u >> 16) & 1u)) >> 16;
    return (unsigned short)r;
}

__device__ __forceinline__ void gll16(const void* g, void* l) {
    __builtin_amdgcn_global_load_lds((const __attribute__((address_space(1))) unsigned int*)g,
                                     (__attribute__((address_space(3))) unsigned int*)l, 16, 0, 0);
}

// ---------------- block reduce helpers ----------------
__device__ __forceinline__ float blockReduceSum(float v, float* sm) {
    int tid = threadIdx.x;
    sm[tid] = v; __syncthreads();
    for (int off = 128; off > 0; off >>= 1) {
        if (tid < off) sm[tid] += sm[tid + off];
        __syncthreads();
    }
    float r = sm[0]; __syncthreads();
    return r;
}
__device__ __forceinline__ float blockReduceMax(float v, float* sm) {
    int tid = threadIdx.x;
    sm[tid] = v; __syncthreads();
    for (int off = 128; off > 0; off >>= 1) {
        if (tid < off) sm[tid] = fmaxf(sm[tid], sm[tid + off]);
        __syncthreads();
    }
    float r = sm[0]; __syncthreads();
    return r;
}

// ---------------- voxel coords + fused voxel count ----------------
__global__ void k_nc(const float* __restrict__ coords, float* __restrict__ nc,
                     int* __restrict__ vidx, int* __restrict__ cntI) {
    int b = blockIdx.x, tid = threadIdx.x;
    __shared__ float sm[256];
    const float* cb = coords + (size_t)b * 3 * NN;
    float s0 = 0, s1 = 0, s2 = 0;
    for (int n = tid; n < NN; n += 256) {
        s0 += cb[n]; s1 += cb[NN + n]; s2 += cb[2 * NN + n];
    }
    float m0 = blockReduceSum(s0, sm) * (1.0f / NN);
    float m1 = blockReduceSum(s1, sm) * (1.0f / NN);
    float m2 = blockReduceSum(s2, sm) * (1.0f / NN);
    float mx = 0;
    for (int n = tid; n < NN; n += 256) {
        float dx = cb[n] - m0, dy = cb[NN + n] - m1, dz = cb[2 * NN + n] - m2;
        mx = fmaxf(mx, dx * dx + dy * dy + dz * dz);
    }
    mx = blockReduceMax(mx, sm);
    float denom = 2.0f * sqrtf(mx);
    float mean[3] = {m0, m1, m2};
    for (int n = tid; n < NN; n += 256) {
        int vi[3];
        #pragma unroll
        for (int ax = 0; ax < 3; ax++) {
            float x = (cb[ax * NN + n] - mean[ax]) / denom + 0.5f;
            x = x * RR;
            x = fminf(fmaxf(x, 0.0f), (float)(RR - 1));
            nc[((size_t)b * 3 + ax) * NN + n] = x;
            vi[ax] = (int)rintf(x);
        }
        int idx = (vi[0] * RR + vi[1]) * RR + vi[2];
        vidx[b * NN + n] = idx;
        atomicAdd(&cntI[b * R3 + idx], 1);
    }
}

// ---------------- scan: 131072 counts -> per-block local scan + block sums ----------------
__global__ void k_scan1(const int* __restrict__ cntI, int* __restrict__ lscan,
                        int* __restrict__ bsum) {
    __shared__ int sm[256];
    int tid = threadIdx.x;
    int i = blockIdx.x * 256 + tid;
    int v = cntI[i];
    sm[tid] = v; __syncthreads();
    for (int off = 1; off < 256; off <<= 1) {
        int t = (tid >= off) ? sm[tid - off] : 0;
        __syncthreads();
        sm[tid] += t;
        __syncthreads();
    }
    lscan[i] = sm[tid] - v;
    if (tid == 255) bsum[blockIdx.x] = sm[tid];
}

__global__ void k_scan2(const int* __restrict__ bsum, int* __restrict__ bbase) {
    __shared__ int sm[512];
    int tid = threadIdx.x;
    int v = bsum[tid];
    sm[tid] = v; __syncthreads();
    for (int off = 1; off < 512; off <<= 1) {
        int t = (tid >= off) ? sm[tid - off] : 0;
        __syncthreads();
        sm[tid] += t;
        __syncthreads();
    }
    bbase[tid] = sm[tid] - v;
}

// ---------------- fill CSR point lists ----------------
__global__ void k_fill(const int* __restrict__ vidx, const int* __restrict__ lscan,
                       const int* __restrict__ bbase, int* __restrict__ rank,
                       int* __restrict__ plist) {
    int i = blockIdx.x * 256 + threadIdx.x;  // B*NN
    int b = i >> 12, n = i & (NN - 1);
    int flat = b * R3 + vidx[i];
    int r = atomicAdd(&rank[flat], 1);
    plist[bbase[flat >> 8] + lscan[flat] + r] = n;
}

// ---------------- features cf f32 -> cl f32 (for gather) ----------------
__global__ void k_tfcl(const float* __restrict__ feat, float* __restrict__ featT) {
    __shared__ float t[64][65];
    int b = blockIdx.y, n0 = blockIdx.x * 64, tid = threadIdx.x;
    int q = tid >> 6, nl = tid & 63;
    #pragma unroll
    for (int k = 0; k < 16; k++) {
        int c = q * 16 + k;
        t[nl][c] = feat[((size_t)(b * CI + c)) * NN + n0 + nl];
    }
    __syncthreads();
    #pragma unroll
    for (int k = 0; k < 16; k++) {
        int n = q * 16 + k;
        featT[((size_t)b * NN + n0 + n) * 64 + nl] = t[n][nl];
    }
}

// ---------------- segmented gather-mean -> gT bf16 cl (no atomics) ----------------
__global__ __launch_bounds__(256) void k_gather(const float* __restrict__ featT,
                                                const int* __restrict__ cntI,
                                                const int* __restrict__ lscan,
                                                const int* __restrict__ bbase,
                                                const int* __restrict__ plist,
                                                ushort_t* __restrict__ gT) {
    int wv = threadIdx.x >> 6, lane = threadIdx.x & 63;
    int vbase = blockIdx.x * 32 + wv * 8;
    for (int k = 0; k < 8; k++) {
        int flat = vbase + k;
        int count = cntI[flat];
        float s = 0.0f;
        if (count > 0) {
            int b = flat >> 15;
            int start = bbase[flat >> 8] + lscan[flat];
            for (int j = 0; j < count; j++) {
                int n = plist[start + j];
                s += featT[((size_t)b * NN + n) * 64 + lane];
            }
            s *= 1.0f / (float)count;
        }
        gT[(size_t)flat * 64 + lane] = f2bf(s);
    }
}

// ---------------- features f32 -> bf16 (cf, for fuzzym) ----------------
__global__ void k_f2b(const float* __restrict__ x, ushort_t* __restrict__ o) {
    size_t i = (size_t)blockIdx.x * 256 + threadIdx.x;
    float4 a = ((const float4*)x)[i * 2];
    float4 b = ((const float4*)x)[i * 2 + 1];
    union { __hip_bfloat162 h[4]; uint4 u; } pk;
    pk.h[0] = __float22bfloat162_rn(make_float2(a.x, a.y));
    pk.h[1] = __float22bfloat162_rn(make_float2(a.z, a.w));
    pk.h[2] = __float22bfloat162_rn(make_float2(b.x, b.y));
    pk.h[3] = __float22bfloat162_rn(make_float2(b.z, b.w));
    ((uint4*)o)[i] = pk.u;
}

// ---------------- weight transform: wS[dzdy 9][cih 2][dx 3][co 64][cis 32] bf16 ----------------
__global__ void k_tws(const float* __restrict__ w, ushort_t* __restrict__ wS) {
    int i = blockIdx.x * 256 + threadIdx.x;  // 110592
    int cis = i & 31, co = (i >> 5) & 63;
    int dx = (i >> 11) % 3, cih = (i / 6144) & 1, dzdy = i / 12288;
    int k = dzdy * 3 + dx, ci = cih * 32 + cis;
    wS[i] = f2bf(w[((size_t)co * CI + ci) * 27 + k]);
}

// ---------------- weight fold/transposes for 1x1 kernels ----------------
__global__ void k_fold(const float* __restrict__ wp, const float* __restrict__ wfu,
                       const float* __restrict__ wf, const float* __restrict__ bf,
                       const float* __restrict__ bfu,
                       float* __restrict__ wpT, float* __restrict__ wfuT,
                       float* __restrict__ bC) {
    int i = blockIdx.x * 256 + threadIdx.x;
    if (i < 4096) {
        int c = i >> 6, o = i & 63;
        wpT[c * 64 + o] = wp[o * 64 + c];
    } else if (i < 12288) {
        int j = i - 4096;
        int c = j >> 6, o = j & 63;
        wfuT[c * 64 + o] = wfu[(size_t)o * 192 + c];
    } else if (i < 16384) {
        int j = i - 12288;
        int c = j >> 6, o = j & 63;
        float s = 0;
        for (int k = 0; k < 64; k++)
            s += wfu[(size_t)o * 192 + 128 + k] * wf[(size_t)k * 64 + c];
        wfuT[(128 + c) * 64 + o] = s;
    } else if (i < 16448) {
        int o = i - 16384;
        float s = bfu[o];
        for (int k = 0; k < 64; k++)
            s += wfu[(size_t)o * 192 + 128 + k] * bf[k];
        bC[o] = s;
    }
}

// ---------------- BN(from accs) + lrelu + bf16 cast (cl -> cl) ----------------
__global__ void k_bncast(const float* __restrict__ x, const float* __restrict__ accs,
                         const float* __restrict__ g, const float* __restrict__ be,
                         float invcnt, float slope, ushort_t* __restrict__ o) {
    size_t i = (size_t)blockIdx.x * 256 + threadIdx.x;  // over B*R3*64/8
    int c0 = (int)((i * 8) & 63);
    float sc[8], sh[8];
    #pragma unroll
    for (int j = 0; j < 8; j++) {
        int c = c0 + j;
        float mean = accs[2 * c] * invcnt;
        float var = accs[2 * c + 1] * invcnt - mean * mean;
        float scale = g[c] * rsqrtf(var + 1e-4f);
        sc[j] = scale;
        sh[j] = be[c] - mean * scale;
    }
    float4 a = ((const float4*)x)[i * 2];
    float4 d = ((const float4*)x)[i * 2 + 1];
    float va[8] = {a.x, a.y, a.z, a.w, d.x, d.y, d.z, d.w};
    unsigned pk[4];
    #pragma unroll
    for (int j = 0; j < 4; j++) {
        float u0 = va[2 * j] * sc[2 * j] + sh[2 * j];
        float u1 = va[2 * j + 1] * sc[2 * j + 1] + sh[2 * j + 1];
        u0 = u0 > 0 ? u0 : slope * u0;
        u1 = u1 > 0 ? u1 : slope * u1;
        pk[j] = (unsigned)f2bf(u0) | ((unsigned)f2bf(u1) << 16);
    }
    ((uint4*)o)[i] = make_uint4(pk[0], pk[1], pk[2], pk[3]);
}

// ---------------- LDS-staged MFMA conv3d 3x3x3, fused BN-stats epilogue ----------------
__global__ __launch_bounds__(256) void k_convlds(const ushort_t* __restrict__ gT,
                                                 const ushort_t* __restrict__ wS,
                                                 float* __restrict__ outCL,
                                                 float* __restrict__ accs) {
    __shared__ ushort_t lin[20480];     // 40960B input plane (also reused as stats buf)
    __shared__ ushort_t lw[2][6144];    // 2 x 12288B weights
    int bid = blockIdx.x;
    int wgid = (bid & 7) * 64 + (bid >> 3);
    int yt = wgid & 3, z0 = (wgid >> 2) & 31, b = wgid >> 7;
    int tid = threadIdx.x;
    int w = __builtin_amdgcn_readfirstlane(tid >> 6);
    int lane = tid & 63, l15 = lane & 15, l4 = lane >> 4;
    int y0 = yt * 8;
    const ushort_t* gTb = gT + (size_t)b * R3 * 64;

    int voxF[4];
    #pragma unroll
    for (int f = 0; f < 4; f++)
        voxF[f] = (w * 2 + (f >> 1)) * 32 + (f & 1) * 16 + l15 - 1;
    bool xlo_ok = (l15 != 0), xhi_ok = (l15 != 15);

    const v8s vzero = {};
    v4f acc[4][4];
    #pragma unroll
    for (int m = 0; m < 4; m++)
        #pragma unroll
        for (int f = 0; f < 4; f++)
            acc[m][f] = (v4f){0.0f, 0.0f, 0.0f, 0.0f};

#define WSTAGE(s)                                                              \
    do {                                                                       \
        const ushort_t* _src = wS + (size_t)(s) * 6144;                        \
        ushort_t* _dst = lw[(s) & 1];                                          \
        _Pragma("unroll") for (int _i = 0; _i < 3; _i++) {                     \
            int _p = _i * 256 + w * 64;                                        \
            gll16(_src + (size_t)(_p + lane) * 8, _dst + (size_t)_p * 8);      \
        }                                                                      \
    } while (0)

#define ISTAGE(dz)                                                             \
    do {                                                                       \
        int _zp = z0 - 1 + (dz);                                               \
        if (_zp < 0 || _zp > 31) {                                             \
            for (int _q = 0; _q < 10; _q++)                                    \
                *(v8s*)&lin[(size_t)(w * 640 + _q * 64 + lane) * 8] = vzero;   \
        } else {                                                               \
            if (yt == 0) *(v8s*)&lin[(size_t)tid * 8] = vzero;                 \
            if (yt == 3) *(v8s*)&lin[(size_t)(2304 + tid) * 8] = vzero;        \
            const ushort_t* _pb = gTb + ((size_t)_zp * 1024 + (size_t)(y0 - 1) * 32) * 64; \
            int _g0 = (yt == 0) ? 256 : 0;                                     \
            int _nc = 10 - (yt == 0) - (yt == 3);                              \
            for (int _i = 0; _i < _nc; _i++) {                                 \
                int _pbase = _g0 + _i * 256 + w * 64;                          \
                int _p = _pbase + lane;                                        \
                int _vx = _p >> 3, _js = _p & 7;                               \
                int _sg = _vx * 8 + (_js ^ (_vx & 7));                         \
                gll16(_pb + (size_t)_sg * 8, lin + (size_t)_pbase * 8);        \
            }                                                                  \
        }                                                                      \
    } while (0)

    WSTAGE(0);
    for (int s = 0; s < 18; s++) {
        int dy = (s / 2) % 3, cih = s & 1;
        asm volatile("s_barrier" ::: "memory");
        if ((s % 6) == 0) ISTAGE(s / 6);
        if (s + 1 < 18) WSTAGE(s + 1);
        if (s + 1 < 18) asm volatile("s_waitcnt vmcnt(3) lgkmcnt(0)" ::: "memory");
        else            asm volatile("s_waitcnt vmcnt(0) lgkmcnt(0)" ::: "memory");
        asm volatile("s_barrier" ::: "memory");

        const ushort_t* lwb = lw[s & 1];
        #pragma unroll
        for (int dx = 0; dx < 3; dx++) {
            v8s Bf[4];
            #pragma unroll
            for (int f = 0; f < 4; f++) {
                int vox = voxF[f] + dy * 32 + dx;
                int g = vox * 8 + ((cih * 4 + l4) ^ (vox & 7));
                int bix = g * 16;
                bix = bix < 0 ? 0 : bix;
                v8s vb = *(const v8s*)((const char*)lin + bix);
                bool ok = (dx == 0 && (f & 1) == 0) ? xlo_ok :
                          (dx == 2 && (f & 1) == 1) ? xhi_ok : true;
                Bf[f] = ok ? vb : vzero;
            }
            const ushort_t* ap = lwb + dx * 2048 + l15 * 32 + l4 * 8;
            #pragma unroll
            for (int m = 0; m < 4; m++) {
                v8s Af = *(const v8s*)(ap + m * 512);
                #pragma unroll
                for (int f = 0; f < 4; f++)
                    acc[m][f] = __builtin_amdgcn_mfma_f32_16x16x32_bf16(Af, Bf[f], acc[m][f], 0, 0, 0);
            }
        }
    }

    // channel-last f4 stores
    #pragma unroll
    for (int m = 0; m < 4; m++) {
        #pragma unroll
        for (int f = 0; f < 4; f++) {
            int y = y0 + w * 2 + (f >> 1);
            int x = (f & 1) * 16 + l15;
            float4 o = make_float4(acc[m][f][0], acc[m][f][1], acc[m][f][2], acc[m][f][3]);
            *(float4*)&outCL[((size_t)b * R3 + z0 * 1024 + y * 32 + x) * 64 + m * 16 + l4 * 4] = o;
        }
    }

    // ---- fused BN-stats: per-block sum/sumsq per co -> atomics ----
    __syncthreads();
    float* sbuf = (float*)lin;
    #pragma unroll
    for (int m = 0; m < 4; m++)
        #pragma unroll
        for (int r = 0; r < 4; r++) {
            float s = 0, q = 0;
            #pragma unroll
            for (int f = 0; f < 4; f++) {
                float v = acc[m][f][r];
                s += v; q += v * v;
            }
            sbuf[tid * 32 + (m * 4 + r) * 2] = s;
            sbuf[tid * 32 + (m * 4 + r) * 2 + 1] = q;
        }
    __syncthreads();
    if (tid < 128) {
        int co = tid >> 1, val = tid & 1;
        int m = co >> 4, cl4 = (co >> 2) & 3, r = co & 3;
        float a = 0;
        for (int w2 = 0; w2 < 4; w2++)
            for (int l = 0; l < 16; l++)
                a += sbuf[(w2 * 64 + cl4 * 16 + l) * 32 + (m * 4 + r) * 2 + val];
        atomicAdd(&accs[2 * co + val], a);
    }
#undef WSTAGE
#undef ISTAGE
}

// reduce 256 partials per channel (one block per channel)
__global__ void k_bnfin2(const float* __restrict__ pst, const float* __restrict__ g,
                         const float* __restrict__ be, float* __restrict__ stats,
                         float invcnt) {
    int c = blockIdx.x, tid = threadIdx.x;
    __shared__ float rs[256], rq[256];
    rs[tid] = pst[(c * 256 + tid) * 2];
    rq[tid] = pst[(c * 256 + tid) * 2 + 1];
    __syncthreads();
    for (int off = 128; off > 0; off >>= 1) {
        if (tid < off) { rs[tid] += rs[tid + off]; rq[tid] += rq[tid + off]; }
        __syncthreads();
    }
    if (tid == 0) {
        float mean = rs[0] * invcnt;
        float var = rq[0] * invcnt - mean * mean;
        float sc = g[c] * rsqrtf(var + 1e-4f);
        stats[2 * c] = sc;
        stats[2 * c + 1] = be[c] - mean * sc;
    }
}

__global__ void k_bn_act(const float* __restrict__ x, const float* __restrict__ stats,
                         float* __restrict__ out, int shift, float slope) {
    size_t i = (size_t)blockIdx.x * 256 + threadIdx.x;
    int c = (int)((i >> shift) & 63);
    float sc = stats[2 * c], sh = stats[2 * c + 1];
    float4 v = ((const float4*)x)[i];
    v.x = v.x * sc + sh; v.y = v.y * sc + sh; v.z = v.z * sc + sh; v.w = v.w * sc + sh;
    v.x = v.x > 0 ? v.x : slope * v.x;
    v.y = v.y > 0 ? v.y : slope * v.y;
    v.z = v.z > 0 ? v.z : slope * v.z;
    v.w = v.w > 0 ? v.w : slope * v.w;
    ((float4*)out)[i] = v;
}

// ---------------- devoxelize, BN(from accs)+lrelu fused, channel-last gather ----------------
__global__ void k_devox2(const float* __restrict__ gcl, const float* __restrict__ accs,
                         const float* __restrict__ g, const float* __restrict__ be,
                         float invcnt, const float* __restrict__ nc,
                         float* __restrict__ out) {
    int b = blockIdx.y;
    int tid = threadIdx.x, p = tid >> 4, q = tid & 15;
    int n = blockIdx.x * 16 + p;
    float x = nc[((size_t)b * 3 + 0) * NN + n];
    float y = nc[((size_t)b * 3 + 1) * NN + n];
    float z = nc[((size_t)b * 3 + 2) * NN + n];
    float fx = floorf(x), fy = floorf(y), fz = floorf(z);
    int lx = (int)fx, ly = (int)fy, lz = (int)fz;
    int hx = min(lx + 1, RR - 1), hy = min(ly + 1, RR - 1), hz = min(lz + 1, RR - 1);
    float frx = x - fx, fry = y - fy, frz = z - fz;
    int xx[2] = {lx, hx}, yy[2] = {ly, hy}, zz[2] = {lz, hz};
    float wx[2] = {1.0f - frx, frx}, wy[2] = {1.0f - fry, fry}, wz[2] = {1.0f - frz, frz};
    float sc[4], sh[4];
    #pragma unroll
    for (int j = 0; j < 4; j++) {
        int c = q * 4 + j;
        float mean = accs[2 * c] * invcnt;
        float var = accs[2 * c + 1] * invcnt - mean * mean;
        float scale = g[c] * rsqrtf(var + 1e-4f);
        sc[j] = scale;
        sh[j] = be[c] - mean * scale;
    }
    float a0 = 0, a1 = 0, a2 = 0, a3 = 0;
    #pragma unroll
    for (int dx = 0; dx < 2; dx++)
        #pragma unroll
        for (int dy = 0; dy < 2; dy++)
            #pragma unroll
            for (int dz = 0; dz < 2; dz++) {
                int idx = (xx[dx] * RR + yy[dy]) * RR + zz[dz];
                float wt = wx[dx] * wy[dy] * wz[dz];
                float4 v = *(const float4*)&gcl[((size_t)b * R3 + idx) * 64 + q * 4];
                float u0 = v.x * sc[0] + sh[0]; u0 = u0 > 0 ? u0 : 0.1f * u0;
                float u1 = v.y * sc[1] + sh[1]; u1 = u1 > 0 ? u1 : 0.1f * u1;
                float u2 = v.z * sc[2] + sh[2]; u2 = u2 > 0 ? u2 : 0.1f * u2;
                float u3 = v.w * sc[3] + sh[3]; u3 = u3 > 0 ? u3 : 0.1f * u3;
                a0 += wt * u0; a1 += wt * u1; a2 += wt * u2; a3 += wt * u3;
            }
    out[((size_t)(b * 64 + q * 4 + 0)) * NN + n] = a0;
    out[((size_t)(b * 64 + q * 4 + 1)) * NN + n] = a1;
    out[((size_t)(b * 64 + q * 4 + 2)) * NN + n] = a2;
    out[((size_t)(b * 64 + q * 4 + 3)) * NN + n] = a3;
}

// ---------------- fuzzy attention (MFMA) v5: A staged in LDS, double-buffered ----------------
__global__ __launch_bounds__(256) void k_fuzzym(const float* __restrict__ coords,
                                                const ushort_t* __restrict__ featb,
                                                float* __restrict__ pnum,
                                                float* __restrict__ pden) {
    __shared__ float cm[3][1024];        // 12 KB
    __shared__ ushort_t la[2][2048];     // 2 x 4 KB A ring
    int b = blockIdx.z, mc = blockIdx.y, nt = blockIdx.x;
    int tid = threadIdx.x;
    int w = tid >> 6, lane = tid & 63, l15 = lane & 15, l4 = lane >> 4;
    int m0 = mc * 1024;

    for (int i = tid; i < 1024; i += 256) {
        float a0 = coords[((size_t)b * 3 + 0) * NN + m0 + i];
        float a1 = coords[((size_t)b * 3 + 1) * NN + m0 + i];
        float a2 = coords[((size_t)b * 3 + 2) * NN + m0 + i];
        float inv = 1.0f / fmaxf(sqrtf(a0 * a0 + a1 * a1 + a2 * a2), 1e-12f);
        cm[0][i] = a0 * inv; cm[1][i] = a1 * inv; cm[2][i] = a2 * inv;
    }

    int n = nt * 64 + w * 16 + l15;
    float q0 = coords[((size_t)b * 3 + 0) * NN + n];
    float q1 = coords[((size_t)b * 3 + 1) * NN + n];
    float q2 = coords[((size_t)b * 3 + 2) * NN + n];
    float qi = 10.0f / fmaxf(sqrtf(q0 * q0 + q1 * q1 + q2 * q2), 1e-12f);
    q0 *= qi; q1 *= qi; q2 *= qi;

    int srow = tid >> 2, sslot = tid & 3;
    int g0 = sslot ^ ((srow >> 1) & 3);
    const ushort_t* fb = featb + (size_t)b * 64 * NN + m0;
    const ushort_t* sbase = fb + (size_t)srow * NN + g0 * 8;
    int rsw = (l15 >> 1) & 3;

    v4f acc[4];
    #pragma unroll
    for (int cb = 0; cb < 4; cb++) acc[cb] = (v4f){0.0f, 0.0f, 0.0f, 0.0f};
    float den = 0.0f;

    gll16(sbase, &la[0][(size_t)tid * 8]);
    asm volatile("s_waitcnt vmcnt(0)" ::: "memory");
    __syncthreads();

    for (int t = 0; t < 32; t++) {
        int cur = t & 1;
        if (t + 1 < 32)
            gll16(sbase + (t + 1) * 32, &la[cur ^ 1][(size_t)tid * 8]);

        int mo = t * 32 + l4 * 8;
        float e[8];
        #pragma unroll
        for (int jj = 0; jj < 2; jj++) {
            float4 x0 = *(const float4*)&cm[0][mo + jj * 4];
            float4 x1 = *(const float4*)&cm[1][mo + jj * 4];
            float4 x2 = *(const float4*)&cm[2][mo + jj * 4];
            e[jj * 4 + 0] = __expf(q0 * x0.x + q1 * x1.x + q2 * x2.x);
            e[jj * 4 + 1] = __expf(q0 * x0.y + q1 * x1.y + q2 * x2.y);
            e[jj * 4 + 2] = __expf(q0 * x0.z + q1 * x1.z + q2 * x2.z);
            e[jj * 4 + 3] = __expf(q0 * x0.w + q1 * x1.w + q2 * x2.w);
        }
        den += ((e[0] + e[1]) + (e[2] + e[3])) + ((e[4] + e[5]) + (e[6] + e[7]));
        union { __hip_bfloat162 h[4]; v8s v; } pk;
        pk.h[0] = __float22bfloat162_rn(make_float2(e[0], e[1]));
        pk.h[1] = __float22bfloat162_rn(make_float2(e[2], e[3]));
        pk.h[2] = __float22bfloat162_rn(make_float2(e[4], e[5]));
        pk.h[3] = __float22bfloat162_rn(make_float2(e[6], e[7]));
        #pragma unroll
        for (int cb = 0; cb < 4; cb++) {
            v8s A = *(const v8s*)&la[cur][(size_t)((cb * 16 + l15) * 4 + (l4 ^ rsw)) * 8];
            acc[cb] = __builtin_amdgcn_mfma_f32_16x16x32_bf16(A, pk.v, acc[cb], 0, 0, 0);
        }
        asm volatile("s_waitcnt vmcnt(0)" ::: "memory");
        __syncthreads();
    }

    den += __shfl_xor(den, 16);
    den += __shfl_xor(den, 32);

    size_t obase = ((size_t)(b * 4 + mc)) * 64 * NN;
    #pragma unroll
    for (int cb = 0; cb < 4; cb++)
        #pragma unroll
        for (int r = 0; r < 4; r++)
            pnum[obase + (size_t)(cb * 16 + l4 * 4 + r) * NN + n] = acc[cb][r];
    if (l4 == 0) pden[((size_t)(b * 4 + mc)) * NN + n] = den;
}

__global__ void k_combine2(const float* __restrict__ pnum, const float* __restrict__ pden,
                           float* __restrict__ fzf) {
    int i = blockIdx.x * 256 + threadIdx.x;
    int b = i >> 18, c = (i >> 12) & 63, n = i & 4095;
    float num = 0, den = 0;
    #pragma unroll
    for (int ch = 0; ch < 4; ch++) {
        num += pnum[((size_t)(b * 4 + ch) * 64 + c) * NN + n];
        den += pden[((size_t)(b * 4 + ch)) * NN + n];
    }
    fzf[((size_t)(b * 64 + c)) * NN + n] = num / den;
}

// ---------------- 1x1 convs: thread = 4n x 1o, partial stats ----------------
__global__ __launch_bounds__(256) void k_1x1s(const float* __restrict__ in,
                                              const float* __restrict__ wT,
                                              const float* __restrict__ bias,
                                              float* __restrict__ out,
                                              float* __restrict__ pst) {
    int b = blockIdx.z, ob = blockIdx.y, bx = blockIdx.x;
    int tid = threadIdx.x;
    int q = tid & 15, o = ob * 16 + (tid >> 4);
    int n = bx * 64 + q * 4;
    const float* src = in + (size_t)b * 64 * NN + n;
    const float* wp_ = wT + o;
    v4f acc = {0, 0, 0, 0};
    #pragma unroll 8
    for (int c = 0; c < 64; c++) {
        float4 x = *(const float4*)&src[(size_t)c * NN];
        float w = wp_[c * 64];
        acc[0] += x.x * w; acc[1] += x.y * w; acc[2] += x.z * w; acc[3] += x.w * w;
    }
    float bv = bias[o];
    float s = 0, q2 = 0;
    float4 ov;
    float* op = (float*)&ov;
    #pragma unroll
    for (int v = 0; v < 4; v++) {
        float val = acc[v] + bv;
        op[v] = val;
        s += val; q2 += val * val;
    }
    *(float4*)&out[((size_t)(b * 64 + o)) * NN + n] = ov;
    #pragma unroll
    for (int off = 1; off < 16; off <<= 1) {
        s += __shfl_xor(s, off);
        q2 += __shfl_xor(q2, off);
    }
    if (q == 0) {
        int part = bx * 4 + b;
        pst[(o * 256 + part) * 2] = s;
        pst[(o * 256 + part) * 2 + 1] = q2;
    }
}

// fusion: wfuT rows 0..63 (vox), 64..127 (pt with BN+relu), 128..191 (folded fzf)
__global__ __launch_bounds__(256) void k_1x1f(const float* __restrict__ vox,
                                              const float* __restrict__ pt,
                                              const float* __restrict__ fzf,
                                              const float* __restrict__ bnB,
                                              const float* __restrict__ wfuT,
                                              const float* __restrict__ bC,
                                              float* __restrict__ out,
                                              float* __restrict__ pst) {
    int b = blockIdx.z, ob = blockIdx.y, bx = blockIdx.x;
    int tid = threadIdx.x;
    int q = tid & 15, o = ob * 16 + (tid >> 4);
    int n = bx * 64 + q * 4;
    const float* srcA = vox + (size_t)b * 64 * NN + n;
    const float* srcB = pt + (size_t)b * 64 * NN + n;
    const float* srcC = fzf + (size_t)b * 64 * NN + n;
    const float* wA = wfuT + o;
    v4f acc = {0, 0, 0, 0};
    #pragma unroll 8
    for (int c = 0; c < 64; c++) {
        float4 x = *(const float4*)&srcA[(size_t)c * NN];
        float w = wA[c * 64];
        acc[0] += x.x * w; acc[1] += x.y * w; acc[2] += x.z * w; acc[3] += x.w * w;
    }
    #pragma unroll 8
    for (int c = 0; c < 64; c++) {
        float4 x = *(const float4*)&srcB[(size_t)c * NN];
        float sc = bnB[2 * c], sh = bnB[2 * c + 1];
        float w = wA[(64 + c) * 64];
        float x0 = fmaxf(x.x * sc + sh, 0.0f), x1 = fmaxf(x.y * sc + sh, 0.0f);
        float x2 = fmaxf(x.z * sc + sh, 0.0f), x3 = fmaxf(x.w * sc + sh, 0.0f);
        acc[0] += x0 * w; acc[1] += x1 * w; acc[2] += x2 * w; acc[3] += x3 * w;
    }
    #pragma unroll 8
    for (int c = 0; c < 64; c++) {
        float4 x = *(const float4*)&srcC[(size_t)c * NN];
        float w = wA[(128 + c) * 64];
        acc[0] += x.x * w; acc[1] += x.y * w; acc[2] += x.z * w; acc[3] += x.w * w;
    }
    float bv = bC[o];
    float s = 0, q2 = 0;
    float4 ov;
    float* op = (float*)&ov;
    #pragma unroll
    for (int v = 0; v < 4; v++) {
        float val = acc[v] + bv;
        op[v] = val;
        s += val; q2 += val * val;
    }
    *(float4*)&out[((size_t)(b * 64 + o)) * NN + n] = ov;
    #pragma unroll
    for (int off = 1; off < 16; off <<= 1) {
        s += __shfl_xor(s, off);
        q2 += __shfl_xor(q2, off);
    }
    if (q == 0) {
        int part = bx * 4 + b;
        pst[(o * 256 + part) * 2] = s;
        pst[(o * 256 + part) * 2 + 1] = q2;
    }
}

// ---------------- launcher ----------------
extern "C" void kernel_launch(void* const* d_in, const int* in_sizes, int n_in,
                              void* d_out, int out_size, void* d_ws, size_t ws_size,
                              hipStream_t stream) {
    const float* features = (const float*)d_in[0];
    const float* coords = (const float*)d_in[1];
    const float* w1 = (const float*)d_in[2];
    const float* g1 = (const float*)d_in[4];
    const float* be1 = (const float*)d_in[5];
    const float* w2 = (const float*)d_in[6];
    const float* g2 = (const float*)d_in[8];
    const float* be2 = (const float*)d_in[9];
    const float* wp = (const float*)d_in[10];
    const float* bp = (const float*)d_in[11];
    const float* gp = (const float*)d_in[12];
    const float* bep = (const float*)d_in[13];
    const float* wf = (const float*)d_in[14];
    const float* bf = (const float*)d_in[15];
    const float* wfu = (const float*)d_in[16];
    const float* bfu = (const float*)d_in[17];
    const float* gfu = (const float*)d_in[18];
    const float* befu = (const float*)d_in[19];

    float* ws = (float*)d_ws;
    float* nc = ws;                        // 49152
    int* vidx = (int*)(ws + 49152);        // 16384 ints
    int* cntI = (int*)(ws + 65536);        // 131072 ints (pden overlays later)
    float* pden = ws + 65536;
    float* gridCL = ws + 196608;           // conv out f32 cl (scan arrays overlay pre-conv)
    int* lscan = (int*)(ws + 196608);      // 131072 ints
    int* bsum = (int*)(ws + 327680);       // 512
    int* bbase = (int*)(ws + 328192);      // 512
    int* rank = (int*)(ws + 328704);       // 131072 ints
    int* plist = (int*)(ws + 459776);      // 16384 ints
    float* featT = ws + 476160;            // 1048576 floats (cl f32 features)
    float* gTpool = ws + 8585216;          // gT bf16 / pnum / pstB later
    ushort_t* gT = (ushort_t*)gTpool;
    float* pnum = gTpool;
    float* pstB = gTpool;
    float* stats = ws + 16973824;          // 512 finalized (pt, fusion)
    float* voxreg = ws + 16974336;         // wS1/wS2 until devox
    ushort_t* wS1 = (ushort_t*)voxreg;
    ushort_t* wS2 = wS1 + 110592;
    float* vox = voxreg;
    float* pt = ws + 18022912;
    float* fzf = ws + 19071488;
    float* wpT = ws + 20120064;            // 4096
    float* wfuT = wpT + 4096;              // 12288
    float* bC = wfuT + 12288;              // 64
    float* fpre = ws + 21168640;           // featb overlays
    ushort_t* featb = (ushort_t*)fpre;
    float* accs = ws + 22217216;           // 512 float stat accumulators (conv)

    float* out = (float*)d_out;

    hipMemsetAsync(accs, 0, 512 * 4, stream);
    hipMemsetAsync(cntI, 0, 131072 * 4, stream);
    hipMemsetAsync(rank, 0, 131072 * 4, stream);

    // prep (independent)
    k_fold<<<65, 256, 0, stream>>>(wp, wfu, wf, bf, bfu, wpT, wfuT, bC);
    k_f2b<<<BB * 64 * NN / 8 / 256, 256, 0, stream>>>(features, featb);
    k_tws<<<432, 256, 0, stream>>>(w1, wS1);
    k_tws<<<432, 256, 0, stream>>>(w2, wS2);
    k_tfcl<<<dim3(64, BB), 256, 0, stream>>>(features, featT);

    // voxelization: coords -> vidx+counts -> CSR -> gather-mean (no heavy atomics)
    k_nc<<<BB, 256, 0, stream>>>(coords, nc, vidx, cntI);
    k_scan1<<<512, 256, 0, stream>>>(cntI, lscan, bsum);
    k_scan2<<<1, 512, 0, stream>>>(bsum, bbase);
    k_fill<<<BB * NN / 256, 256, 0, stream>>>(vidx, lscan, bbase, rank, plist);
    k_gather<<<4096, 256, 0, stream>>>(featT, cntI, lscan, bbase, plist, gT);

    // voxel branch
    k_convlds<<<512, 256, 0, stream>>>(gT, wS1, gridCL, accs);
    k_bncast<<<BB * R3 * 64 / 8 / 256, 256, 0, stream>>>(gridCL, accs, g1, be1,
                                                         1.0f / (BB * R3), 0.1f, gT);
    k_convlds<<<512, 256, 0, stream>>>(gT, wS2, gridCL, accs + 128);
    k_devox2<<<dim3(NN / 16, BB), 256, 0, stream>>>(gridCL, accs + 128, g2, be2,
                                                    1.0f / (BB * R3), nc, vox);

    // fuzzy branch
    k_fuzzym<<<dim3(64, 4, BB), 256, 0, stream>>>(coords, featb, pnum, pden);
    k_combine2<<<BB * 64 * NN / 256, 256, 0, stream>>>(pnum, pden, fzf);

    // point branch (partial stats into pstB, overlaying the now-dead pnum pool)
    k_1x1s<<<dim3(NN / 64, 4, BB), 256, 0, stream>>>(features, wpT, bp, pt, pstB);
    k_bnfin2<<<64, 256, 0, stream>>>(pstB, gp, bep, stats + 256, 1.0f / (BB * NN));

    // fusion (wf folded into wfuT segC; pt BN on the fly; partial stats)
    k_1x1f<<<dim3(NN / 64, 4, BB), 256, 0, stream>>>(vox, pt, fzf, stats + 256, wfuT, bC,
                                                     fpre, pstB);
    k_bnfin2<<<64, 256, 0, stream>>>(pstB, gfu, befu, stats + 384, 1.0f / (BB * NN));
    k_bn_act<<<BB * 64 * NN / 4 / 256, 256, 0, stream>>>(fpre, stats + 384, out, 10, 0.0f);

    hipMemcpyAsync(out + (size_t)BB * CO * NN, coords, (size_t)BB * 3 * NN * 4,
                   hipMemcpyDeviceToDevice, stream);
}